// Round 1
// baseline (5724.696 us; speedup 1.0000x reference)
//
#include <hip/hip_runtime.h>

#define Hdim 128
#define NN 10000
#define NE 320000
#define NG 16
#define TROW 16
#define SROW 136   // padded LDS row stride (floats), 544B (16B aligned)

__device__ __forceinline__ float sigm(float x){ return 1.0f/(1.0f+expf(-x)); }

__device__ __forceinline__ void fma4(float* a, float s, float4 w){
    a[0]=fmaf(s,w.x,a[0]); a[1]=fmaf(s,w.y,a[1]); a[2]=fmaf(s,w.z,a[2]); a[3]=fmaf(s,w.w,a[3]);
}
__device__ __forceinline__ float f4c(const float4& v, int i){
    return i==0?v.x : i==1?v.y : i==2?v.z : v.w;
}

// ---------------------------------------------------------------- count
__global__ void count_kernel(const int* __restrict__ batch, float* __restrict__ cnt){
    int i = blockIdx.x*256 + threadIdx.x;
    if (i < NN) atomicAdd(&cnt[batch[i]], 1.0f);
}

// ------------------------------------------- per-step graph-level precompute
// gu[g] = u[g] @ We[384:512] + be   (edge model's u-part, bias folded)
// nu[g] = u[g] @ Wn[256:384] + bn   (node model's u-part, bias folded)
__global__ __launch_bounds__(256) void graph_pre_kernel(
    const float* __restrict__ u, const float* __restrict__ We, const float* __restrict__ be,
    const float* __restrict__ Wn, const float* __restrict__ bn,
    float* __restrict__ gu, float* __restrict__ nu)
{
    __shared__ float sU[NG*SROW];
    int tid = threadIdx.x;
    { int g = tid>>4, j0 = (tid&15)*8;
      *(float4*)(sU+g*SROW+j0)   = *(const float4*)(u+g*Hdim+j0);
      *(float4*)(sU+g*SROW+j0+4) = *(const float4*)(u+g*Hdim+j0+4); }
    __syncthreads();
    int which = tid>>7, j = tid&127;
    const float* W = which ? (Wn + 256*Hdim) : (We + 384*Hdim);
    float bias = which ? bn[j] : be[j];
    float* op  = which ? nu : gu;
    float acc[NG];
    #pragma unroll
    for (int g=0; g<NG; ++g) acc[g] = bias;
    for (int k=0; k<Hdim; ++k){
        float w = W[k*Hdim + j];
        #pragma unroll
        for (int g=0; g<NG; ++g) acc[g] = fmaf(sU[g*SROW+k], w, acc[g]);
    }
    for (int g=0; g<NG; ++g) op[g*Hdim+j] = acc[g];
}

// ------------------------------------------- per-step node-level precompute
// xs1 = x @ We[0:128]  (x[src] part) ; xs2 = x @ We[128:256] (x[dst] part)
__global__ __launch_bounds__(256) void node_pre_kernel(
    const float* __restrict__ x, const float* __restrict__ We,
    float* __restrict__ xs1, float* __restrict__ xs2)
{
    __shared__ float sX[TROW*SROW];
    int tid = threadIdx.x; int n0 = blockIdx.x*TROW;
    { int r = tid>>4, j0 = (tid&15)*8;
      const float* p = x + (long)(n0+r)*Hdim + j0;
      *(float4*)(sX+r*SROW+j0)   = *(const float4*)p;
      *(float4*)(sX+r*SROW+j0+4) = *(const float4*)(p+4); }
    __syncthreads();
    int rt = tid>>6, ct = tid&63;
    int r0 = rt*4; int j0c = ct*4; int mat = j0c>>7; int j0 = j0c&127;
    float acc[4][4];
    #pragma unroll
    for (int r=0;r<4;++r){ acc[r][0]=0.f; acc[r][1]=0.f; acc[r][2]=0.f; acc[r][3]=0.f; }
    const float* W = We + mat*128*Hdim;
    for (int k=0; k<Hdim; k+=4){
        float4 a[4];
        #pragma unroll
        for (int r=0;r<4;++r) a[r] = *(const float4*)(sX+(r0+r)*SROW+k);
        #pragma unroll
        for (int kk=0;kk<4;++kk){
            float4 w = *(const float4*)(W + (k+kk)*Hdim + j0);
            #pragma unroll
            for (int r=0;r<4;++r) fma4(acc[r], f4c(a[r],kk), w);
        }
    }
    float* out = mat ? xs2 : xs1;
    #pragma unroll
    for (int r=0;r<4;++r)
        *(float4*)(out + (long)(n0+r0+r)*Hdim + j0) =
            make_float4(acc[r][0],acc[r][1],acc[r][2],acc[r][3]);
}

// ------------------------------------------- shared GRU phases (per 16-row tile)
// rz phase: sRZ[16][256] = [sIn|sH] @ [Wih;Whh][:, 0:256] + bih + bhh
__device__ __forceinline__ void gru_rz_phase(
    const float* sIn, const float* sH, float* sRZ,
    const float* __restrict__ Wih, const float* __restrict__ Whh,
    const float* __restrict__ bih, const float* __restrict__ bhh, int tid)
{
    int rt = tid>>6, ct = tid&63; int e0 = rt*4, j0 = ct*4;
    float acc[4][4];
    float4 bi = *(const float4*)(bih + j0);
    float4 bh = *(const float4*)(bhh + j0);
    #pragma unroll
    for (int e=0;e<4;++e){ acc[e][0]=bi.x+bh.x; acc[e][1]=bi.y+bh.y;
                           acc[e][2]=bi.z+bh.z; acc[e][3]=bi.w+bh.w; }
    for (int k=0; k<Hdim; k+=4){
        float4 ai[4], ah[4];
        #pragma unroll
        for (int e=0;e<4;++e){ ai[e]=*(const float4*)(sIn+(e0+e)*SROW+k);
                               ah[e]=*(const float4*)(sH +(e0+e)*SROW+k); }
        #pragma unroll
        for (int kk=0;kk<4;++kk){
            float4 wi = *(const float4*)(Wih + (k+kk)*384 + j0);
            float4 wh = *(const float4*)(Whh + (k+kk)*384 + j0);
            #pragma unroll
            for (int e=0;e<4;++e){
                fma4(acc[e], f4c(ai[e],kk), wi);
                fma4(acc[e], f4c(ah[e],kk), wh);
            }
        }
    }
    #pragma unroll
    for (int e=0;e<4;++e)
        *(float4*)(sRZ + (e0+e)*256 + j0) =
            make_float4(acc[e][0],acc[e][1],acc[e][2],acc[e][3]);
}

// n phase + gates: returns new h values for (2 rows e0.., 4 cols j0..)
__device__ __forceinline__ void gru_n_gates(
    const float* sIn, const float* sH, const float* sRZ,
    const float* __restrict__ Wih, const float* __restrict__ Whh,
    const float* __restrict__ bih, const float* __restrict__ bhh, int tid,
    int& e0o, int& j0o, float out[2][4])
{
    int rt = tid>>5, ct = tid&31; int e0 = rt*2, j0 = ct*4;
    e0o = e0; j0o = j0;
    float ni[2][4], nh[2][4];
    float4 bi = *(const float4*)(bih + 256 + j0);
    float4 bh = *(const float4*)(bhh + 256 + j0);
    #pragma unroll
    for (int e=0;e<2;++e){ ni[e][0]=bi.x; ni[e][1]=bi.y; ni[e][2]=bi.z; ni[e][3]=bi.w;
                           nh[e][0]=bh.x; nh[e][1]=bh.y; nh[e][2]=bh.z; nh[e][3]=bh.w; }
    for (int k=0; k<Hdim; k+=4){
        float4 ai0=*(const float4*)(sIn+(e0  )*SROW+k);
        float4 ai1=*(const float4*)(sIn+(e0+1)*SROW+k);
        float4 ah0=*(const float4*)(sH +(e0  )*SROW+k);
        float4 ah1=*(const float4*)(sH +(e0+1)*SROW+k);
        #pragma unroll
        for (int kk=0;kk<4;++kk){
            float4 wi = *(const float4*)(Wih + (k+kk)*384 + 256 + j0);
            float4 wh = *(const float4*)(Whh + (k+kk)*384 + 256 + j0);
            fma4(ni[0], f4c(ai0,kk), wi); fma4(ni[1], f4c(ai1,kk), wi);
            fma4(nh[0], f4c(ah0,kk), wh); fma4(nh[1], f4c(ah1,kk), wh);
        }
    }
    #pragma unroll
    for (int e=0;e<2;++e){
        int ee = e0+e;
        #pragma unroll
        for (int jj=0;jj<4;++jj){
            float r = sigm(sRZ[ee*256 + j0+jj]);
            float z = sigm(sRZ[ee*256 + 128 + j0+jj]);
            float n = tanhf(fmaf(r, nh[e][jj], ni[e][jj]));
            float h = sH[ee*SROW + j0+jj];
            out[e][jj] = (1.f - z)*n + z*h;
        }
    }
}

// ------------------------------------------- fused edge model + edge GRU
__global__ __launch_bounds__(256) void edge_kernel(
    float* __restrict__ ea,
    const float* __restrict__ xs1, const float* __restrict__ xs2,
    const float* __restrict__ gu,
    const float* __restrict__ We,
    const float* __restrict__ Wih, const float* __restrict__ Whh,
    const float* __restrict__ bih, const float* __restrict__ bhh,
    const int* __restrict__ srcv, const int* __restrict__ dstv,
    const int* __restrict__ batch, float* __restrict__ agg)
{
    __shared__ float sA[TROW*SROW];
    __shared__ float sEo[TROW*SROW];
    __shared__ float sRZ[TROW*256];
    __shared__ int sSrc[TROW], sDst[TROW], sG[TROW];
    int tid = threadIdx.x;
    long e0b = (long)blockIdx.x * TROW;
    if (tid < TROW){
        int s = srcv[e0b+tid], d = dstv[e0b+tid];
        sSrc[tid]=s; sDst[tid]=d; sG[tid]=batch[s];
    }
    { int r = tid>>4, j0 = (tid&15)*8;
      const float* p = ea + (e0b+r)*Hdim + j0;
      *(float4*)(sA+r*SROW+j0)   = *(const float4*)p;
      *(float4*)(sA+r*SROW+j0+4) = *(const float4*)(p+4); }
    __syncthreads();
    // phase1: eo = relu(ea @ We3 + xs1[src] + xs2[dst] + gu[g]) (biases in gu)
    {
        int rt = tid>>5, ct = tid&31; int e0 = rt*2, j0 = ct*4;
        float acc[2][4];
        #pragma unroll
        for (int e=0;e<2;++e){
            int ee = e0+e;
            float4 a = *(const float4*)(xs1 + (long)sSrc[ee]*Hdim + j0);
            float4 b = *(const float4*)(xs2 + (long)sDst[ee]*Hdim + j0);
            float4 c = *(const float4*)(gu  + sG[ee]*Hdim + j0);
            acc[e][0]=a.x+b.x+c.x; acc[e][1]=a.y+b.y+c.y;
            acc[e][2]=a.z+b.z+c.z; acc[e][3]=a.w+b.w+c.w;
        }
        const float* W3 = We + 256*Hdim;
        for (int k=0; k<Hdim; k+=4){
            float4 a0 = *(const float4*)(sA+(e0  )*SROW+k);
            float4 a1 = *(const float4*)(sA+(e0+1)*SROW+k);
            #pragma unroll
            for (int kk=0;kk<4;++kk){
                float4 w = *(const float4*)(W3 + (k+kk)*Hdim + j0);
                fma4(acc[0], f4c(a0,kk), w);
                fma4(acc[1], f4c(a1,kk), w);
            }
        }
        #pragma unroll
        for (int e=0;e<2;++e)
            *(float4*)(sEo+(e0+e)*SROW+j0) = make_float4(
                fmaxf(acc[e][0],0.f), fmaxf(acc[e][1],0.f),
                fmaxf(acc[e][2],0.f), fmaxf(acc[e][3],0.f));
    }
    __syncthreads();
    gru_rz_phase(sEo, sA, sRZ, Wih, Whh, bih, bhh, tid);
    __syncthreads();
    {
        int e0, j0; float o[2][4];
        gru_n_gates(sEo, sA, sRZ, Wih, Whh, bih, bhh, tid, e0, j0, o);
        #pragma unroll
        for (int e=0;e<2;++e){
            int ee = e0+e; long row = e0b+ee;
            *(float4*)(ea + row*Hdim + j0) = make_float4(o[e][0],o[e][1],o[e][2],o[e][3]);
            float* ap = agg + (long)sDst[ee]*Hdim + j0;
            atomicAdd(ap+0,o[e][0]); atomicAdd(ap+1,o[e][1]);
            atomicAdd(ap+2,o[e][2]); atomicAdd(ap+3,o[e][3]);
        }
    }
}

// ------------------------------------------- fused node model + node GRU
__global__ __launch_bounds__(256) void node_kernel(
    float* __restrict__ x,
    const float* __restrict__ agg, const float* __restrict__ nu,
    const float* __restrict__ Wn,
    const float* __restrict__ Wih, const float* __restrict__ Whh,
    const float* __restrict__ bih, const float* __restrict__ bhh,
    const int* __restrict__ batch, float* __restrict__ xsum)
{
    __shared__ float sX[TROW*SROW];
    __shared__ float sAg[TROW*SROW];
    __shared__ float sXo[TROW*SROW];
    __shared__ float sRZ[TROW*256];
    __shared__ int sG[TROW];
    int tid = threadIdx.x; int n0 = blockIdx.x*TROW;
    if (tid < TROW) sG[tid] = batch[n0+tid];
    { int r = tid>>4, j0 = (tid&15)*8;
      const float* px = x   + (long)(n0+r)*Hdim + j0;
      const float* pa = agg + (long)(n0+r)*Hdim + j0;
      *(float4*)(sX +r*SROW+j0)   = *(const float4*)px;
      *(float4*)(sX +r*SROW+j0+4) = *(const float4*)(px+4);
      *(float4*)(sAg+r*SROW+j0)   = *(const float4*)pa;
      *(float4*)(sAg+r*SROW+j0+4) = *(const float4*)(pa+4); }
    __syncthreads();
    // phase1: xo = relu([x|agg] @ Wn[0:256] + nu[g]) (u-part + bias in nu)
    {
        int rt = tid>>5, ct = tid&31; int e0 = rt*2, j0 = ct*4;
        float acc[2][4];
        #pragma unroll
        for (int e=0;e<2;++e){
            float4 c = *(const float4*)(nu + sG[e0+e]*Hdim + j0);
            acc[e][0]=c.x; acc[e][1]=c.y; acc[e][2]=c.z; acc[e][3]=c.w;
        }
        for (int k=0; k<Hdim; k+=4){
            float4 a0=*(const float4*)(sX+(e0  )*SROW+k);
            float4 a1=*(const float4*)(sX+(e0+1)*SROW+k);
            #pragma unroll
            for (int kk=0;kk<4;++kk){
                float4 w = *(const float4*)(Wn + (k+kk)*Hdim + j0);
                fma4(acc[0], f4c(a0,kk), w); fma4(acc[1], f4c(a1,kk), w);
            }
        }
        for (int k=0; k<Hdim; k+=4){
            float4 a0=*(const float4*)(sAg+(e0  )*SROW+k);
            float4 a1=*(const float4*)(sAg+(e0+1)*SROW+k);
            #pragma unroll
            for (int kk=0;kk<4;++kk){
                float4 w = *(const float4*)(Wn + (128+k+kk)*Hdim + j0);
                fma4(acc[0], f4c(a0,kk), w); fma4(acc[1], f4c(a1,kk), w);
            }
        }
        #pragma unroll
        for (int e=0;e<2;++e)
            *(float4*)(sXo+(e0+e)*SROW+j0) = make_float4(
                fmaxf(acc[e][0],0.f), fmaxf(acc[e][1],0.f),
                fmaxf(acc[e][2],0.f), fmaxf(acc[e][3],0.f));
    }
    __syncthreads();
    gru_rz_phase(sXo, sX, sRZ, Wih, Whh, bih, bhh, tid);
    __syncthreads();
    {
        int e0, j0; float o[2][4];
        gru_n_gates(sXo, sX, sRZ, Wih, Whh, bih, bhh, tid, e0, j0, o);
        #pragma unroll
        for (int e=0;e<2;++e){
            int ee = e0+e;
            *(float4*)(x + (long)(n0+ee)*Hdim + j0) =
                make_float4(o[e][0],o[e][1],o[e][2],o[e][3]);
            float* sp = xsum + sG[ee]*Hdim + j0;
            atomicAdd(sp+0,o[e][0]); atomicAdd(sp+1,o[e][1]);
            atomicAdd(sp+2,o[e][2]); atomicAdd(sp+3,o[e][3]);
        }
    }
}

// ------------------------------------------- fused global model + global GRU
__global__ __launch_bounds__(256) void global_kernel(
    const float* __restrict__ xsum, const float* __restrict__ cnt,
    float* __restrict__ u,
    const float* __restrict__ Wg, const float* __restrict__ bg,
    const float* __restrict__ Wih, const float* __restrict__ Whh,
    const float* __restrict__ bih, const float* __restrict__ bhh,
    float* __restrict__ out, int step)
{
    __shared__ float sXm[NG*SROW];
    __shared__ float sU[NG*SROW];
    __shared__ float sUo[NG*SROW];
    __shared__ float sRZ[NG*256];
    int tid = threadIdx.x;
    { int g = tid>>4, j0 = (tid&15)*8;
      float inv = 1.0f / fmaxf(cnt[g], 1.0f);
      #pragma unroll
      for (int jj=0;jj<8;++jj) sXm[g*SROW+j0+jj] = xsum[g*Hdim+j0+jj]*inv;
      *(float4*)(sU+g*SROW+j0)   = *(const float4*)(u+g*Hdim+j0);
      *(float4*)(sU+g*SROW+j0+4) = *(const float4*)(u+g*Hdim+j0+4); }
    __syncthreads();
    // phase1: uo = relu([x_mean|u] @ Wg + bg)
    {
        int rt = tid>>5, ct = tid&31; int e0 = rt*2, j0 = ct*4;
        float acc[2][4];
        float4 b = *(const float4*)(bg + j0);
        #pragma unroll
        for (int e=0;e<2;++e){ acc[e][0]=b.x; acc[e][1]=b.y; acc[e][2]=b.z; acc[e][3]=b.w; }
        for (int k=0; k<Hdim; k+=4){
            float4 a0=*(const float4*)(sXm+(e0  )*SROW+k);
            float4 a1=*(const float4*)(sXm+(e0+1)*SROW+k);
            #pragma unroll
            for (int kk=0;kk<4;++kk){
                float4 w = *(const float4*)(Wg + (k+kk)*Hdim + j0);
                fma4(acc[0], f4c(a0,kk), w); fma4(acc[1], f4c(a1,kk), w);
            }
        }
        for (int k=0; k<Hdim; k+=4){
            float4 a0=*(const float4*)(sU+(e0  )*SROW+k);
            float4 a1=*(const float4*)(sU+(e0+1)*SROW+k);
            #pragma unroll
            for (int kk=0;kk<4;++kk){
                float4 w = *(const float4*)(Wg + (128+k+kk)*Hdim + j0);
                fma4(acc[0], f4c(a0,kk), w); fma4(acc[1], f4c(a1,kk), w);
            }
        }
        #pragma unroll
        for (int e=0;e<2;++e)
            *(float4*)(sUo+(e0+e)*SROW+j0) = make_float4(
                fmaxf(acc[e][0],0.f), fmaxf(acc[e][1],0.f),
                fmaxf(acc[e][2],0.f), fmaxf(acc[e][3],0.f));
    }
    __syncthreads();
    gru_rz_phase(sUo, sU, sRZ, Wih, Whh, bih, bhh, tid);
    __syncthreads();
    {
        int e0, j0; float o[2][4];
        gru_n_gates(sUo, sU, sRZ, Wih, Whh, bih, bhh, tid, e0, j0, o);
        #pragma unroll
        for (int e=0;e<2;++e){
            int g = e0+e;
            float4 v = make_float4(o[e][0],o[e][1],o[e][2],o[e][3]);
            *(float4*)(u + g*Hdim + j0) = v;
            *(float4*)(out + (long)(g*3 + step)*Hdim + j0) = v;
        }
    }
}

// ---------------------------------------------------------------- host
extern "C" void kernel_launch(void* const* d_in, const int* in_sizes, int n_in,
                              void* d_out, int out_size, void* d_ws, size_t ws_size,
                              hipStream_t stream)
{
    const float* x    = (const float*)d_in[0];
    const float* ea_i = (const float*)d_in[1];
    const float* u    = (const float*)d_in[2];
    const float* We   = (const float*)d_in[3];
    const float* be   = (const float*)d_in[4];
    const float* Wn   = (const float*)d_in[5];
    const float* bn   = (const float*)d_in[6];
    const float* Wg   = (const float*)d_in[7];
    const float* bg   = (const float*)d_in[8];
    const float* eWih = (const float*)d_in[9];
    const float* eWhh = (const float*)d_in[10];
    const float* ebih = (const float*)d_in[11];
    const float* ebhh = (const float*)d_in[12];
    const float* nWih = (const float*)d_in[13];
    const float* nWhh = (const float*)d_in[14];
    const float* nbih = (const float*)d_in[15];
    const float* nbhh = (const float*)d_in[16];
    const float* gWih = (const float*)d_in[17];
    const float* gWhh = (const float*)d_in[18];
    const float* gbih = (const float*)d_in[19];
    const float* gbhh = (const float*)d_in[20];
    const int*   ei   = (const int*)d_in[21];
    const int*   batch= (const int*)d_in[22];
    const int* src = ei;
    const int* dst = ei + NE;
    float* out = (float*)d_out;

    size_t off = 0;
    auto alloc = [&](size_t bytes)->char*{
        char* p = (char*)d_ws + off;
        off += (bytes + 255) & ~(size_t)255;
        return p;
    };
    float* ea   = (float*)alloc((size_t)NE*Hdim*4);
    float* xcur = (float*)alloc((size_t)NN*Hdim*4);
    float* xs1  = (float*)alloc((size_t)NN*Hdim*4);
    float* xs2  = (float*)alloc((size_t)NN*Hdim*4);
    float* agg  = (float*)alloc((size_t)NN*Hdim*4);
    float* ucur = (float*)alloc((size_t)NG*Hdim*4);
    float* gu   = (float*)alloc((size_t)NG*Hdim*4);
    float* nu   = (float*)alloc((size_t)NG*Hdim*4);
    float* xsum = (float*)alloc((size_t)NG*Hdim*4);
    float* cnt  = (float*)alloc((size_t)NG*4);

    hipMemcpyAsync(ea,   ea_i, (size_t)NE*Hdim*4, hipMemcpyDeviceToDevice, stream);
    hipMemcpyAsync(xcur, x,    (size_t)NN*Hdim*4, hipMemcpyDeviceToDevice, stream);
    hipMemcpyAsync(ucur, u,    (size_t)NG*Hdim*4, hipMemcpyDeviceToDevice, stream);
    hipMemsetAsync(cnt, 0, NG*4, stream);
    count_kernel<<<(NN+255)/256, 256, 0, stream>>>(batch, cnt);

    for (int t=0; t<3; ++t){
        graph_pre_kernel<<<1, 256, 0, stream>>>(ucur, We, be, Wn, bn, gu, nu);
        node_pre_kernel<<<NN/TROW, 256, 0, stream>>>(xcur, We, xs1, xs2);
        hipMemsetAsync(agg, 0, (size_t)NN*Hdim*4, stream);
        edge_kernel<<<NE/TROW, 256, 0, stream>>>(ea, xs1, xs2, gu, We,
                                                 eWih, eWhh, ebih, ebhh,
                                                 src, dst, batch, agg);
        hipMemsetAsync(xsum, 0, (size_t)NG*Hdim*4, stream);
        node_kernel<<<NN/TROW, 256, 0, stream>>>(xcur, agg, nu, Wn,
                                                 nWih, nWhh, nbih, nbhh,
                                                 batch, xsum);
        global_kernel<<<1, 256, 0, stream>>>(xsum, cnt, ucur, Wg, bg,
                                             gWih, gWhh, gbih, gbhh,
                                             out, t);
    }
}

// Round 2
// 2033.717 us; speedup vs baseline: 2.8149x; 2.8149x over previous
//
#include <hip/hip_runtime.h>

#define Hdim 128
#define NN 10000
#define NE 320000
#define NG 16
#define EB 128          // rows (edges or nodes) per block
#define SXO 136         // LDS bf16 row stride (272B: 16B aligned, 2-way-free b128 frags)

typedef __attribute__((ext_vector_type(8))) short bf8;   // 8 bf16 = 4 VGPRs
typedef __attribute__((ext_vector_type(4))) float f4;
#define MFMA16 __builtin_amdgcn_mfma_f32_16x16x32_bf16

__device__ __forceinline__ float sigm(float x){ return 1.0f/(1.0f+expf(-x)); }

__device__ __forceinline__ unsigned short f2bf(float v){
    unsigned int b = __float_as_uint(v);
    return (unsigned short)((b + 0x7FFFu + ((b>>16)&1u)) >> 16);
}

// load 8 consecutive f32 from global, convert RNE -> bf16 fragment
__device__ __forceinline__ bf8 load_frag_f32(const float* __restrict__ p){
    float4 a = *(const float4*)p;
    float4 b = *(const float4*)(p+4);
    bf8 f;
    f[0]=(short)f2bf(a.x); f[1]=(short)f2bf(a.y); f[2]=(short)f2bf(a.z); f[3]=(short)f2bf(a.w);
    f[4]=(short)f2bf(b.x); f[5]=(short)f2bf(b.y); f[6]=(short)f2bf(b.z); f[7]=(short)f2bf(b.w);
    return f;
}

__device__ __forceinline__ bf8 load_pb(const unsigned short* __restrict__ P,
                                       int ntile, int ksteps, int kstep, int lane){
    return *(const bf8*)(P + ((((ntile*ksteps + kstep)<<6) + lane)<<3));
}

// ---------------------------------------------------------------- pack B
// dst element ((ntile*ksteps+kstep)*64+lane)*8+e  =  W[kstep*32+(lane>>4)*8+e][ntile*16+(lane&15)]
// W rows: k < Krows0 -> S0[k][coloff+n] else S1[k-Krows0][coloff+n], row-major ld
__global__ void pack_b(const float* __restrict__ S0, const float* __restrict__ S1,
                       int ld, int coloff, int Krows0, int Ktot, int Ntot,
                       unsigned short* __restrict__ dst)
{
    int idx = blockIdx.x*256 + threadIdx.x;
    int total = Ktot*Ntot;
    if (idx >= total) return;
    int e    = idx & 7;
    int lane = (idx >> 3) & 63;
    int kt   = idx >> 9;
    int ksteps = Ktot >> 5;
    int ntile = kt / ksteps, kstep = kt - ntile*ksteps;
    int k = kstep*32 + ((lane>>4)<<3) + e;
    int n = ntile*16 + (lane&15);
    const float* S = (k < Krows0) ? S0 : S1;
    int kk = (k < Krows0) ? k : (k - Krows0);
    dst[idx] = f2bf(S[(long)kk*ld + coloff + n]);
}

// ---------------------------------------------------------------- count
__global__ void count_kernel(const int* __restrict__ batch, float* __restrict__ cnt){
    int i = blockIdx.x*256 + threadIdx.x;
    if (i < NN) atomicAdd(&cnt[batch[i]], 1.0f);
}

// ------------------------------------------- per-step graph-level precompute (tiny, f32)
// gu[g] = u[g] @ We[384:512] + be ; nu[g] = u[g] @ Wn[256:384] + bn
__global__ __launch_bounds__(256) void graph_pre_kernel(
    const float* __restrict__ u, const float* __restrict__ We, const float* __restrict__ be,
    const float* __restrict__ Wn, const float* __restrict__ bn,
    float* __restrict__ gu, float* __restrict__ nu)
{
    __shared__ float sU[NG*132];
    int tid = threadIdx.x;
    { int g = tid>>4, j0 = (tid&15)*8;
      *(float4*)(sU+g*132+j0)   = *(const float4*)(u+g*Hdim+j0);
      *(float4*)(sU+g*132+j0+4) = *(const float4*)(u+g*Hdim+j0+4); }
    __syncthreads();
    int which = tid>>7, j = tid&127;
    const float* W = which ? (Wn + 256*Hdim) : (We + 384*Hdim);
    float bias = which ? bn[j] : be[j];
    float* op  = which ? nu : gu;
    float acc[NG];
    #pragma unroll
    for (int g=0; g<NG; ++g) acc[g] = bias;
    for (int k=0; k<Hdim; ++k){
        float w = W[k*Hdim + j];
        #pragma unroll
        for (int g=0; g<NG; ++g) acc[g] = fmaf(sU[g*132+k], w, acc[g]);
    }
    for (int g=0; g<NG; ++g) op[g*Hdim+j] = acc[g];
}

// ------------------------------------------- xs12 = x @ [We1 | We2]  (MFMA, N=256)
__global__ __launch_bounds__(256,2) void xs_mfma(
    const float* __restrict__ x, const unsigned short* __restrict__ PXS,
    float* __restrict__ xs12)
{
    int tid = threadIdx.x, lane = tid&63, wave = tid>>6;
    int nb = blockIdx.x*EB + wave*32;
    int arow = lane&15, kg = lane>>4;
    int col = lane&15, crow = kg*4;
    bf8 xF[2][4];
    #pragma unroll
    for (int m=0;m<2;++m){
        int row = nb + m*16 + arow; if (row > NN-1) row = NN-1;
        #pragma unroll
        for (int ks=0;ks<4;++ks)
            xF[m][ks] = load_frag_f32(x + (long)row*Hdim + ks*32 + kg*8);
    }
    #pragma unroll 4
    for (int nt=0; nt<16; ++nt){
        f4 acc0 = {0.f,0.f,0.f,0.f}, acc1 = {0.f,0.f,0.f,0.f};
        #pragma unroll
        for (int ks=0;ks<4;++ks){
            bf8 b = load_pb(PXS, nt, 4, ks, lane);
            acc0 = MFMA16(xF[0][ks], b, acc0, 0,0,0);
            acc1 = MFMA16(xF[1][ks], b, acc1, 0,0,0);
        }
        #pragma unroll
        for (int r=0;r<4;++r){
            int row0 = nb + crow + r, row1 = nb + 16 + crow + r;
            if (row0 < NN) xs12[(long)row0*256 + nt*16 + col] = acc0[r];
            if (row1 < NN) xs12[(long)row1*256 + nt*16 + col] = acc1[r];
        }
    }
}

// ------------------------------------------- fused edge model + edge GRU (MFMA)
__global__ __launch_bounds__(256,2) void edge_mfma(
    float* __restrict__ ea,
    const float* __restrict__ xs12, const float* __restrict__ gu,
    const unsigned short* __restrict__ PW1, const unsigned short* __restrict__ PRZ,
    const unsigned short* __restrict__ PNI, const unsigned short* __restrict__ PNH,
    const float* __restrict__ bih, const float* __restrict__ bhh,
    const int* __restrict__ srcv, const int* __restrict__ dstv,
    const int* __restrict__ batch, float* __restrict__ agg)
{
    __shared__ __align__(16) unsigned short sEo[EB*SXO];
    __shared__ int sS[EB], sD[EB], sG[EB];
    int tid = threadIdx.x, lane = tid&63, wave = tid>>6;
    long eb = (long)blockIdx.x*EB;
    if (tid < EB){
        int s = srcv[eb+tid], d = dstv[eb+tid];
        sS[tid]=s; sD[tid]=d; sG[tid]=batch[s];
    }
    __syncthreads();
    int r0 = wave*32;
    int arow = lane&15, kg = lane>>4;
    int col = lane&15, crow = kg*4;
    // h fragments (edge_attr)
    bf8 eaF[2][4];
    #pragma unroll
    for (int m=0;m<2;++m)
        #pragma unroll
        for (int ks=0;ks<4;++ks)
            eaF[m][ks] = load_frag_f32(ea + (eb + r0 + m*16 + arow)*Hdim + ks*32 + kg*8);
    // phase1: eo = relu(ea@We3 + xs1[src] + xs2[dst] + gu[g])  (be folded in gu)
    #pragma unroll 2
    for (int nt=0; nt<8; ++nt){
        int j = nt*16 + col;
        f4 acc[2];
        #pragma unroll
        for (int m=0;m<2;++m)
            #pragma unroll
            for (int r=0;r<4;++r){
                int lr = r0 + m*16 + crow + r;
                acc[m][r] = xs12[(long)sS[lr]*256 + j]
                          + xs12[(long)sD[lr]*256 + 128 + j]
                          + gu[sG[lr]*Hdim + j];
            }
        #pragma unroll
        for (int ks=0;ks<4;++ks){
            bf8 b = load_pb(PW1, nt, 4, ks, lane);
            acc[0] = MFMA16(eaF[0][ks], b, acc[0], 0,0,0);
            acc[1] = MFMA16(eaF[1][ks], b, acc[1], 0,0,0);
        }
        #pragma unroll
        for (int m=0;m<2;++m)
            #pragma unroll
            for (int r=0;r<4;++r){
                int lr = r0 + m*16 + crow + r;
                sEo[lr*SXO + j] = f2bf(fmaxf(acc[m][r], 0.f));
            }
    }
    // eo fragments from LDS (wave-private rows; compiler inserts lgkmcnt)
    bf8 eoF[2][4];
    #pragma unroll
    for (int m=0;m<2;++m)
        #pragma unroll
        for (int ks=0;ks<4;++ks)
            eoF[m][ks] = *(const bf8*)(sEo + (r0 + m*16 + arow)*SXO + ks*32 + kg*8);
    // gates: rz over K=256 [eo|ea]; n_i = eo@Wni, n_h = ea@Wnh
    #pragma unroll 1
    for (int nt=0; nt<8; ++nt){
        int j = nt*16 + col;
        float vr = bih[j] + bhh[j];
        float vz = bih[128+j] + bhh[128+j];
        float vi = bih[256+j], vh = bhh[256+j];
        f4 ar[2], az[2], ai[2], ah[2];
        #pragma unroll
        for (int m=0;m<2;++m){
            ar[m] = (f4){vr,vr,vr,vr}; az[m] = (f4){vz,vz,vz,vz};
            ai[m] = (f4){vi,vi,vi,vi}; ah[m] = (f4){vh,vh,vh,vh};
        }
        #pragma unroll
        for (int ks=0;ks<8;++ks){
            bf8 A0 = (ks<4) ? eoF[0][ks] : eaF[0][ks-4];
            bf8 A1 = (ks<4) ? eoF[1][ks] : eaF[1][ks-4];
            bf8 bR = load_pb(PRZ, nt,   8, ks, lane);
            bf8 bZ = load_pb(PRZ, nt+8, 8, ks, lane);
            ar[0] = MFMA16(A0, bR, ar[0], 0,0,0);
            ar[1] = MFMA16(A1, bR, ar[1], 0,0,0);
            az[0] = MFMA16(A0, bZ, az[0], 0,0,0);
            az[1] = MFMA16(A1, bZ, az[1], 0,0,0);
        }
        #pragma unroll
        for (int ks=0;ks<4;++ks){
            bf8 bI = load_pb(PNI, nt, 4, ks, lane);
            bf8 bH = load_pb(PNH, nt, 4, ks, lane);
            ai[0] = MFMA16(eoF[0][ks], bI, ai[0], 0,0,0);
            ai[1] = MFMA16(eoF[1][ks], bI, ai[1], 0,0,0);
            ah[0] = MFMA16(eaF[0][ks], bH, ah[0], 0,0,0);
            ah[1] = MFMA16(eaF[1][ks], bH, ah[1], 0,0,0);
        }
        #pragma unroll
        for (int m=0;m<2;++m)
            #pragma unroll
            for (int r=0;r<4;++r){
                int lr = r0 + m*16 + crow + r;
                long grow = eb + lr;
                float h  = ea[grow*Hdim + j];
                float rr = sigm(ar[m][r]);
                float zz = sigm(az[m][r]);
                float nn = tanhf(fmaf(rr, ah[m][r], ai[m][r]));
                float o  = (1.0f - zz)*nn + zz*h;
                ea[grow*Hdim + j] = o;
                atomicAdd(&agg[(long)sD[lr]*Hdim + j], o);
            }
    }
}

// ------------------------------------------- fused node model + node GRU (MFMA)
__global__ __launch_bounds__(256,2) void node_mfma(
    float* __restrict__ x, const float* __restrict__ agg,
    const float* __restrict__ nu,
    const unsigned short* __restrict__ PP1, const unsigned short* __restrict__ PRZ,
    const unsigned short* __restrict__ PNI, const unsigned short* __restrict__ PNH,
    const float* __restrict__ bih, const float* __restrict__ bhh,
    const int* __restrict__ batch, float* __restrict__ xsum)
{
    __shared__ __align__(16) unsigned short sXo[EB*SXO];
    __shared__ int sG[EB];
    int tid = threadIdx.x, lane = tid&63, wave = tid>>6;
    int nb = blockIdx.x*EB;
    if (tid < EB){
        int row = nb + tid; if (row > NN-1) row = NN-1;
        sG[tid] = batch[row];
    }
    __syncthreads();
    int r0 = wave*32;
    int arow = lane&15, kg = lane>>4;
    int col = lane&15, crow = kg*4;
    bf8 xF[2][4], agF[2][4];
    #pragma unroll
    for (int m=0;m<2;++m){
        int row = nb + r0 + m*16 + arow; if (row > NN-1) row = NN-1;
        #pragma unroll
        for (int ks=0;ks<4;++ks){
            xF[m][ks]  = load_frag_f32(x   + (long)row*Hdim + ks*32 + kg*8);
            agF[m][ks] = load_frag_f32(agg + (long)row*Hdim + ks*32 + kg*8);
        }
    }
    // phase1: xo = relu([x|agg]@Wn[0:256] + nu[g])  (u-part + bn folded in nu)
    #pragma unroll 2
    for (int nt=0; nt<8; ++nt){
        int j = nt*16 + col;
        f4 acc[2];
        #pragma unroll
        for (int m=0;m<2;++m)
            #pragma unroll
            for (int r=0;r<4;++r){
                int lr = r0 + m*16 + crow + r;
                acc[m][r] = nu[sG[lr]*Hdim + j];
            }
        #pragma unroll
        for (int ks=0;ks<8;++ks){
            bf8 A0 = (ks<4) ? xF[0][ks] : agF[0][ks-4];
            bf8 A1 = (ks<4) ? xF[1][ks] : agF[1][ks-4];
            bf8 b = load_pb(PP1, nt, 8, ks, lane);
            acc[0] = MFMA16(A0, b, acc[0], 0,0,0);
            acc[1] = MFMA16(A1, b, acc[1], 0,0,0);
        }
        #pragma unroll
        for (int m=0;m<2;++m)
            #pragma unroll
            for (int r=0;r<4;++r){
                int lr = r0 + m*16 + crow + r;
                sXo[lr*SXO + j] = f2bf(fmaxf(acc[m][r], 0.f));
            }
    }
    bf8 xoF[2][4];
    #pragma unroll
    for (int m=0;m<2;++m)
        #pragma unroll
        for (int ks=0;ks<4;++ks)
            xoF[m][ks] = *(const bf8*)(sXo + (r0 + m*16 + arow)*SXO + ks*32 + kg*8);
    #pragma unroll 1
    for (int nt=0; nt<8; ++nt){
        int j = nt*16 + col;
        float vr = bih[j] + bhh[j];
        float vz = bih[128+j] + bhh[128+j];
        float vi = bih[256+j], vh = bhh[256+j];
        f4 ar[2], az[2], ai[2], ah[2];
        #pragma unroll
        for (int m=0;m<2;++m){
            ar[m] = (f4){vr,vr,vr,vr}; az[m] = (f4){vz,vz,vz,vz};
            ai[m] = (f4){vi,vi,vi,vi}; ah[m] = (f4){vh,vh,vh,vh};
        }
        #pragma unroll
        for (int ks=0;ks<8;++ks){
            bf8 A0 = (ks<4) ? xoF[0][ks] : xF[0][ks-4];
            bf8 A1 = (ks<4) ? xoF[1][ks] : xF[1][ks-4];
            bf8 bR = load_pb(PRZ, nt,   8, ks, lane);
            bf8 bZ = load_pb(PRZ, nt+8, 8, ks, lane);
            ar[0] = MFMA16(A0, bR, ar[0], 0,0,0);
            ar[1] = MFMA16(A1, bR, ar[1], 0,0,0);
            az[0] = MFMA16(A0, bZ, az[0], 0,0,0);
            az[1] = MFMA16(A1, bZ, az[1], 0,0,0);
        }
        #pragma unroll
        for (int ks=0;ks<4;++ks){
            bf8 bI = load_pb(PNI, nt, 4, ks, lane);
            bf8 bH = load_pb(PNH, nt, 4, ks, lane);
            ai[0] = MFMA16(xoF[0][ks], bI, ai[0], 0,0,0);
            ai[1] = MFMA16(xoF[1][ks], bI, ai[1], 0,0,0);
            ah[0] = MFMA16(xF[0][ks],  bH, ah[0], 0,0,0);
            ah[1] = MFMA16(xF[1][ks],  bH, ah[1], 0,0,0);
        }
        #pragma unroll
        for (int m=0;m<2;++m)
            #pragma unroll
            for (int r=0;r<4;++r){
                int lr = r0 + m*16 + crow + r;
                int row = nb + lr;
                if (row < NN){
                    float h  = x[(long)row*Hdim + j];
                    float rr = sigm(ar[m][r]);
                    float zz = sigm(az[m][r]);
                    float nn = tanhf(fmaf(rr, ah[m][r], ai[m][r]));
                    float o  = (1.0f - zz)*nn + zz*h;
                    x[(long)row*Hdim + j] = o;
                    atomicAdd(&xsum[sG[lr]*Hdim + j], o);
                }
            }
    }
}

// ------------------------------------------- fused global model + global GRU (tiny, f32)
__global__ __launch_bounds__(256) void global_kernel(
    const float* __restrict__ xsum, const float* __restrict__ cnt,
    float* __restrict__ u,
    const float* __restrict__ Wg, const float* __restrict__ bg,
    const float* __restrict__ Wih, const float* __restrict__ Whh,
    const float* __restrict__ bih, const float* __restrict__ bhh,
    float* __restrict__ out, int step)
{
    __shared__ float sXm[NG*132];
    __shared__ float sU[NG*132];
    __shared__ float sUo[NG*132];
    __shared__ float sRZ[NG*256];
    int tid = threadIdx.x;
    { int g = tid>>4, j0 = (tid&15)*8;
      float inv = 1.0f / fmaxf(cnt[g], 1.0f);
      #pragma unroll
      for (int jj=0;jj<8;++jj) sXm[g*132+j0+jj] = xsum[g*Hdim+j0+jj]*inv;
      *(float4*)(sU+g*132+j0)   = *(const float4*)(u+g*Hdim+j0);
      *(float4*)(sU+g*132+j0+4) = *(const float4*)(u+g*Hdim+j0+4); }
    __syncthreads();
    // uo = relu([x_mean|u] @ Wg + bg) ; then GRU, 2 rows x 1 col per thread via 128-col split
    { int g2 = tid>>7, j = tid&127;       // each thread: 8 graphs (g2*8..) one col
      for (int gg=0; gg<8; ++gg){
          int g = g2*8+gg;
          float a = bg[j];
          for (int k=0;k<Hdim;++k){
              a = fmaf(sXm[g*132+k], Wg[k*Hdim+j], a);
              a = fmaf(sU[g*132+k],  Wg[(128+k)*Hdim+j], a);
          }
          sUo[g*132+j] = fmaxf(a, 0.f);
      }
    }
    __syncthreads();
    { int g2 = tid>>7, j = tid&127;
      for (int gg=0; gg<8; ++gg){
          int g = g2*8+gg;
          float r = bih[j]+bhh[j], z = bih[128+j]+bhh[128+j];
          for (int k=0;k<Hdim;++k){
              float in = sUo[g*132+k], h = sU[g*132+k];
              r = fmaf(in, Wih[k*384+j],     r); r = fmaf(h, Whh[k*384+j],     r);
              z = fmaf(in, Wih[k*384+128+j], z); z = fmaf(h, Whh[k*384+128+j], z);
          }
          sRZ[g*256+j] = r; sRZ[g*256+128+j] = z;
      }
    }
    __syncthreads();
    { int g2 = tid>>7, j = tid&127;
      for (int gg=0; gg<8; ++gg){
          int g = g2*8+gg;
          float ni = bih[256+j], nh = bhh[256+j];
          for (int k=0;k<Hdim;++k){
              ni = fmaf(sUo[g*132+k], Wih[k*384+256+j], ni);
              nh = fmaf(sU[g*132+k],  Whh[k*384+256+j], nh);
          }
          float r = sigm(sRZ[g*256+j]);
          float z = sigm(sRZ[g*256+128+j]);
          float n = tanhf(fmaf(r, nh, ni));
          float h = sU[g*132+j];
          float o = (1.0f - z)*n + z*h;
          u[g*Hdim+j] = o;
          out[(long)(g*3 + step)*Hdim + j] = o;
      }
    }
}

// ---------------------------------------------------------------- host
extern "C" void kernel_launch(void* const* d_in, const int* in_sizes, int n_in,
                              void* d_out, int out_size, void* d_ws, size_t ws_size,
                              hipStream_t stream)
{
    const float* x    = (const float*)d_in[0];
    const float* ea_i = (const float*)d_in[1];
    const float* u    = (const float*)d_in[2];
    const float* We   = (const float*)d_in[3];
    const float* be   = (const float*)d_in[4];
    const float* Wn   = (const float*)d_in[5];
    const float* bn   = (const float*)d_in[6];
    const float* Wg   = (const float*)d_in[7];
    const float* bg   = (const float*)d_in[8];
    const float* eWih = (const float*)d_in[9];
    const float* eWhh = (const float*)d_in[10];
    const float* ebih = (const float*)d_in[11];
    const float* ebhh = (const float*)d_in[12];
    const float* nWih = (const float*)d_in[13];
    const float* nWhh = (const float*)d_in[14];
    const float* nbih = (const float*)d_in[15];
    const float* nbhh = (const float*)d_in[16];
    const float* gWih = (const float*)d_in[17];
    const float* gWhh = (const float*)d_in[18];
    const float* gbih = (const float*)d_in[19];
    const float* gbhh = (const float*)d_in[20];
    const int*   ei   = (const int*)d_in[21];
    const int*   batch= (const int*)d_in[22];
    const int* src = ei;
    const int* dst = ei + NE;
    float* out = (float*)d_out;

    size_t off = 0;
    auto alloc = [&](size_t bytes)->char*{
        char* p = (char*)d_ws + off;
        off += (bytes + 255) & ~(size_t)255;
        return p;
    };
    float* ea   = (float*)alloc((size_t)NE*Hdim*4);
    float* xcur = (float*)alloc((size_t)NN*Hdim*4);
    float* xs12 = (float*)alloc((size_t)NN*256*4);
    float* agg  = (float*)alloc((size_t)NN*Hdim*4);
    float* ucur = (float*)alloc((size_t)NG*Hdim*4);
    float* gu   = (float*)alloc((size_t)NG*Hdim*4);
    float* nu   = (float*)alloc((size_t)NG*Hdim*4);
    float* xsum = (float*)alloc((size_t)NG*Hdim*4);
    float* cnt  = (float*)alloc((size_t)NG*4);
    unsigned short* PXS  = (unsigned short*)alloc(32768*2);  // x@[We1|We2]  K=128 N=256
    unsigned short* PW1  = (unsigned short*)alloc(16384*2);  // We3          K=128 N=128
    unsigned short* PeRZ = (unsigned short*)alloc(65536*2);  // [eWih;eWhh] rz K=256 N=256
    unsigned short* PeNI = (unsigned short*)alloc(16384*2);
    unsigned short* PeNH = (unsigned short*)alloc(16384*2);
    unsigned short* PnP1 = (unsigned short*)alloc(32768*2);  // Wn[0:256]    K=256 N=128
    unsigned short* PnRZ = (unsigned short*)alloc(65536*2);
    unsigned short* PnNI = (unsigned short*)alloc(16384*2);
    unsigned short* PnNH = (unsigned short*)alloc(16384*2);

    hipMemcpyAsync(ea,   ea_i, (size_t)NE*Hdim*4, hipMemcpyDeviceToDevice, stream);
    hipMemcpyAsync(xcur, x,    (size_t)NN*Hdim*4, hipMemcpyDeviceToDevice, stream);
    hipMemcpyAsync(ucur, u,    (size_t)NG*Hdim*4, hipMemcpyDeviceToDevice, stream);
    hipMemsetAsync(cnt, 0, NG*4, stream);
    count_kernel<<<(NN+255)/256, 256, 0, stream>>>(batch, cnt);

    // weight packs (constant across steps)
    auto pk = [&](const float* S0, const float* S1, int ld, int coloff,
                  int Krows0, int Ktot, int Ntot, unsigned short* dst){
        int total = Ktot*Ntot;
        pack_b<<<(total+255)/256, 256, 0, stream>>>(S0, S1, ld, coloff, Krows0, Ktot, Ntot, dst);
    };
    pk(We,            We,   Hdim, 0,   128, 128, 128, PXS);          // We1
    pk(We+128*Hdim,   We,   Hdim, 0,   128, 128, 128, PXS+16384);    // We2
    pk(We+256*Hdim,   We,   Hdim, 0,   128, 128, 128, PW1);          // We3
    pk(eWih, eWhh, 384, 0,   128, 256, 256, PeRZ);
    pk(eWih, eWih, 384, 256, 128, 128, 128, PeNI);
    pk(eWhh, eWhh, 384, 256, 128, 128, 128, PeNH);
    pk(Wn,   Wn,   Hdim, 0,  256, 256, 128, PnP1);
    pk(nWih, nWhh, 384, 0,   128, 256, 256, PnRZ);
    pk(nWih, nWih, 384, 256, 128, 128, 128, PnNI);
    pk(nWhh, nWhh, 384, 256, 128, 128, 128, PnNH);

    for (int t=0; t<3; ++t){
        xs_mfma<<<(NN+EB-1)/EB, 256, 0, stream>>>(xcur, PXS, xs12);
        graph_pre_kernel<<<1, 256, 0, stream>>>(ucur, We, be, Wn, bn, gu, nu);
        hipMemsetAsync(agg, 0, (size_t)NN*Hdim*4, stream);
        edge_mfma<<<NE/EB, 256, 0, stream>>>(ea, xs12, gu, PW1, PeRZ, PeNI, PeNH,
                                             ebih, ebhh, src, dst, batch, agg);
        hipMemsetAsync(xsum, 0, (size_t)NG*Hdim*4, stream);
        node_mfma<<<(NN+EB-1)/EB, 256, 0, stream>>>(xcur, agg, nu, PnP1, PnRZ, PnNI, PnNH,
                                                    nbih, nbhh, batch, xsum);
        global_kernel<<<1, 256, 0, stream>>>(xsum, cnt, ucur, Wg, bg,
                                             gWih, gWhh, gbih, gbhh, out, t);
    }
}

// Round 3
// 1880.832 us; speedup vs baseline: 3.0437x; 1.0813x over previous
//
#include <hip/hip_runtime.h>

#define Hdim 128
#define NN 10000
#define NE 320000
#define NG 16
#define EB 128          // rows (edges or nodes) per block
#define SXO 136         // LDS bf16 row stride

typedef __attribute__((ext_vector_type(8))) short bf8;   // 8 bf16 = 4 VGPRs
typedef __attribute__((ext_vector_type(4))) float f4;
#define MFMA16 __builtin_amdgcn_mfma_f32_16x16x32_bf16

__device__ __forceinline__ float sigm(float x){ return 1.0f/(1.0f+expf(-x)); }

__device__ __forceinline__ unsigned short f2bf(float v){
    unsigned int b = __float_as_uint(v);
    return (unsigned short)((b + 0x7FFFu + ((b>>16)&1u)) >> 16);
}
__device__ __forceinline__ float bf2f(unsigned short u){
    return __uint_as_float(((unsigned int)u)<<16);
}

// load 8 consecutive f32 from global, convert RNE -> bf16 fragment
__device__ __forceinline__ bf8 load_frag_f32(const float* __restrict__ p){
    float4 a = *(const float4*)p;
    float4 b = *(const float4*)(p+4);
    bf8 f;
    f[0]=(short)f2bf(a.x); f[1]=(short)f2bf(a.y); f[2]=(short)f2bf(a.z); f[3]=(short)f2bf(a.w);
    f[4]=(short)f2bf(b.x); f[5]=(short)f2bf(b.y); f[6]=(short)f2bf(b.z); f[7]=(short)f2bf(b.w);
    return f;
}

__device__ __forceinline__ bf8 load_pb(const unsigned short* __restrict__ P,
                                       int ntile, int ksteps, int kstep, int lane){
    return *(const bf8*)(P + ((((ntile*ksteps + kstep)<<6) + lane)<<3));
}

// ---------------------------------------------------------------- pack all B mats (1 launch)
struct PackJob { const float* s0; const float* s1; int ld, coloff, kr0, ktot, cnt, base; };
struct PackJobs { PackJob j[10]; };

__global__ __launch_bounds__(256) void pack_all(PackJobs P, unsigned short* __restrict__ dst)
{
    int idx = blockIdx.x*256 + threadIdx.x;
    #pragma unroll
    for (int t=0; t<10; ++t){
        int lo = P.j[t].base, hi = lo + P.j[t].cnt;
        if (idx >= lo && idx < hi){
            int l = idx - lo;
            int e    = l & 7;
            int lane = (l >> 3) & 63;
            int kt   = l >> 9;
            int ksteps = P.j[t].ktot >> 5;
            int ntile = kt / ksteps, kstep = kt - ntile*ksteps;
            int k = kstep*32 + ((lane>>4)<<3) + e;
            int n = ntile*16 + (lane&15);
            const float* S = (k < P.j[t].kr0) ? P.j[t].s0 : P.j[t].s1;
            int kk = (k < P.j[t].kr0) ? k : (k - P.j[t].kr0);
            dst[idx] = f2bf(S[(long)kk*P.j[t].ld + P.j[t].coloff + n]);
        }
    }
}

// ---------------------------------------------------------------- ea f32 -> bf16 state
__global__ __launch_bounds__(256) void conv_bf16(const float* __restrict__ in,
                                                 unsigned short* __restrict__ outp)
{
    long i = ((long)blockIdx.x*256 + threadIdx.x)*8;
    *(bf8*)(outp+i) = load_frag_f32(in+i);
}

// ---------------------------------------------------------------- count
__global__ void count_kernel(const int* __restrict__ batch, float* __restrict__ cnt){
    int i = blockIdx.x*256 + threadIdx.x;
    if (i < NN) atomicAdd(&cnt[batch[i]], 1.0f);
}

// ------------------------------------------- per-step graph precompute (32 blocks x 128)
// gu[g] = u[g]@We[384:512]+be ; nu[g] = u[g]@Wn[256:384]+bn ; block0 zeroes xsum
__global__ __launch_bounds__(128) void graph_pre_kernel(
    const float* __restrict__ u, const float* __restrict__ We, const float* __restrict__ be,
    const float* __restrict__ Wn, const float* __restrict__ bn,
    float* __restrict__ gu, float* __restrict__ nu, float* __restrict__ xsum)
{
    __shared__ float sU[Hdim];
    int b = blockIdx.x, which = b>>4, g = b&15, j = threadIdx.x;
    sU[j] = u[g*Hdim + j];
    if (b == 0){
        #pragma unroll
        for (int q=0;q<NG;++q) xsum[q*Hdim + j] = 0.f;
    }
    __syncthreads();
    const float* W = which ? (Wn + 256*Hdim) : (We + 384*Hdim);
    float a0 = which ? bn[j] : be[j], a1=0.f, a2=0.f, a3=0.f;
    for (int k=0;k<Hdim;k+=4){
        a0 = fmaf(sU[k+0], W[(k+0)*Hdim+j], a0);
        a1 = fmaf(sU[k+1], W[(k+1)*Hdim+j], a1);
        a2 = fmaf(sU[k+2], W[(k+2)*Hdim+j], a2);
        a3 = fmaf(sU[k+3], W[(k+3)*Hdim+j], a3);
    }
    (which ? nu : gu)[g*Hdim + j] = (a0+a1)+(a2+a3);
}

// ------------------------------------------- xs12 = x @ [We1|We2] (+gu fold), zero agg
__global__ __launch_bounds__(256,2) void xs_mfma(
    const float* __restrict__ x, const unsigned short* __restrict__ PXS,
    const float* __restrict__ gu, const int* __restrict__ batch,
    float* __restrict__ xs12, float* __restrict__ agg)
{
    int tid = threadIdx.x, lane = tid&63, wave = tid>>6;
    int nbB = blockIdx.x*EB;
    int nb = nbB + wave*32;
    // zero agg rows for this block
    {
        long base = (long)nbB*Hdim;
        #pragma unroll
        for (int q=0;q<16;++q){
            long off = base + q*1024 + tid*4;
            if ((off>>7) < NN) *(float4*)(agg+off) = make_float4(0.f,0.f,0.f,0.f);
        }
    }
    int arow = lane&15, kg = lane>>4;
    int col = lane&15, crow = kg*4;
    bf8 xF[2][4];
    #pragma unroll
    for (int m=0;m<2;++m){
        int row = nb + m*16 + arow; if (row > NN-1) row = NN-1;
        #pragma unroll
        for (int ks=0;ks<4;++ks)
            xF[m][ks] = load_frag_f32(x + (long)row*Hdim + ks*32 + kg*8);
    }
    int g0[4], g1[4];
    #pragma unroll
    for (int r=0;r<4;++r){
        int ra = nb + crow + r;      if (ra > NN-1) ra = NN-1;
        int rb = nb + 16 + crow + r; if (rb > NN-1) rb = NN-1;
        g0[r] = batch[ra]; g1[r] = batch[rb];
    }
    #pragma unroll 4
    for (int nt=0; nt<16; ++nt){
        f4 acc0 = {0.f,0.f,0.f,0.f}, acc1 = {0.f,0.f,0.f,0.f};
        #pragma unroll
        for (int ks=0;ks<4;++ks){
            bf8 b = load_pb(PXS, nt, 4, ks, lane);
            acc0 = MFMA16(xF[0][ks], b, acc0, 0,0,0);
            acc1 = MFMA16(xF[1][ks], b, acc1, 0,0,0);
        }
        #pragma unroll
        for (int r=0;r<4;++r){
            int row0 = nb + crow + r, row1 = nb + 16 + crow + r;
            float add0 = (nt<8) ? gu[g0[r]*Hdim + nt*16 + col] : 0.f;
            float add1 = (nt<8) ? gu[g1[r]*Hdim + nt*16 + col] : 0.f;
            if (row0 < NN) xs12[(long)row0*256 + nt*16 + col] = acc0[r] + add0;
            if (row1 < NN) xs12[(long)row1*256 + nt*16 + col] = acc1[r] + add1;
        }
    }
}

// ------------------------------------------- fused edge model + edge GRU (bf16 state)
__global__ __launch_bounds__(256,4) void edge_mfma(
    unsigned short* __restrict__ ea,
    const float* __restrict__ xs12,
    const unsigned short* __restrict__ PW1, const unsigned short* __restrict__ PRZ,
    const unsigned short* __restrict__ PNI, const unsigned short* __restrict__ PNH,
    const float* __restrict__ bih, const float* __restrict__ bhh,
    const int* __restrict__ srcv, const int* __restrict__ dstv,
    float* __restrict__ agg)
{
    __shared__ __align__(16) unsigned short sEo[EB*SXO];
    __shared__ int sS[EB], sD[EB];
    int tid = threadIdx.x, lane = tid&63, wave = tid>>6;
    long eb = (long)blockIdx.x*EB;
    if (tid < EB){ sS[tid] = srcv[eb+tid]; sD[tid] = dstv[eb+tid]; }
    __syncthreads();
    int r0 = wave*32;
    int arow = lane&15, kg = lane>>4;
    int col = lane&15, crow = kg*4;
    // h fragments (bf16 state, direct load)
    bf8 eaF[2][4];
    #pragma unroll
    for (int m=0;m<2;++m)
        #pragma unroll
        for (int ks=0;ks<4;++ks)
            eaF[m][ks] = *(const bf8*)(ea + (eb + r0 + m*16 + arow)*Hdim + ks*32 + kg*8);
    // phase1: eo = relu(ea@We3 + xs1g[src] + xs2[dst])   (gu+be folded into xs1g)
    #pragma unroll 2
    for (int nt=0; nt<8; ++nt){
        int j = nt*16 + col;
        f4 acc[2];
        #pragma unroll
        for (int m=0;m<2;++m)
            #pragma unroll
            for (int r=0;r<4;++r){
                int lr = r0 + m*16 + crow + r;
                acc[m][r] = xs12[(long)sS[lr]*256 + j]
                          + xs12[(long)sD[lr]*256 + 128 + j];
            }
        #pragma unroll
        for (int ks=0;ks<4;++ks){
            bf8 b = load_pb(PW1, nt, 4, ks, lane);
            acc[0] = MFMA16(eaF[0][ks], b, acc[0], 0,0,0);
            acc[1] = MFMA16(eaF[1][ks], b, acc[1], 0,0,0);
        }
        #pragma unroll
        for (int m=0;m<2;++m)
            #pragma unroll
            for (int r=0;r<4;++r){
                int lr = r0 + m*16 + crow + r;
                sEo[lr*SXO + j] = f2bf(fmaxf(acc[m][r], 0.f));
            }
    }
    // eo fragments (wave-private rows, no barrier needed)
    bf8 eoF[2][4];
    #pragma unroll
    for (int m=0;m<2;++m)
        #pragma unroll
        for (int ks=0;ks<4;++ks)
            eoF[m][ks] = *(const bf8*)(sEo + (r0 + m*16 + arow)*SXO + ks*32 + kg*8);
    // gates: rz over K=256 [eo|ea]; n_i = eo@Wni, n_h = ea@Wnh
    #pragma unroll 1
    for (int nt=0; nt<8; ++nt){
        int j = nt*16 + col;
        float vr = bih[j] + bhh[j];
        float vz = bih[128+j] + bhh[128+j];
        float vi = bih[256+j], vh = bhh[256+j];
        f4 ar[2], az[2], ai[2], ah[2];
        #pragma unroll
        for (int m=0;m<2;++m){
            ar[m] = (f4){vr,vr,vr,vr}; az[m] = (f4){vz,vz,vz,vz};
            ai[m] = (f4){vi,vi,vi,vi}; ah[m] = (f4){vh,vh,vh,vh};
        }
        #pragma unroll
        for (int ks=0;ks<8;++ks){
            bf8 A0 = (ks<4) ? eoF[0][ks] : eaF[0][ks-4];
            bf8 A1 = (ks<4) ? eoF[1][ks] : eaF[1][ks-4];
            bf8 bR = load_pb(PRZ, nt,   8, ks, lane);
            bf8 bZ = load_pb(PRZ, nt+8, 8, ks, lane);
            ar[0] = MFMA16(A0, bR, ar[0], 0,0,0);
            ar[1] = MFMA16(A1, bR, ar[1], 0,0,0);
            az[0] = MFMA16(A0, bZ, az[0], 0,0,0);
            az[1] = MFMA16(A1, bZ, az[1], 0,0,0);
        }
        #pragma unroll
        for (int ks=0;ks<4;++ks){
            bf8 bI = load_pb(PNI, nt, 4, ks, lane);
            bf8 bH = load_pb(PNH, nt, 4, ks, lane);
            ai[0] = MFMA16(eoF[0][ks], bI, ai[0], 0,0,0);
            ai[1] = MFMA16(eoF[1][ks], bI, ai[1], 0,0,0);
            ah[0] = MFMA16(eaF[0][ks], bH, ah[0], 0,0,0);
            ah[1] = MFMA16(eaF[1][ks], bH, ah[1], 0,0,0);
        }
        #pragma unroll
        for (int m=0;m<2;++m)
            #pragma unroll
            for (int r=0;r<4;++r){
                int lr = r0 + m*16 + crow + r;
                long grow = eb + lr;
                float h  = bf2f(ea[grow*Hdim + j]);
                float rr = sigm(ar[m][r]);
                float zz = sigm(az[m][r]);
                float nn = tanhf(fmaf(rr, ah[m][r], ai[m][r]));
                float o  = (1.0f - zz)*nn + zz*h;
                ea[grow*Hdim + j] = f2bf(o);
                atomicAdd(&agg[(long)sD[lr]*Hdim + j], o);
            }
    }
}

// ------------------------------------------- fused node model + node GRU (f32 state)
__global__ __launch_bounds__(256,2) void node_mfma(
    float* __restrict__ x, const float* __restrict__ agg,
    const float* __restrict__ nu,
    const unsigned short* __restrict__ PP1, const unsigned short* __restrict__ PRZ,
    const unsigned short* __restrict__ PNI, const unsigned short* __restrict__ PNH,
    const float* __restrict__ bih, const float* __restrict__ bhh,
    const int* __restrict__ batch, float* __restrict__ xsum)
{
    __shared__ __align__(16) unsigned short sXo[EB*SXO];
    __shared__ int sG[EB];
    int tid = threadIdx.x, lane = tid&63, wave = tid>>6;
    int nb = blockIdx.x*EB;
    if (tid < EB){
        int row = nb + tid; if (row > NN-1) row = NN-1;
        sG[tid] = batch[row];
    }
    __syncthreads();
    int r0 = wave*32;
    int arow = lane&15, kg = lane>>4;
    int col = lane&15, crow = kg*4;
    bf8 xF[2][4], agF[2][4];
    #pragma unroll
    for (int m=0;m<2;++m){
        int row = nb + r0 + m*16 + arow; if (row > NN-1) row = NN-1;
        #pragma unroll
        for (int ks=0;ks<4;++ks){
            xF[m][ks]  = load_frag_f32(x   + (long)row*Hdim + ks*32 + kg*8);
            agF[m][ks] = load_frag_f32(agg + (long)row*Hdim + ks*32 + kg*8);
        }
    }
    // phase1: xo = relu([x|agg]@Wn[0:256] + nu[g])
    #pragma unroll 2
    for (int nt=0; nt<8; ++nt){
        int j = nt*16 + col;
        f4 acc[2];
        #pragma unroll
        for (int m=0;m<2;++m)
            #pragma unroll
            for (int r=0;r<4;++r)
                acc[m][r] = nu[sG[r0 + m*16 + crow + r]*Hdim + j];
        #pragma unroll
        for (int ks=0;ks<8;++ks){
            bf8 A0 = (ks<4) ? xF[0][ks] : agF[0][ks-4];
            bf8 A1 = (ks<4) ? xF[1][ks] : agF[1][ks-4];
            bf8 b = load_pb(PP1, nt, 8, ks, lane);
            acc[0] = MFMA16(A0, b, acc[0], 0,0,0);
            acc[1] = MFMA16(A1, b, acc[1], 0,0,0);
        }
        #pragma unroll
        for (int m=0;m<2;++m)
            #pragma unroll
            for (int r=0;r<4;++r){
                int lr = r0 + m*16 + crow + r;
                sXo[lr*SXO + j] = f2bf(fmaxf(acc[m][r], 0.f));
            }
    }
    bf8 xoF[2][4];
    #pragma unroll
    for (int m=0;m<2;++m)
        #pragma unroll
        for (int ks=0;ks<4;++ks)
            xoF[m][ks] = *(const bf8*)(sXo + (r0 + m*16 + arow)*SXO + ks*32 + kg*8);
    #pragma unroll 1
    for (int nt=0; nt<8; ++nt){
        int j = nt*16 + col;
        float vr = bih[j] + bhh[j];
        float vz = bih[128+j] + bhh[128+j];
        float vi = bih[256+j], vh = bhh[256+j];
        f4 ar[2], az[2], ai[2], ah[2];
        #pragma unroll
        for (int m=0;m<2;++m){
            ar[m] = (f4){vr,vr,vr,vr}; az[m] = (f4){vz,vz,vz,vz};
            ai[m] = (f4){vi,vi,vi,vi}; ah[m] = (f4){vh,vh,vh,vh};
        }
        #pragma unroll
        for (int ks=0;ks<8;++ks){
            bf8 A0 = (ks<4) ? xoF[0][ks] : xF[0][ks-4];
            bf8 A1 = (ks<4) ? xoF[1][ks] : xF[1][ks-4];
            bf8 bR = load_pb(PRZ, nt,   8, ks, lane);
            bf8 bZ = load_pb(PRZ, nt+8, 8, ks, lane);
            ar[0] = MFMA16(A0, bR, ar[0], 0,0,0);
            ar[1] = MFMA16(A1, bR, ar[1], 0,0,0);
            az[0] = MFMA16(A0, bZ, az[0], 0,0,0);
            az[1] = MFMA16(A1, bZ, az[1], 0,0,0);
        }
        #pragma unroll
        for (int ks=0;ks<4;++ks){
            bf8 bI = load_pb(PNI, nt, 4, ks, lane);
            bf8 bH = load_pb(PNH, nt, 4, ks, lane);
            ai[0] = MFMA16(xoF[0][ks], bI, ai[0], 0,0,0);
            ai[1] = MFMA16(xoF[1][ks], bI, ai[1], 0,0,0);
            ah[0] = MFMA16(xF[0][ks],  bH, ah[0], 0,0,0);
            ah[1] = MFMA16(xF[1][ks],  bH, ah[1], 0,0,0);
        }
        #pragma unroll
        for (int m=0;m<2;++m)
            #pragma unroll
            for (int r=0;r<4;++r){
                int lr = r0 + m*16 + crow + r;
                int row = nb + lr;
                if (row < NN){
                    float h  = x[(long)row*Hdim + j];
                    float rr = sigm(ar[m][r]);
                    float zz = sigm(az[m][r]);
                    float nn = tanhf(fmaf(rr, ah[m][r], ai[m][r]));
                    float o  = (1.0f - zz)*nn + zz*h;
                    x[(long)row*Hdim + j] = o;
                    atomicAdd(&xsum[sG[lr]*Hdim + j], o);
                }
            }
    }
}

// ------------------------------------------- fused global model + global GRU (16 blocks)
__global__ __launch_bounds__(128) void global_kernel(
    const float* __restrict__ xsum, const float* __restrict__ cnt,
    float* __restrict__ u,
    const float* __restrict__ Wg, const float* __restrict__ bg,
    const float* __restrict__ Wih, const float* __restrict__ Whh,
    const float* __restrict__ bih, const float* __restrict__ bhh,
    float* __restrict__ out, int step)
{
    __shared__ float sXm[Hdim], sU[Hdim], sUo[Hdim];
    int g = blockIdx.x, j = threadIdx.x;
    float inv = 1.0f / fmaxf(cnt[g], 1.0f);
    sXm[j] = xsum[g*Hdim + j] * inv;
    float hj = u[g*Hdim + j];
    sU[j] = hj;
    __syncthreads();
    float a = bg[j];
    for (int k=0;k<Hdim;++k){
        a = fmaf(sXm[k], Wg[k*Hdim + j], a);
        a = fmaf(sU[k],  Wg[(128+k)*Hdim + j], a);
    }
    sUo[j] = fmaxf(a, 0.f);
    __syncthreads();
    float r = bih[j]+bhh[j], z = bih[128+j]+bhh[128+j];
    float ni = bih[256+j], nh = bhh[256+j];
    for (int k=0;k<Hdim;++k){
        float in = sUo[k], h = sU[k];
        r  = fmaf(in, Wih[k*384 + j],       r);
        r  = fmaf(h,  Whh[k*384 + j],       r);
        z  = fmaf(in, Wih[k*384 + 128 + j], z);
        z  = fmaf(h,  Whh[k*384 + 128 + j], z);
        ni = fmaf(in, Wih[k*384 + 256 + j], ni);
        nh = fmaf(h,  Whh[k*384 + 256 + j], nh);
    }
    float rr = sigm(r), zz = sigm(z);
    float n = tanhf(fmaf(rr, nh, ni));
    float o = (1.0f - zz)*n + zz*hj;
    u[g*Hdim + j] = o;
    out[(long)(g*3 + step)*Hdim + j] = o;
}

// ---------------------------------------------------------------- host
extern "C" void kernel_launch(void* const* d_in, const int* in_sizes, int n_in,
                              void* d_out, int out_size, void* d_ws, size_t ws_size,
                              hipStream_t stream)
{
    const float* x    = (const float*)d_in[0];
    const float* ea_i = (const float*)d_in[1];
    const float* u    = (const float*)d_in[2];
    const float* We   = (const float*)d_in[3];
    const float* be   = (const float*)d_in[4];
    const float* Wn   = (const float*)d_in[5];
    const float* bn   = (const float*)d_in[6];
    const float* Wg   = (const float*)d_in[7];
    const float* bg   = (const float*)d_in[8];
    const float* eWih = (const float*)d_in[9];
    const float* eWhh = (const float*)d_in[10];
    const float* ebih = (const float*)d_in[11];
    const float* ebhh = (const float*)d_in[12];
    const float* nWih = (const float*)d_in[13];
    const float* nWhh = (const float*)d_in[14];
    const float* nbih = (const float*)d_in[15];
    const float* nbhh = (const float*)d_in[16];
    const float* gWih = (const float*)d_in[17];
    const float* gWhh = (const float*)d_in[18];
    const float* gbih = (const float*)d_in[19];
    const float* gbhh = (const float*)d_in[20];
    const int*   ei   = (const int*)d_in[21];
    const int*   batch= (const int*)d_in[22];
    const int* src = ei;
    const int* dst = ei + NE;
    float* out = (float*)d_out;

    size_t off = 0;
    auto alloc = [&](size_t bytes)->char*{
        char* p = (char*)d_ws + off;
        off += (bytes + 255) & ~(size_t)255;
        return p;
    };
    unsigned short* ea = (unsigned short*)alloc((size_t)NE*Hdim*2);   // bf16 state
    float* xcur = (float*)alloc((size_t)NN*Hdim*4);
    float* xs12 = (float*)alloc((size_t)NN*256*4);
    float* agg  = (float*)alloc((size_t)NN*Hdim*4);
    float* ucur = (float*)alloc((size_t)NG*Hdim*4);
    float* gu   = (float*)alloc((size_t)NG*Hdim*4);
    float* nu   = (float*)alloc((size_t)NG*Hdim*4);
    float* xsum = (float*)alloc((size_t)NG*Hdim*4);
    float* cnt  = (float*)alloc((size_t)NG*4);
    unsigned short* PK = (unsigned short*)alloc((size_t)278528*2);

    // pack layout (element offsets into PK)
    unsigned short* PXS  = PK + 0;        // We1|We2  (2 jobs)
    unsigned short* PW1  = PK + 32768;    // We3
    unsigned short* PeRZ = PK + 49152;
    unsigned short* PeNI = PK + 114688;
    unsigned short* PeNH = PK + 131072;
    unsigned short* PnP1 = PK + 147456;
    unsigned short* PnRZ = PK + 180224;
    unsigned short* PnNI = PK + 245760;
    unsigned short* PnNH = PK + 262144;

    conv_bf16<<<NE*Hdim/8/256, 256, 0, stream>>>(ea_i, ea);
    hipMemcpyAsync(xcur, x, (size_t)NN*Hdim*4, hipMemcpyDeviceToDevice, stream);
    hipMemcpyAsync(ucur, u, (size_t)NG*Hdim*4, hipMemcpyDeviceToDevice, stream);
    hipMemsetAsync(cnt, 0, NG*4, stream);
    count_kernel<<<(NN+255)/256, 256, 0, stream>>>(batch, cnt);

    PackJobs PJ;
    auto setj = [&](int t, const float* s0, const float* s1, int ld, int coloff,
                    int kr0, int ktot, int ntot, int base){
        PJ.j[t] = PackJob{ s0, s1, ld, coloff, kr0, ktot, ktot*ntot, base };
    };
    setj(0, We,            We,   Hdim, 0,   128, 128, 128, 0);
    setj(1, We+128*Hdim,   We,   Hdim, 0,   128, 128, 128, 16384);
    setj(2, We+256*Hdim,   We,   Hdim, 0,   128, 128, 128, 32768);
    setj(3, eWih, eWhh, 384, 0,   128, 256, 256, 49152);
    setj(4, eWih, eWih, 384, 256, 128, 128, 128, 114688);
    setj(5, eWhh, eWhh, 384, 256, 128, 128, 128, 131072);
    setj(6, Wn,   Wn,   Hdim, 0,  256, 256, 128, 147456);
    setj(7, nWih, nWhh, 384, 0,   128, 256, 256, 180224);
    setj(8, nWih, nWih, 384, 256, 128, 128, 128, 245760);
    setj(9, nWhh, nWhh, 384, 256, 128, 128, 128, 262144);
    pack_all<<<278528/256, 256, 0, stream>>>(PJ, PK);

    for (int t=0; t<3; ++t){
        graph_pre_kernel<<<32, 128, 0, stream>>>(ucur, We, be, Wn, bn, gu, nu, xsum);
        xs_mfma<<<(NN+EB-1)/EB, 256, 0, stream>>>(xcur, PXS, gu, batch, xs12, agg);
        edge_mfma<<<NE/EB, 256, 0, stream>>>(ea, xs12, PW1, PeRZ, PeNI, PeNH,
                                             ebih, ebhh, src, dst, agg);
        node_mfma<<<(NN+EB-1)/EB, 256, 0, stream>>>(xcur, agg, nu, PnP1, PnRZ, PnNI, PnNH,
                                                    nbih, nbhh, batch, xsum);
        global_kernel<<<NG, 128, 0, stream>>>(xsum, cnt, ucur, Wg, bg,
                                              gWih, gWhh, gbih, gbhh, out, t);
    }
}

// Round 4
// 1685.392 us; speedup vs baseline: 3.3967x; 1.1160x over previous
//
#include <hip/hip_runtime.h>

#define Hdim 128
#define NN 10000
#define NE 320000
#define NG 16
#define EB 128          // rows (edges or nodes) per block
#define SXO 136         // LDS bf16 row stride

typedef __attribute__((ext_vector_type(8))) short bf8;   // 8 bf16 = 4 VGPRs
typedef __attribute__((ext_vector_type(4))) float f4;
#define MFMA16 __builtin_amdgcn_mfma_f32_16x16x32_bf16

__device__ __forceinline__ float sigm(float x){ return 1.0f/(1.0f+expf(-x)); }

__device__ __forceinline__ unsigned short f2bf(float v){
    unsigned int b = __float_as_uint(v);
    return (unsigned short)((b + 0x7FFFu + ((b>>16)&1u)) >> 16);
}
__device__ __forceinline__ float bf2f(unsigned short u){
    return __uint_as_float(((unsigned int)u)<<16);
}

__device__ __forceinline__ bf8 load_frag_f32(const float* __restrict__ p){
    float4 a = *(const float4*)p;
    float4 b = *(const float4*)(p+4);
    bf8 f;
    f[0]=(short)f2bf(a.x); f[1]=(short)f2bf(a.y); f[2]=(short)f2bf(a.z); f[3]=(short)f2bf(a.w);
    f[4]=(short)f2bf(b.x); f[5]=(short)f2bf(b.y); f[6]=(short)f2bf(b.z); f[7]=(short)f2bf(b.w);
    return f;
}

__device__ __forceinline__ bf8 load_pb(const unsigned short* __restrict__ P,
                                       int ntile, int ksteps, int kstep, int lane){
    return *(const bf8*)(P + ((((ntile*ksteps + kstep)<<6) + lane)<<3));
}

// ---------------------------------------------------------------- pack all B mats
struct PackJob { const float* s0; const float* s1; int ld, coloff, kr0, ktot, cnt, base; };
struct PackJobs { PackJob j[10]; };

__global__ __launch_bounds__(256) void pack_all(PackJobs P, unsigned short* __restrict__ dst)
{
    int idx = blockIdx.x*256 + threadIdx.x;
    #pragma unroll
    for (int t=0; t<10; ++t){
        int lo = P.j[t].base, hi = lo + P.j[t].cnt;
        if (idx >= lo && idx < hi){
            int l = idx - lo;
            int e    = l & 7;
            int lane = (l >> 3) & 63;
            int kt   = l >> 9;
            int ksteps = P.j[t].ktot >> 5;
            int ntile = kt / ksteps, kstep = kt - ntile*ksteps;
            int k = kstep*32 + ((lane>>4)<<3) + e;
            int n = ntile*16 + (lane&15);
            const float* S = (k < P.j[t].kr0) ? P.j[t].s0 : P.j[t].s1;
            int kk = (k < P.j[t].kr0) ? k : (k - P.j[t].kr0);
            dst[idx] = f2bf(S[(long)kk*P.j[t].ld + P.j[t].coloff + n]);
        }
    }
}

// ---------------------------------------------------------------- edge sort by dst
__global__ void hist_kernel(const int* __restrict__ dst, int* __restrict__ histo){
    int e = blockIdx.x*256 + threadIdx.x;
    if (e < NE) atomicAdd(&histo[dst[e]], 1);
}

__global__ __launch_bounds__(256) void scan_kernel(const int* __restrict__ histo,
                                                   int* __restrict__ cursor){
    __shared__ int ls[256];
    int t = threadIdx.x;
    int s = 0;
    #pragma unroll 8
    for (int i=0;i<40;++i){ int idx = t*40+i; if (idx < NN) s += histo[idx]; }
    ls[t] = s; __syncthreads();
    for (int off=1; off<256; off<<=1){
        int v = ls[t];
        if (t >= off) v += ls[t-off];
        __syncthreads();
        ls[t] = v; __syncthreads();
    }
    int run = ls[t] - s;   // exclusive base
    for (int i=0;i<40;++i){
        int idx = t*40+i;
        if (idx < NN){ cursor[idx] = run; run += histo[idx]; }
    }
}

__global__ void scatter_kernel(const int* __restrict__ src, const int* __restrict__ dst,
                               int* __restrict__ cursor,
                               int* __restrict__ ssrc, int* __restrict__ sdst,
                               int* __restrict__ perm){
    int e = blockIdx.x*256 + threadIdx.x;
    if (e < NE){
        int d = dst[e];
        int p = atomicAdd(&cursor[d], 1);
        ssrc[p] = src[e]; sdst[p] = d; perm[p] = e;
    }
}

// ea_sorted[p] = bf16(ea_in[perm[p]])
__global__ __launch_bounds__(256) void conv_perm(const float* __restrict__ in,
                                                 const int* __restrict__ perm,
                                                 unsigned short* __restrict__ outp){
    long i = (long)blockIdx.x*256 + threadIdx.x;   // i indexes 8-elem groups, total NE*16
    long row = i >> 4; int c8 = (int)(i & 15);
    long srow = perm[row];
    *(bf8*)(outp + row*Hdim + c8*8) = load_frag_f32(in + srow*Hdim + c8*8);
}

// ---------------------------------------------------------------- count
__global__ void count_kernel(const int* __restrict__ batch, float* __restrict__ cnt){
    int i = blockIdx.x*256 + threadIdx.x;
    if (i < NN) atomicAdd(&cnt[batch[i]], 1.0f);
}

// ------------------------------------------- initial graph precompute (t=0 only)
__global__ __launch_bounds__(128) void graph_pre_kernel(
    const float* __restrict__ u, const float* __restrict__ We, const float* __restrict__ be,
    const float* __restrict__ Wn, const float* __restrict__ bn,
    float* __restrict__ gu, float* __restrict__ nu, float* __restrict__ xsum)
{
    __shared__ float sU[Hdim];
    int b = blockIdx.x, which = b>>4, g = b&15, j = threadIdx.x;
    sU[j] = u[g*Hdim + j];
    if (b == 0){
        #pragma unroll
        for (int q=0;q<NG;++q) xsum[q*Hdim + j] = 0.f;
    }
    __syncthreads();
    const float* W = which ? (Wn + 256*Hdim) : (We + 384*Hdim);
    float a0 = which ? bn[j] : be[j], a1=0.f, a2=0.f, a3=0.f;
    for (int k=0;k<Hdim;k+=4){
        a0 = fmaf(sU[k+0], W[(k+0)*Hdim+j], a0);
        a1 = fmaf(sU[k+1], W[(k+1)*Hdim+j], a1);
        a2 = fmaf(sU[k+2], W[(k+2)*Hdim+j], a2);
        a3 = fmaf(sU[k+3], W[(k+3)*Hdim+j], a3);
    }
    (which ? nu : gu)[g*Hdim + j] = (a0+a1)+(a2+a3);
}

// ------------------------------------------- xs12 (bf16) = x @ [We1|We2] (+gu fold), zero agg
__global__ __launch_bounds__(256,2) void xs_mfma(
    const float* __restrict__ x, const unsigned short* __restrict__ PXS,
    const float* __restrict__ gu, const int* __restrict__ batch,
    unsigned short* __restrict__ xs12, float* __restrict__ agg)
{
    int tid = threadIdx.x, lane = tid&63, wave = tid>>6;
    int nbB = blockIdx.x*EB;
    int nb = nbB + wave*32;
    {
        long base = (long)nbB*Hdim;
        #pragma unroll
        for (int q=0;q<16;++q){
            long off = base + q*1024 + tid*4;
            if ((off>>7) < NN) *(float4*)(agg+off) = make_float4(0.f,0.f,0.f,0.f);
        }
    }
    int arow = lane&15, kg = lane>>4;
    int col = lane&15, crow = kg*4;
    bf8 xF[2][4];
    #pragma unroll
    for (int m=0;m<2;++m){
        int row = nb + m*16 + arow; if (row > NN-1) row = NN-1;
        #pragma unroll
        for (int ks=0;ks<4;++ks)
            xF[m][ks] = load_frag_f32(x + (long)row*Hdim + ks*32 + kg*8);
    }
    int g0[4], g1[4];
    #pragma unroll
    for (int r=0;r<4;++r){
        int ra = nb + crow + r;      if (ra > NN-1) ra = NN-1;
        int rb = nb + 16 + crow + r; if (rb > NN-1) rb = NN-1;
        g0[r] = batch[ra]; g1[r] = batch[rb];
    }
    #pragma unroll 4
    for (int nt=0; nt<16; ++nt){
        f4 acc0 = {0.f,0.f,0.f,0.f}, acc1 = {0.f,0.f,0.f,0.f};
        #pragma unroll
        for (int ks=0;ks<4;++ks){
            bf8 b = load_pb(PXS, nt, 4, ks, lane);
            acc0 = MFMA16(xF[0][ks], b, acc0, 0,0,0);
            acc1 = MFMA16(xF[1][ks], b, acc1, 0,0,0);
        }
        #pragma unroll
        for (int r=0;r<4;++r){
            int row0 = nb + crow + r, row1 = nb + 16 + crow + r;
            float add0 = (nt<8) ? gu[g0[r]*Hdim + nt*16 + col] : 0.f;
            float add1 = (nt<8) ? gu[g1[r]*Hdim + nt*16 + col] : 0.f;
            if (row0 < NN) xs12[(long)row0*256 + nt*16 + col] = f2bf(acc0[r] + add0);
            if (row1 < NN) xs12[(long)row1*256 + nt*16 + col] = f2bf(acc1[r] + add1);
        }
    }
}

// ------------------------------------------- fused edge model + edge GRU (dst-sorted)
__global__ __launch_bounds__(256,4) void edge_mfma(
    unsigned short* __restrict__ ea,
    const unsigned short* __restrict__ xs12,
    const unsigned short* __restrict__ PW1, const unsigned short* __restrict__ PRZ,
    const unsigned short* __restrict__ PNI, const unsigned short* __restrict__ PNH,
    const float* __restrict__ bih, const float* __restrict__ bhh,
    const int* __restrict__ ssrc, const int* __restrict__ sdst,
    float* __restrict__ agg)
{
    __shared__ __align__(16) unsigned short sEo[EB*SXO];   // phase1: eo; later: o for agg
    __shared__ int sS[EB], sD[EB];
    int tid = threadIdx.x, lane = tid&63, wave = tid>>6;
    long eb = (long)blockIdx.x*EB;
    if (tid < EB){ sS[tid] = ssrc[eb+tid]; sD[tid] = sdst[eb+tid]; }
    __syncthreads();
    int r0 = wave*32;
    int arow = lane&15, kg = lane>>4;
    int col = lane&15, crow = kg*4;
    bf8 eaF[2][4];
    #pragma unroll
    for (int m=0;m<2;++m)
        #pragma unroll
        for (int ks=0;ks<4;++ks)
            eaF[m][ks] = *(const bf8*)(ea + (eb + r0 + m*16 + arow)*Hdim + ks*32 + kg*8);
    // phase1: eo = relu(ea@We3 + xs1g[src] + xs2[dst])
    #pragma unroll 2
    for (int nt=0; nt<8; ++nt){
        int j = nt*16 + col;
        f4 acc[2];
        #pragma unroll
        for (int m=0;m<2;++m)
            #pragma unroll
            for (int r=0;r<4;++r){
                int lr = r0 + m*16 + crow + r;
                acc[m][r] = bf2f(xs12[(long)sS[lr]*256 + j])
                          + bf2f(xs12[(long)sD[lr]*256 + 128 + j]);
            }
        #pragma unroll
        for (int ks=0;ks<4;++ks){
            bf8 b = load_pb(PW1, nt, 4, ks, lane);
            acc[0] = MFMA16(eaF[0][ks], b, acc[0], 0,0,0);
            acc[1] = MFMA16(eaF[1][ks], b, acc[1], 0,0,0);
        }
        #pragma unroll
        for (int m=0;m<2;++m)
            #pragma unroll
            for (int r=0;r<4;++r){
                int lr = r0 + m*16 + crow + r;
                sEo[lr*SXO + j] = f2bf(fmaxf(acc[m][r], 0.f));
            }
    }
    bf8 eoF[2][4];
    #pragma unroll
    for (int m=0;m<2;++m)
        #pragma unroll
        for (int ks=0;ks<4;++ks)
            eoF[m][ks] = *(const bf8*)(sEo + (r0 + m*16 + arow)*SXO + ks*32 + kg*8);
    // gates; write new state + stash o (bf16) back into sEo for segmented aggregation
    #pragma unroll 1
    for (int nt=0; nt<8; ++nt){
        int j = nt*16 + col;
        float vr = bih[j] + bhh[j];
        float vz = bih[128+j] + bhh[128+j];
        float vi = bih[256+j], vh = bhh[256+j];
        f4 ar[2], az[2], ai[2], ah[2];
        #pragma unroll
        for (int m=0;m<2;++m){
            ar[m] = (f4){vr,vr,vr,vr}; az[m] = (f4){vz,vz,vz,vz};
            ai[m] = (f4){vi,vi,vi,vi}; ah[m] = (f4){vh,vh,vh,vh};
        }
        #pragma unroll
        for (int ks=0;ks<8;++ks){
            bf8 A0 = (ks<4) ? eoF[0][ks] : eaF[0][ks-4];
            bf8 A1 = (ks<4) ? eoF[1][ks] : eaF[1][ks-4];
            bf8 bR = load_pb(PRZ, nt,   8, ks, lane);
            bf8 bZ = load_pb(PRZ, nt+8, 8, ks, lane);
            ar[0] = MFMA16(A0, bR, ar[0], 0,0,0);
            ar[1] = MFMA16(A1, bR, ar[1], 0,0,0);
            az[0] = MFMA16(A0, bZ, az[0], 0,0,0);
            az[1] = MFMA16(A1, bZ, az[1], 0,0,0);
        }
        #pragma unroll
        for (int ks=0;ks<4;++ks){
            bf8 bI = load_pb(PNI, nt, 4, ks, lane);
            bf8 bH = load_pb(PNH, nt, 4, ks, lane);
            ai[0] = MFMA16(eoF[0][ks], bI, ai[0], 0,0,0);
            ai[1] = MFMA16(eoF[1][ks], bI, ai[1], 0,0,0);
            ah[0] = MFMA16(eaF[0][ks], bH, ah[0], 0,0,0);
            ah[1] = MFMA16(eaF[1][ks], bH, ah[1], 0,0,0);
        }
        #pragma unroll
        for (int m=0;m<2;++m)
            #pragma unroll
            for (int r=0;r<4;++r){
                int lr = r0 + m*16 + crow + r;
                long grow = eb + lr;
                float h  = bf2f(ea[grow*Hdim + j]);
                float rr = sigm(ar[m][r]);
                float zz = sigm(az[m][r]);
                float nn = tanhf(fmaf(rr, ah[m][r], ai[m][r]));
                float o  = (1.0f - zz)*nn + zz*h;
                unsigned short ob = f2bf(o);
                ea[grow*Hdim + j] = ob;
                sEo[lr*SXO + j] = ob;
            }
    }
    __syncthreads();
    // segmented column-sum over sorted dst runs: ~few atomics per column per block
    {
        int j = tid & 127;
        int half = tid >> 7;
        int lo = half*64, hi = lo + 64;
        float acc = 0.f;
        for (int row=lo; row<hi; ++row){
            acc += bf2f(sEo[row*SXO + j]);
            bool flush = (row == hi-1) || (sD[row] != sD[row+1]);
            if (flush){
                atomicAdd(&agg[(long)sD[row]*Hdim + j], acc);
                acc = 0.f;
            }
        }
    }
}

// ------------------------------------------- fused node model + node GRU (f32 state)
__global__ __launch_bounds__(256,2) void node_mfma(
    float* __restrict__ x, const float* __restrict__ agg,
    const float* __restrict__ nu,
    const unsigned short* __restrict__ PP1, const unsigned short* __restrict__ PRZ,
    const unsigned short* __restrict__ PNI, const unsigned short* __restrict__ PNH,
    const float* __restrict__ bih, const float* __restrict__ bhh,
    const int* __restrict__ batch, float* __restrict__ xsum)
{
    __shared__ __align__(16) unsigned short sXo[EB*SXO];
    __shared__ int sG[EB];
    int tid = threadIdx.x, lane = tid&63, wave = tid>>6;
    int nb = blockIdx.x*EB;
    if (tid < EB){
        int row = nb + tid; if (row > NN-1) row = NN-1;
        sG[tid] = batch[row];
    }
    __syncthreads();
    int r0 = wave*32;
    int arow = lane&15, kg = lane>>4;
    int col = lane&15, crow = kg*4;
    bf8 xF[2][4], agF[2][4];
    #pragma unroll
    for (int m=0;m<2;++m){
        int row = nb + r0 + m*16 + arow; if (row > NN-1) row = NN-1;
        #pragma unroll
        for (int ks=0;ks<4;++ks){
            xF[m][ks]  = load_frag_f32(x   + (long)row*Hdim + ks*32 + kg*8);
            agF[m][ks] = load_frag_f32(agg + (long)row*Hdim + ks*32 + kg*8);
        }
    }
    #pragma unroll 2
    for (int nt=0; nt<8; ++nt){
        int j = nt*16 + col;
        f4 acc[2];
        #pragma unroll
        for (int m=0;m<2;++m)
            #pragma unroll
            for (int r=0;r<4;++r)
                acc[m][r] = nu[sG[r0 + m*16 + crow + r]*Hdim + j];
        #pragma unroll
        for (int ks=0;ks<8;++ks){
            bf8 A0 = (ks<4) ? xF[0][ks] : agF[0][ks-4];
            bf8 A1 = (ks<4) ? xF[1][ks] : agF[1][ks-4];
            bf8 b = load_pb(PP1, nt, 8, ks, lane);
            acc[0] = MFMA16(A0, b, acc[0], 0,0,0);
            acc[1] = MFMA16(A1, b, acc[1], 0,0,0);
        }
        #pragma unroll
        for (int m=0;m<2;++m)
            #pragma unroll
            for (int r=0;r<4;++r){
                int lr = r0 + m*16 + crow + r;
                sXo[lr*SXO + j] = f2bf(fmaxf(acc[m][r], 0.f));
            }
    }
    bf8 xoF[2][4];
    #pragma unroll
    for (int m=0;m<2;++m)
        #pragma unroll
        for (int ks=0;ks<4;++ks)
            xoF[m][ks] = *(const bf8*)(sXo + (r0 + m*16 + arow)*SXO + ks*32 + kg*8);
    #pragma unroll 1
    for (int nt=0; nt<8; ++nt){
        int j = nt*16 + col;
        float vr = bih[j] + bhh[j];
        float vz = bih[128+j] + bhh[128+j];
        float vi = bih[256+j], vh = bhh[256+j];
        f4 ar[2], az[2], ai[2], ah[2];
        #pragma unroll
        for (int m=0;m<2;++m){
            ar[m] = (f4){vr,vr,vr,vr}; az[m] = (f4){vz,vz,vz,vz};
            ai[m] = (f4){vi,vi,vi,vi}; ah[m] = (f4){vh,vh,vh,vh};
        }
        #pragma unroll
        for (int ks=0;ks<8;++ks){
            bf8 A0 = (ks<4) ? xoF[0][ks] : xF[0][ks-4];
            bf8 A1 = (ks<4) ? xoF[1][ks] : xF[1][ks-4];
            bf8 bR = load_pb(PRZ, nt,   8, ks, lane);
            bf8 bZ = load_pb(PRZ, nt+8, 8, ks, lane);
            ar[0] = MFMA16(A0, bR, ar[0], 0,0,0);
            ar[1] = MFMA16(A1, bR, ar[1], 0,0,0);
            az[0] = MFMA16(A0, bZ, az[0], 0,0,0);
            az[1] = MFMA16(A1, bZ, az[1], 0,0,0);
        }
        #pragma unroll
        for (int ks=0;ks<4;++ks){
            bf8 bI = load_pb(PNI, nt, 4, ks, lane);
            bf8 bH = load_pb(PNH, nt, 4, ks, lane);
            ai[0] = MFMA16(xoF[0][ks], bI, ai[0], 0,0,0);
            ai[1] = MFMA16(xoF[1][ks], bI, ai[1], 0,0,0);
            ah[0] = MFMA16(xF[0][ks],  bH, ah[0], 0,0,0);
            ah[1] = MFMA16(xF[1][ks],  bH, ah[1], 0,0,0);
        }
        #pragma unroll
        for (int m=0;m<2;++m)
            #pragma unroll
            for (int r=0;r<4;++r){
                int lr = r0 + m*16 + crow + r;
                int row = nb + lr;
                if (row < NN){
                    float h  = x[(long)row*Hdim + j];
                    float rr = sigm(ar[m][r]);
                    float zz = sigm(az[m][r]);
                    float nn = tanhf(fmaf(rr, ah[m][r], ai[m][r]));
                    float o  = (1.0f - zz)*nn + zz*h;
                    x[(long)row*Hdim + j] = o;
                    atomicAdd(&xsum[sG[lr]*Hdim + j], o);
                }
            }
    }
}

// ------------------------------------------- global model + GRU + NEXT-step gu/nu
__global__ __launch_bounds__(128) void global_kernel(
    float* __restrict__ xsum, const float* __restrict__ cnt,
    float* __restrict__ u,
    const float* __restrict__ Wg, const float* __restrict__ bg,
    const float* __restrict__ Wih, const float* __restrict__ Whh,
    const float* __restrict__ bih, const float* __restrict__ bhh,
    const float* __restrict__ We, const float* __restrict__ be,
    const float* __restrict__ Wn, const float* __restrict__ bn,
    float* __restrict__ gu, float* __restrict__ nu,
    float* __restrict__ out, int step)
{
    __shared__ float sXm[Hdim], sU[Hdim], sUo[Hdim], sO[Hdim];
    int g = blockIdx.x, j = threadIdx.x;
    float inv = 1.0f / fmaxf(cnt[g], 1.0f);
    sXm[j] = xsum[g*Hdim + j] * inv;
    xsum[g*Hdim + j] = 0.f;            // re-zero for next step
    float hj = u[g*Hdim + j];
    sU[j] = hj;
    __syncthreads();
    float a = bg[j];
    for (int k=0;k<Hdim;++k){
        a = fmaf(sXm[k], Wg[k*Hdim + j], a);
        a = fmaf(sU[k],  Wg[(128+k)*Hdim + j], a);
    }
    sUo[j] = fmaxf(a, 0.f);
    __syncthreads();
    float r = bih[j]+bhh[j], z = bih[128+j]+bhh[128+j];
    float ni = bih[256+j], nh = bhh[256+j];
    for (int k=0;k<Hdim;++k){
        float in = sUo[k], h = sU[k];
        r  = fmaf(in, Wih[k*384 + j],       r);
        r  = fmaf(h,  Whh[k*384 + j],       r);
        z  = fmaf(in, Wih[k*384 + 128 + j], z);
        z  = fmaf(h,  Whh[k*384 + 128 + j], z);
        ni = fmaf(in, Wih[k*384 + 256 + j], ni);
        nh = fmaf(h,  Whh[k*384 + 256 + j], nh);
    }
    float rr = sigm(r), zz = sigm(z);
    float n = tanhf(fmaf(rr, nh, ni));
    float o = (1.0f - zz)*n + zz*hj;
    u[g*Hdim + j] = o;
    out[(long)(g*3 + step)*Hdim + j] = o;
    sO[j] = o;
    __syncthreads();
    // next-step gu/nu from the new u
    float a0 = be[j], a1 = bn[j];
    for (int k=0;k<Hdim;++k){
        float v = sO[k];
        a0 = fmaf(v, We[(384+k)*Hdim + j], a0);
        a1 = fmaf(v, Wn[(256+k)*Hdim + j], a1);
    }
    gu[g*Hdim + j] = a0;
    nu[g*Hdim + j] = a1;
}

// ---------------------------------------------------------------- host
extern "C" void kernel_launch(void* const* d_in, const int* in_sizes, int n_in,
                              void* d_out, int out_size, void* d_ws, size_t ws_size,
                              hipStream_t stream)
{
    const float* x    = (const float*)d_in[0];
    const float* ea_i = (const float*)d_in[1];
    const float* u    = (const float*)d_in[2];
    const float* We   = (const float*)d_in[3];
    const float* be   = (const float*)d_in[4];
    const float* Wn   = (const float*)d_in[5];
    const float* bn   = (const float*)d_in[6];
    const float* Wg   = (const float*)d_in[7];
    const float* bg   = (const float*)d_in[8];
    const float* eWih = (const float*)d_in[9];
    const float* eWhh = (const float*)d_in[10];
    const float* ebih = (const float*)d_in[11];
    const float* ebhh = (const float*)d_in[12];
    const float* nWih = (const float*)d_in[13];
    const float* nWhh = (const float*)d_in[14];
    const float* nbih = (const float*)d_in[15];
    const float* nbhh = (const float*)d_in[16];
    const float* gWih = (const float*)d_in[17];
    const float* gWhh = (const float*)d_in[18];
    const float* gbih = (const float*)d_in[19];
    const float* gbhh = (const float*)d_in[20];
    const int*   ei   = (const int*)d_in[21];
    const int*   batch= (const int*)d_in[22];
    const int* src = ei;
    const int* dst = ei + NE;
    float* out = (float*)d_out;

    size_t off = 0;
    auto alloc = [&](size_t bytes)->char*{
        char* p = (char*)d_ws + off;
        off += (bytes + 255) & ~(size_t)255;
        return p;
    };
    unsigned short* ea   = (unsigned short*)alloc((size_t)NE*Hdim*2);
    float*          xcur = (float*)alloc((size_t)NN*Hdim*4);
    unsigned short* xs12 = (unsigned short*)alloc((size_t)NN*256*2);
    float*          agg  = (float*)alloc((size_t)NN*Hdim*4);
    float*          ucur = (float*)alloc((size_t)NG*Hdim*4);
    float*          gu   = (float*)alloc((size_t)NG*Hdim*4);
    float*          nu   = (float*)alloc((size_t)NG*Hdim*4);
    float*          xsum = (float*)alloc((size_t)NG*Hdim*4);
    float*          cnt  = (float*)alloc((size_t)NG*4);
    unsigned short* PK   = (unsigned short*)alloc((size_t)278528*2);
    int* histo  = (int*)alloc((size_t)NN*4);
    int* cursor = (int*)alloc((size_t)NN*4);
    int* ssrc   = (int*)alloc((size_t)NE*4);
    int* sdst   = (int*)alloc((size_t)NE*4);
    int* perm   = (int*)alloc((size_t)NE*4);

    unsigned short* PXS  = PK + 0;
    unsigned short* PW1  = PK + 32768;
    unsigned short* PeRZ = PK + 49152;
    unsigned short* PeNI = PK + 114688;
    unsigned short* PeNH = PK + 131072;
    unsigned short* PnP1 = PK + 147456;
    unsigned short* PnRZ = PK + 180224;
    unsigned short* PnNI = PK + 245760;
    unsigned short* PnNH = PK + 262144;

    // one-time: sort edges by dst, permuted bf16 edge state
    hipMemsetAsync(histo, 0, (size_t)NN*4, stream);
    hist_kernel<<<(NE+255)/256, 256, 0, stream>>>(dst, histo);
    scan_kernel<<<1, 256, 0, stream>>>(histo, cursor);
    scatter_kernel<<<(NE+255)/256, 256, 0, stream>>>(src, dst, cursor, ssrc, sdst, perm);
    conv_perm<<<NE*16/256, 256, 0, stream>>>(ea_i, perm, ea);

    hipMemcpyAsync(xcur, x, (size_t)NN*Hdim*4, hipMemcpyDeviceToDevice, stream);
    hipMemcpyAsync(ucur, u, (size_t)NG*Hdim*4, hipMemcpyDeviceToDevice, stream);
    hipMemsetAsync(cnt, 0, NG*4, stream);
    count_kernel<<<(NN+255)/256, 256, 0, stream>>>(batch, cnt);

    PackJobs PJ;
    auto setj = [&](int t, const float* s0, const float* s1, int ld, int coloff,
                    int kr0, int ktot, int ntot, int base){
        PJ.j[t] = PackJob{ s0, s1, ld, coloff, kr0, ktot, ktot*ntot, base };
    };
    setj(0, We,            We,   Hdim, 0,   128, 128, 128, 0);
    setj(1, We+128*Hdim,   We,   Hdim, 0,   128, 128, 128, 16384);
    setj(2, We+256*Hdim,   We,   Hdim, 0,   128, 128, 128, 32768);
    setj(3, eWih, eWhh, 384, 0,   128, 256, 256, 49152);
    setj(4, eWih, eWih, 384, 256, 128, 128, 128, 114688);
    setj(5, eWhh, eWhh, 384, 256, 128, 128, 128, 131072);
    setj(6, Wn,   Wn,   Hdim, 0,  256, 256, 128, 147456);
    setj(7, nWih, nWhh, 384, 0,   128, 256, 256, 180224);
    setj(8, nWih, nWih, 384, 256, 128, 128, 128, 245760);
    setj(9, nWhh, nWhh, 384, 256, 128, 128, 128, 262144);
    pack_all<<<278528/256, 256, 0, stream>>>(PJ, PK);

    graph_pre_kernel<<<32, 128, 0, stream>>>(ucur, We, be, Wn, bn, gu, nu, xsum);

    for (int t=0; t<3; ++t){
        xs_mfma<<<(NN+EB-1)/EB, 256, 0, stream>>>(xcur, PXS, gu, batch, xs12, agg);
        edge_mfma<<<NE/EB, 256, 0, stream>>>(ea, xs12, PW1, PeRZ, PeNI, PeNH,
                                             ebih, ebhh, ssrc, sdst, agg);
        node_mfma<<<(NN+EB-1)/EB, 256, 0, stream>>>(xcur, agg, nu, PnP1, PnRZ, PnNI, PnNH,
                                                    nbih, nbhh, batch, xsum);
        global_kernel<<<NG, 128, 0, stream>>>(xsum, cnt, ucur, Wg, bg,
                                              gWih, gWhh, gbih, gbhh,
                                              We, be, Wn, bn, gu, nu, out, t);
    }
}

// Round 5
// 1145.522 us; speedup vs baseline: 4.9975x; 1.4713x over previous
//
#include <hip/hip_runtime.h>

#define Hdim 128
#define NN 10000
#define NE 320000
#define NG 16
#define EB 128          // edge rows per block
#define NB 64           // node rows per block
#define SXO 136         // LDS bf16 row stride

typedef __attribute__((ext_vector_type(8))) short bf8;   // 8 bf16 = 4 VGPRs
typedef __attribute__((ext_vector_type(4))) float f4;
#define MFMA16 __builtin_amdgcn_mfma_f32_16x16x32_bf16

#if __has_builtin(__builtin_amdgcn_exp2f)
#define EXP2F(x) __builtin_amdgcn_exp2f(x)
#else
#define EXP2F(x) exp2f(x)
#endif
#if __has_builtin(__builtin_amdgcn_rcpf)
#define RCPF(x) __builtin_amdgcn_rcpf(x)
#else
#define RCPF(x) (1.0f/(x))
#endif

__device__ __forceinline__ float fsigm(float x){
    return RCPF(1.0f + EXP2F(-1.442695041f*x));
}
__device__ __forceinline__ float ftanh(float x){
    float t = EXP2F(2.885390082f*x);          // e^(2x)
    return 1.0f - 2.0f*RCPF(t + 1.0f);        // (t-1)/(t+1)
}

__device__ __forceinline__ unsigned short f2bf(float v){
    unsigned int b = __float_as_uint(v);
    return (unsigned short)((b + 0x7FFFu + ((b>>16)&1u)) >> 16);
}
__device__ __forceinline__ float bf2f(unsigned short u){
    return __uint_as_float(((unsigned int)u)<<16);
}

__device__ __forceinline__ bf8 load_frag_f32(const float* __restrict__ p){
    float4 a = *(const float4*)p;
    float4 b = *(const float4*)(p+4);
    bf8 f;
    f[0]=(short)f2bf(a.x); f[1]=(short)f2bf(a.y); f[2]=(short)f2bf(a.z); f[3]=(short)f2bf(a.w);
    f[4]=(short)f2bf(b.x); f[5]=(short)f2bf(b.y); f[6]=(short)f2bf(b.z); f[7]=(short)f2bf(b.w);
    return f;
}

__device__ __forceinline__ bf8 load_pb(const unsigned short* __restrict__ P,
                                       int ntile, int ksteps, int kstep, int lane){
    return *(const bf8*)(P + ((((ntile*ksteps + kstep)<<6) + lane)<<3));
}

// ---------------------------------------------------------------- pack all B mats
struct PackJob { const float* s0; const float* s1; int ld, coloff, kr0, ktot, cnt, base; };
struct PackJobs { PackJob j[10]; };

__global__ __launch_bounds__(256) void pack_all(PackJobs P, unsigned short* __restrict__ dst)
{
    int idx = blockIdx.x*256 + threadIdx.x;
    #pragma unroll
    for (int t=0; t<10; ++t){
        int lo = P.j[t].base, hi = lo + P.j[t].cnt;
        if (idx >= lo && idx < hi){
            int l = idx - lo;
            int e    = l & 7;
            int lane = (l >> 3) & 63;
            int kt   = l >> 9;
            int ksteps = P.j[t].ktot >> 5;
            int ntile = kt / ksteps, kstep = kt - ntile*ksteps;
            int k = kstep*32 + ((lane>>4)<<3) + e;
            int n = ntile*16 + (lane&15);
            const float* S = (k < P.j[t].kr0) ? P.j[t].s0 : P.j[t].s1;
            int kk = (k < P.j[t].kr0) ? k : (k - P.j[t].kr0);
            dst[idx] = f2bf(S[(long)kk*P.j[t].ld + P.j[t].coloff + n]);
        }
    }
}

// ---------------------------------------------------------------- edge sort by dst
__global__ void hist_count(const int* __restrict__ dst, const int* __restrict__ batch,
                           int* __restrict__ histo, float* __restrict__ cnt){
    int e = blockIdx.x*256 + threadIdx.x;
    if (e < NE) atomicAdd(&histo[dst[e]], 1);
    if (e < NN) atomicAdd(&cnt[batch[e]], 1.0f);
}

__global__ __launch_bounds__(256) void scan_kernel(const int* __restrict__ histo,
                                                   int* __restrict__ cursor){
    __shared__ int ls[256];
    int t = threadIdx.x;
    int s = 0;
    #pragma unroll 8
    for (int i=0;i<40;++i){ int idx = t*40+i; if (idx < NN) s += histo[idx]; }
    ls[t] = s; __syncthreads();
    for (int off=1; off<256; off<<=1){
        int v = ls[t];
        if (t >= off) v += ls[t-off];
        __syncthreads();
        ls[t] = v; __syncthreads();
    }
    int run = ls[t] - s;
    for (int i=0;i<40;++i){
        int idx = t*40+i;
        if (idx < NN){ cursor[idx] = run; run += histo[idx]; }
    }
}

__global__ void scatter_kernel(const int* __restrict__ src, const int* __restrict__ dst,
                               int* __restrict__ cursor,
                               int* __restrict__ ssrc, int* __restrict__ sdst,
                               int* __restrict__ perm){
    int e = blockIdx.x*256 + threadIdx.x;
    if (e < NE){
        int d = dst[e];
        int p = atomicAdd(&cursor[d], 1);
        ssrc[p] = src[e]; sdst[p] = d; perm[p] = e;
    }
}

// ---------------------------------------------------------------- all f32->bf16 converts
__global__ __launch_bounds__(256) void conv_all(
    const float* __restrict__ ea_i, const int* __restrict__ perm,
    const float* __restrict__ x, const float* __restrict__ u,
    unsigned short* __restrict__ ea, unsigned short* __restrict__ xb,
    float* __restrict__ ucur)
{
    long idx = (long)blockIdx.x*256 + threadIdx.x;
    const long GE = (long)NE*16;
    const long GX = GE + (long)NN*16;
    if (idx < GE){
        long row = idx>>4; int c8 = (int)(idx&15);
        long srow = perm[row];
        *(bf8*)(ea + row*Hdim + c8*8) = load_frag_f32(ea_i + srow*Hdim + c8*8);
    } else if (idx < GX){
        long i2 = idx - GE; long row = i2>>4; int c8 = (int)(i2&15);
        *(bf8*)(xb + row*Hdim + c8*8) = load_frag_f32(x + row*Hdim + c8*8);
    } else {
        int i3 = (int)(idx - GX);   // 0..255
        *(float4*)(ucur + i3*8)   = *(const float4*)(u + i3*8);
        *(float4*)(ucur + i3*8+4) = *(const float4*)(u + i3*8+4);
    }
}

// ------------------------------------------- initial gu/nu (t=0), zero xsum
__global__ __launch_bounds__(128) void graph_pre_kernel(
    const float* __restrict__ u, const float* __restrict__ We, const float* __restrict__ be,
    const float* __restrict__ Wn, const float* __restrict__ bn,
    float* __restrict__ gu, float* __restrict__ nu, float* __restrict__ xsum)
{
    __shared__ float sU[Hdim];
    int b = blockIdx.x, which = b>>4, g = b&15, j = threadIdx.x;
    sU[j] = u[g*Hdim + j];
    if (b == 0){
        #pragma unroll
        for (int q=0;q<NG;++q) xsum[q*Hdim + j] = 0.f;
    }
    __syncthreads();
    const float* W = which ? (Wn + 256*Hdim) : (We + 384*Hdim);
    float a0 = which ? bn[j] : be[j], a1=0.f, a2=0.f, a3=0.f;
    for (int k=0;k<Hdim;k+=4){
        a0 = fmaf(sU[k+0], W[(k+0)*Hdim+j], a0);
        a1 = fmaf(sU[k+1], W[(k+1)*Hdim+j], a1);
        a2 = fmaf(sU[k+2], W[(k+2)*Hdim+j], a2);
        a3 = fmaf(sU[k+3], W[(k+3)*Hdim+j], a3);
    }
    (which ? nu : gu)[g*Hdim + j] = (a0+a1)+(a2+a3);
}

// ------------------------------------------- xs1g (bf16) = x@We1 + gu[batch]; zero agg
__global__ __launch_bounds__(256,2) void xs_mfma(
    const unsigned short* __restrict__ xb, const unsigned short* __restrict__ PXS,
    const float* __restrict__ gu, const int* __restrict__ batch,
    unsigned short* __restrict__ xs1g, float* __restrict__ agg)
{
    int tid = threadIdx.x, lane = tid&63, wave = tid>>6;
    int nbB = blockIdx.x*EB;
    int nb = nbB + wave*32;
    {
        long base = (long)nbB*Hdim;
        #pragma unroll
        for (int q=0;q<16;++q){
            long off = base + q*1024 + tid*4;
            if ((off>>7) < NN) *(float4*)(agg+off) = make_float4(0.f,0.f,0.f,0.f);
        }
    }
    int arow = lane&15, kg = lane>>4;
    int col = lane&15, crow = kg*4;
    bf8 xF[2][4];
    #pragma unroll
    for (int m=0;m<2;++m){
        int row = nb + m*16 + arow; if (row > NN-1) row = NN-1;
        #pragma unroll
        for (int ks=0;ks<4;++ks)
            xF[m][ks] = *(const bf8*)(xb + (long)row*Hdim + ks*32 + kg*8);
    }
    int g0[4], g1[4];
    #pragma unroll
    for (int r=0;r<4;++r){
        int ra = nb + crow + r;      if (ra > NN-1) ra = NN-1;
        int rb = nb + 16 + crow + r; if (rb > NN-1) rb = NN-1;
        g0[r] = batch[ra]; g1[r] = batch[rb];
    }
    #pragma unroll 2
    for (int nt=0; nt<8; ++nt){
        f4 acc0 = {0.f,0.f,0.f,0.f}, acc1 = {0.f,0.f,0.f,0.f};
        #pragma unroll
        for (int ks=0;ks<4;++ks){
            bf8 b = load_pb(PXS, nt, 4, ks, lane);
            acc0 = MFMA16(xF[0][ks], b, acc0, 0,0,0);
            acc1 = MFMA16(xF[1][ks], b, acc1, 0,0,0);
        }
        int j = nt*16 + col;
        #pragma unroll
        for (int r=0;r<4;++r){
            int row0 = nb + crow + r, row1 = nb + 16 + crow + r;
            if (row0 < NN) xs1g[(long)row0*Hdim + j] = f2bf(acc0[r] + gu[g0[r]*Hdim + j]);
            if (row1 < NN) xs1g[(long)row1*Hdim + j] = f2bf(acc1[r] + gu[g1[r]*Hdim + j]);
        }
    }
}

// ------------------------------------------- fused edge model + edge GRU (dst-sorted)
__global__ __launch_bounds__(256,4) void edge_mfma(
    unsigned short* __restrict__ ea,
    const unsigned short* __restrict__ xs1g, const unsigned short* __restrict__ xb,
    const unsigned short* __restrict__ PW1, const unsigned short* __restrict__ PX2,
    const unsigned short* __restrict__ PRZ,
    const unsigned short* __restrict__ PNI, const unsigned short* __restrict__ PNH,
    const float* __restrict__ bih, const float* __restrict__ bhh,
    const int* __restrict__ ssrc, const int* __restrict__ sdst,
    float* __restrict__ agg)
{
    __shared__ __align__(16) unsigned short sEo[EB*SXO];
    __shared__ int sS[EB], sD[EB];
    int tid = threadIdx.x, lane = tid&63, wave = tid>>6;
    long eb = (long)blockIdx.x*EB;
    if (tid < EB){ sS[tid] = ssrc[eb+tid]; sD[tid] = sdst[eb+tid]; }
    __syncthreads();
    int r0 = wave*32;
    int arow = lane&15, kg = lane>>4;
    int col = lane&15, crow = kg*4;
    bf8 eaF[2][4], xdF[2][4];
    #pragma unroll
    for (int m=0;m<2;++m){
        int lr = r0 + m*16 + arow;
        long drow = sD[lr];
        #pragma unroll
        for (int ks=0;ks<4;++ks){
            eaF[m][ks] = *(const bf8*)(ea + (eb + lr)*Hdim + ks*32 + kg*8);
            xdF[m][ks] = *(const bf8*)(xb + drow*Hdim + ks*32 + kg*8);
        }
    }
    // phase1: eo = relu(ea@We3 + xb[dst]@We2 + xs1g[src])  (x@We1+u@We4+be in xs1g)
    #pragma unroll 2
    for (int nt=0; nt<8; ++nt){
        int j = nt*16 + col;
        f4 acc[2];
        #pragma unroll
        for (int m=0;m<2;++m)
            #pragma unroll
            for (int r=0;r<4;++r){
                int lr = r0 + m*16 + crow + r;
                acc[m][r] = bf2f(xs1g[(long)sS[lr]*Hdim + j]);
            }
        #pragma unroll
        for (int ks=0;ks<4;++ks){
            bf8 b = load_pb(PW1, nt, 4, ks, lane);
            acc[0] = MFMA16(eaF[0][ks], b, acc[0], 0,0,0);
            acc[1] = MFMA16(eaF[1][ks], b, acc[1], 0,0,0);
        }
        #pragma unroll
        for (int ks=0;ks<4;++ks){
            bf8 b = load_pb(PX2, nt, 4, ks, lane);
            acc[0] = MFMA16(xdF[0][ks], b, acc[0], 0,0,0);
            acc[1] = MFMA16(xdF[1][ks], b, acc[1], 0,0,0);
        }
        #pragma unroll
        for (int m=0;m<2;++m)
            #pragma unroll
            for (int r=0;r<4;++r){
                int lr = r0 + m*16 + crow + r;
                sEo[lr*SXO + j] = f2bf(fmaxf(acc[m][r], 0.f));
            }
    }
    bf8 eoF[2][4];
    #pragma unroll
    for (int m=0;m<2;++m)
        #pragma unroll
        for (int ks=0;ks<4;++ks)
            eoF[m][ks] = *(const bf8*)(sEo + (r0 + m*16 + arow)*SXO + ks*32 + kg*8);
    // gates
    #pragma unroll 1
    for (int nt=0; nt<8; ++nt){
        int j = nt*16 + col;
        float vr = bih[j] + bhh[j];
        float vz = bih[128+j] + bhh[128+j];
        float vi = bih[256+j], vh = bhh[256+j];
        f4 ar[2], az[2], ai[2], ah[2];
        #pragma unroll
        for (int m=0;m<2;++m){
            ar[m] = (f4){vr,vr,vr,vr}; az[m] = (f4){vz,vz,vz,vz};
            ai[m] = (f4){vi,vi,vi,vi}; ah[m] = (f4){vh,vh,vh,vh};
        }
        #pragma unroll
        for (int ks=0;ks<8;++ks){
            bf8 A0 = (ks<4) ? eoF[0][ks] : eaF[0][ks-4];
            bf8 A1 = (ks<4) ? eoF[1][ks] : eaF[1][ks-4];
            bf8 bR = load_pb(PRZ, nt,   8, ks, lane);
            bf8 bZ = load_pb(PRZ, nt+8, 8, ks, lane);
            ar[0] = MFMA16(A0, bR, ar[0], 0,0,0);
            ar[1] = MFMA16(A1, bR, ar[1], 0,0,0);
            az[0] = MFMA16(A0, bZ, az[0], 0,0,0);
            az[1] = MFMA16(A1, bZ, az[1], 0,0,0);
        }
        #pragma unroll
        for (int ks=0;ks<4;++ks){
            bf8 bI = load_pb(PNI, nt, 4, ks, lane);
            bf8 bH = load_pb(PNH, nt, 4, ks, lane);
            ai[0] = MFMA16(eoF[0][ks], bI, ai[0], 0,0,0);
            ai[1] = MFMA16(eoF[1][ks], bI, ai[1], 0,0,0);
            ah[0] = MFMA16(eaF[0][ks], bH, ah[0], 0,0,0);
            ah[1] = MFMA16(eaF[1][ks], bH, ah[1], 0,0,0);
        }
        #pragma unroll
        for (int m=0;m<2;++m)
            #pragma unroll
            for (int r=0;r<4;++r){
                int lr = r0 + m*16 + crow + r;
                long grow = eb + lr;
                float h  = bf2f(ea[grow*Hdim + j]);
                float rr = fsigm(ar[m][r]);
                float zz = fsigm(az[m][r]);
                float nn = ftanh(fmaf(rr, ah[m][r], ai[m][r]));
                float o  = (1.0f - zz)*nn + zz*h;
                unsigned short ob = f2bf(o);
                ea[grow*Hdim + j] = ob;
                sEo[lr*SXO + j] = ob;
            }
    }
    __syncthreads();
    // segmented column-sum over sorted dst runs
    {
        int j = tid & 127;
        int half = tid >> 7;
        int lo = half*64, hi = lo + 64;
        float acc = 0.f;
        for (int row=lo; row<hi; ++row){
            acc += bf2f(sEo[row*SXO + j]);
            bool flush = (row == hi-1) || (sD[row] != sD[row+1]);
            if (flush){
                atomicAdd(&agg[(long)sD[row]*Hdim + j], acc);
                acc = 0.f;
            }
        }
    }
}

// ------------------------------------------- fused node model + node GRU (bf16 state)
__global__ __launch_bounds__(256,4) void node_mfma(
    unsigned short* __restrict__ xb, const float* __restrict__ agg,
    const float* __restrict__ nu,
    const unsigned short* __restrict__ PP1, const unsigned short* __restrict__ PRZ,
    const unsigned short* __restrict__ PNI, const unsigned short* __restrict__ PNH,
    const float* __restrict__ bih, const float* __restrict__ bhh,
    const int* __restrict__ batch, float* __restrict__ xsum)
{
    __shared__ __align__(16) unsigned short sXo[NB*SXO];
    __shared__ int sG[NB];
    int tid = threadIdx.x, lane = tid&63, wave = tid>>6;
    int nb = blockIdx.x*NB;
    if (tid < NB){
        int row = nb + tid; if (row > NN-1) row = NN-1;
        sG[tid] = batch[row];
    }
    __syncthreads();
    int r0 = wave*16;                 // 16 rows per wave, 4 waves = 64 rows
    int arow = lane&15, kg = lane>>4;
    int col = lane&15, crow = kg*4;
    bf8 xF[4], agF[4];
    {
        int row = nb + r0 + arow; if (row > NN-1) row = NN-1;
        #pragma unroll
        for (int ks=0;ks<4;++ks){
            xF[ks]  = *(const bf8*)(xb + (long)row*Hdim + ks*32 + kg*8);
            agF[ks] = load_frag_f32(agg + (long)row*Hdim + ks*32 + kg*8);
        }
    }
    // phase1: xo = relu([x|agg]@Wn[0:256] + nu[g])
    #pragma unroll 2
    for (int nt=0; nt<8; ++nt){
        int j = nt*16 + col;
        f4 acc;
        #pragma unroll
        for (int r=0;r<4;++r)
            acc[r] = nu[sG[r0 + crow + r]*Hdim + j];
        #pragma unroll
        for (int ks=0;ks<8;++ks){
            bf8 A = (ks<4) ? xF[ks] : agF[ks-4];
            bf8 b = load_pb(PP1, nt, 8, ks, lane);
            acc = MFMA16(A, b, acc, 0,0,0);
        }
        #pragma unroll
        for (int r=0;r<4;++r)
            sXo[(r0 + crow + r)*SXO + j] = f2bf(fmaxf(acc[r], 0.f));
    }
    bf8 xoF[4];
    #pragma unroll
    for (int ks=0;ks<4;++ks)
        xoF[ks] = *(const bf8*)(sXo + (r0 + arow)*SXO + ks*32 + kg*8);
    #pragma unroll 1
    for (int nt=0; nt<8; ++nt){
        int j = nt*16 + col;
        float vr = bih[j] + bhh[j];
        float vz = bih[128+j] + bhh[128+j];
        float vi = bih[256+j], vh = bhh[256+j];
        f4 ar = {vr,vr,vr,vr}, az = {vz,vz,vz,vz};
        f4 ai = {vi,vi,vi,vi}, ah = {vh,vh,vh,vh};
        #pragma unroll
        for (int ks=0;ks<8;++ks){
            bf8 A = (ks<4) ? xoF[ks] : xF[ks-4];
            bf8 bR = load_pb(PRZ, nt,   8, ks, lane);
            bf8 bZ = load_pb(PRZ, nt+8, 8, ks, lane);
            ar = MFMA16(A, bR, ar, 0,0,0);
            az = MFMA16(A, bZ, az, 0,0,0);
        }
        #pragma unroll
        for (int ks=0;ks<4;++ks){
            bf8 bI = load_pb(PNI, nt, 4, ks, lane);
            bf8 bH = load_pb(PNH, nt, 4, ks, lane);
            ai = MFMA16(xoF[ks], bI, ai, 0,0,0);
            ah = MFMA16(xF[ks],  bH, ah, 0,0,0);
        }
        #pragma unroll
        for (int r=0;r<4;++r){
            int lr = r0 + crow + r;
            int row = nb + lr;
            unsigned short ob = 0;
            if (row < NN){
                float h  = bf2f(xb[(long)row*Hdim + j]);
                float rr = fsigm(ar[r]);
                float zz = fsigm(az[r]);
                float nn = ftanh(fmaf(rr, ah[r], ai[r]));
                float o  = (1.0f - zz)*nn + zz*h;
                ob = f2bf(o);
                xb[(long)row*Hdim + j] = ob;
            }
            sXo[lr*SXO + j] = ob;
        }
    }
    __syncthreads();
    // segmented column-sum over sorted batch runs -> xsum
    {
        int j = tid & 127;
        int half = tid >> 7;
        int lo = half*32, hi = lo + 32;
        float acc = 0.f;
        for (int row=lo; row<hi; ++row){
            acc += bf2f(sXo[row*SXO + j]);
            bool flush = (row == hi-1) || (sG[row] != sG[row+1]);
            if (flush){
                atomicAdd(&xsum[sG[row]*Hdim + j], acc);
                acc = 0.f;
            }
        }
    }
}

// ------------------------------------------- global model + GRU + next-step gu/nu
__global__ __launch_bounds__(128) void global_kernel(
    float* __restrict__ xsum, const float* __restrict__ cnt,
    float* __restrict__ u,
    const float* __restrict__ Wg, const float* __restrict__ bg,
    const float* __restrict__ Wih, const float* __restrict__ Whh,
    const float* __restrict__ bih, const float* __restrict__ bhh,
    const float* __restrict__ We, const float* __restrict__ be,
    const float* __restrict__ Wn, const float* __restrict__ bn,
    float* __restrict__ gu, float* __restrict__ nu,
    float* __restrict__ out, int step)
{
    __shared__ float sXm[Hdim], sU[Hdim], sUo[Hdim], sO[Hdim];
    int g = blockIdx.x, j = threadIdx.x;
    float inv = 1.0f / fmaxf(cnt[g], 1.0f);
    sXm[j] = xsum[g*Hdim + j] * inv;
    xsum[g*Hdim + j] = 0.f;
    float hj = u[g*Hdim + j];
    sU[j] = hj;
    __syncthreads();
    float a = bg[j];
    for (int k=0;k<Hdim;++k){
        a = fmaf(sXm[k], Wg[k*Hdim + j], a);
        a = fmaf(sU[k],  Wg[(128+k)*Hdim + j], a);
    }
    sUo[j] = fmaxf(a, 0.f);
    __syncthreads();
    float r = bih[j]+bhh[j], z = bih[128+j]+bhh[128+j];
    float ni = bih[256+j], nh = bhh[256+j];
    for (int k=0;k<Hdim;++k){
        float in = sUo[k], h = sU[k];
        r  = fmaf(in, Wih[k*384 + j],       r);
        r  = fmaf(h,  Whh[k*384 + j],       r);
        z  = fmaf(in, Wih[k*384 + 128 + j], z);
        z  = fmaf(h,  Whh[k*384 + 128 + j], z);
        ni = fmaf(in, Wih[k*384 + 256 + j], ni);
        nh = fmaf(h,  Whh[k*384 + 256 + j], nh);
    }
    float rr = fsigm(r), zz = fsigm(z);
    float n = ftanh(fmaf(rr, nh, ni));
    float o = (1.0f - zz)*n + zz*hj;
    u[g*Hdim + j] = o;
    out[(long)(g*3 + step)*Hdim + j] = o;
    sO[j] = o;
    __syncthreads();
    float a0 = be[j], a1 = bn[j];
    for (int k=0;k<Hdim;++k){
        float v = sO[k];
        a0 = fmaf(v, We[(384+k)*Hdim + j], a0);
        a1 = fmaf(v, Wn[(256+k)*Hdim + j], a1);
    }
    gu[g*Hdim + j] = a0;
    nu[g*Hdim + j] = a1;
}

// ---------------------------------------------------------------- host
extern "C" void kernel_launch(void* const* d_in, const int* in_sizes, int n_in,
                              void* d_out, int out_size, void* d_ws, size_t ws_size,
                              hipStream_t stream)
{
    const float* x    = (const float*)d_in[0];
    const float* ea_i = (const float*)d_in[1];
    const float* u    = (const float*)d_in[2];
    const float* We   = (const float*)d_in[3];
    const float* be   = (const float*)d_in[4];
    const float* Wn   = (const float*)d_in[5];
    const float* bn   = (const float*)d_in[6];
    const float* Wg   = (const float*)d_in[7];
    const float* bg   = (const float*)d_in[8];
    const float* eWih = (const float*)d_in[9];
    const float* eWhh = (const float*)d_in[10];
    const float* ebih = (const float*)d_in[11];
    const float* ebhh = (const float*)d_in[12];
    const float* nWih = (const float*)d_in[13];
    const float* nWhh = (const float*)d_in[14];
    const float* nbih = (const float*)d_in[15];
    const float* nbhh = (const float*)d_in[16];
    const float* gWih = (const float*)d_in[17];
    const float* gWhh = (const float*)d_in[18];
    const float* gbih = (const float*)d_in[19];
    const float* gbhh = (const float*)d_in[20];
    const int*   ei   = (const int*)d_in[21];
    const int*   batch= (const int*)d_in[22];
    const int* src = ei;
    const int* dst = ei + NE;
    float* out = (float*)d_out;

    size_t off = 0;
    auto alloc = [&](size_t bytes)->char*{
        char* p = (char*)d_ws + off;
        off += (bytes + 255) & ~(size_t)255;
        return p;
    };
    unsigned short* ea   = (unsigned short*)alloc((size_t)NE*Hdim*2);
    unsigned short* xb   = (unsigned short*)alloc((size_t)NN*Hdim*2);
    unsigned short* xs1g = (unsigned short*)alloc((size_t)NN*Hdim*2);
    float*          agg  = (float*)alloc((size_t)NN*Hdim*4);
    float*          ucur = (float*)alloc((size_t)NG*Hdim*4);
    float*          gu   = (float*)alloc((size_t)NG*Hdim*4);
    float*          nu   = (float*)alloc((size_t)NG*Hdim*4);
    float*          xsum = (float*)alloc((size_t)NG*Hdim*4);
    unsigned short* PK   = (unsigned short*)alloc((size_t)278528*2);
    int* histo  = (int*)alloc((size_t)(NN+NG)*4);
    float* cnt  = (float*)(histo + NN);
    int* cursor = (int*)alloc((size_t)NN*4);
    int* ssrc   = (int*)alloc((size_t)NE*4);
    int* sdst   = (int*)alloc((size_t)NE*4);
    int* perm   = (int*)alloc((size_t)NE*4);

    unsigned short* PXS  = PK + 0;        // We1
    unsigned short* PX2  = PK + 16384;    // We2
    unsigned short* PW1  = PK + 32768;    // We3
    unsigned short* PeRZ = PK + 49152;
    unsigned short* PeNI = PK + 114688;
    unsigned short* PeNH = PK + 131072;
    unsigned short* PnP1 = PK + 147456;
    unsigned short* PnRZ = PK + 180224;
    unsigned short* PnNI = PK + 245760;
    unsigned short* PnNH = PK + 262144;

    hipMemsetAsync(histo, 0, (size_t)(NN+NG)*4, stream);
    hist_count<<<(NE+255)/256, 256, 0, stream>>>(dst, batch, histo, cnt);
    scan_kernel<<<1, 256, 0, stream>>>(histo, cursor);
    scatter_kernel<<<(NE+255)/256, 256, 0, stream>>>(src, dst, cursor, ssrc, sdst, perm);
    {
        long groups = (long)(NE+NN+NG)*16;
        conv_all<<<(int)((groups+255)/256), 256, 0, stream>>>(ea_i, perm, x, u, ea, xb, ucur);
    }

    PackJobs PJ;
    auto setj = [&](int t, const float* s0, const float* s1, int ld, int coloff,
                    int kr0, int ktot, int ntot, int base){
        PJ.j[t] = PackJob{ s0, s1, ld, coloff, kr0, ktot, ktot*ntot, base };
    };
    setj(0, We,            We,   Hdim, 0,   128, 128, 128, 0);
    setj(1, We+128*Hdim,   We,   Hdim, 0,   128, 128, 128, 16384);
    setj(2, We+256*Hdim,   We,   Hdim, 0,   128, 128, 128, 32768);
    setj(3, eWih, eWhh, 384, 0,   128, 256, 256, 49152);
    setj(4, eWih, eWih, 384, 256, 128, 128, 128, 114688);
    setj(5, eWhh, eWhh, 384, 256, 128, 128, 128, 131072);
    setj(6, Wn,   Wn,   Hdim, 0,  256, 256, 128, 147456);
    setj(7, nWih, nWhh, 384, 0,   128, 256, 256, 180224);
    setj(8, nWih, nWih, 384, 256, 128, 128, 128, 245760);
    setj(9, nWhh, nWhh, 384, 256, 128, 128, 128, 262144);
    pack_all<<<278528/256, 256, 0, stream>>>(PJ, PK);

    graph_pre_kernel<<<32, 128, 0, stream>>>(ucur, We, be, Wn, bn, gu, nu, xsum);

    for (int t=0; t<3; ++t){
        xs_mfma<<<(NN+EB-1)/EB, 256, 0, stream>>>(xb, PXS, gu, batch, xs1g, agg);
        edge_mfma<<<NE/EB, 256, 0, stream>>>(ea, xs1g, xb, PW1, PX2, PeRZ, PeNI, PeNH,
                                             ebih, ebhh, ssrc, sdst, agg);
        node_mfma<<<(NN+NB-1)/NB, 256, 0, stream>>>(xb, agg, nu, PnP1, PnRZ, PnNI, PnNH,
                                                    nbih, nbhh, batch, xsum);
        global_kernel<<<NG, 128, 0, stream>>>(xsum, cnt, ucur, Wg, bg,
                                              gWih, gWhh, gbih, gbhh,
                                              We, be, Wn, bn, gu, nu, out, t);
    }
}

// Round 6
// 1015.712 us; speedup vs baseline: 5.6361x; 1.1278x over previous
//
#include <hip/hip_runtime.h>

#define Hdim 128
#define NN 10000
#define NE 320000
#define NG 16
#define EB 256          // edge rows per block (4 waves x 64 rows)
#define EBX 128         // xs rows per block (4 waves x 32 rows)
#define NB 64           // node rows per block
#define SXO 136         // LDS bf16 row stride

typedef __attribute__((ext_vector_type(8))) short bf8;   // 8 bf16 = 4 VGPRs
typedef __attribute__((ext_vector_type(4))) float f4;
#define MFMA16 __builtin_amdgcn_mfma_f32_16x16x32_bf16

#if __has_builtin(__builtin_amdgcn_exp2f)
#define EXP2F(x) __builtin_amdgcn_exp2f(x)
#else
#define EXP2F(x) exp2f(x)
#endif
#if __has_builtin(__builtin_amdgcn_rcpf)
#define RCPF(x) __builtin_amdgcn_rcpf(x)
#else
#define RCPF(x) (1.0f/(x))
#endif

__device__ __forceinline__ float fsigm(float x){
    return RCPF(1.0f + EXP2F(-1.442695041f*x));
}
__device__ __forceinline__ float ftanh(float x){
    float t = EXP2F(2.885390082f*x);          // e^(2x)
    return 1.0f - 2.0f*RCPF(t + 1.0f);        // (t-1)/(t+1)
}

__device__ __forceinline__ unsigned short f2bf(float v){
    unsigned int b = __float_as_uint(v);
    return (unsigned short)((b + 0x7FFFu + ((b>>16)&1u)) >> 16);
}
__device__ __forceinline__ float bf2f(unsigned short u){
    return __uint_as_float(((unsigned int)u)<<16);
}

__device__ __forceinline__ bf8 load_frag_f32(const float* __restrict__ p){
    float4 a = *(const float4*)p;
    float4 b = *(const float4*)(p+4);
    bf8 f;
    f[0]=(short)f2bf(a.x); f[1]=(short)f2bf(a.y); f[2]=(short)f2bf(a.z); f[3]=(short)f2bf(a.w);
    f[4]=(short)f2bf(b.x); f[5]=(short)f2bf(b.y); f[6]=(short)f2bf(b.z); f[7]=(short)f2bf(b.w);
    return f;
}

__device__ __forceinline__ bf8 load_pb(const unsigned short* __restrict__ P,
                                       int ntile, int ksteps, int kstep, int lane){
    return *(const bf8*)(P + ((((ntile*ksteps + kstep)<<6) + lane)<<3));
}

// ---------------------------------------------------------------- pack all B mats
struct PackJob { const float* s0; const float* s1; int ld, coloff, kr0, ktot, cnt, base; };
struct PackJobs { PackJob j[10]; };

__global__ __launch_bounds__(256) void pack_all(PackJobs P, unsigned short* __restrict__ dst)
{
    int idx = blockIdx.x*256 + threadIdx.x;
    #pragma unroll
    for (int t=0; t<10; ++t){
        int lo = P.j[t].base, hi = lo + P.j[t].cnt;
        if (idx >= lo && idx < hi){
            int l = idx - lo;
            int e    = l & 7;
            int lane = (l >> 3) & 63;
            int kt   = l >> 9;
            int ksteps = P.j[t].ktot >> 5;
            int ntile = kt / ksteps, kstep = kt - ntile*ksteps;
            int k = kstep*32 + ((lane>>4)<<3) + e;
            int n = ntile*16 + (lane&15);
            const float* S = (k < P.j[t].kr0) ? P.j[t].s0 : P.j[t].s1;
            int kk = (k < P.j[t].kr0) ? k : (k - P.j[t].kr0);
            dst[idx] = f2bf(S[(long)kk*P.j[t].ld + P.j[t].coloff + n]);
        }
    }
}

// ---------------------------------------------------------------- edge sort by dst
__global__ void hist_count(const int* __restrict__ dst, const int* __restrict__ batch,
                           int* __restrict__ histo, float* __restrict__ cnt){
    int e = blockIdx.x*256 + threadIdx.x;
    if (e < NE) atomicAdd(&histo[dst[e]], 1);
    if (e < NN) atomicAdd(&cnt[batch[e]], 1.0f);
}

__global__ __launch_bounds__(256) void scan_kernel(const int* __restrict__ histo,
                                                   int* __restrict__ cursor){
    __shared__ int ls[256];
    int t = threadIdx.x;
    int s = 0;
    #pragma unroll 8
    for (int i=0;i<40;++i){ int idx = t*40+i; if (idx < NN) s += histo[idx]; }
    ls[t] = s; __syncthreads();
    for (int off=1; off<256; off<<=1){
        int v = ls[t];
        if (t >= off) v += ls[t-off];
        __syncthreads();
        ls[t] = v; __syncthreads();
    }
    int run = ls[t] - s;
    for (int i=0;i<40;++i){
        int idx = t*40+i;
        if (idx < NN){ cursor[idx] = run; run += histo[idx]; }
    }
}

__global__ void scatter_kernel(const int* __restrict__ src, const int* __restrict__ dst,
                               int* __restrict__ cursor,
                               int* __restrict__ ssrc, int* __restrict__ sdst,
                               int* __restrict__ perm){
    int e = blockIdx.x*256 + threadIdx.x;
    if (e < NE){
        int d = dst[e];
        int p = atomicAdd(&cursor[d], 1);
        ssrc[p] = src[e]; sdst[p] = d; perm[p] = e;
    }
}

// ---------------------------------------------------------------- all f32->bf16 converts
__global__ __launch_bounds__(256) void conv_all(
    const float* __restrict__ ea_i, const int* __restrict__ perm,
    const float* __restrict__ x, const float* __restrict__ u,
    unsigned short* __restrict__ ea, unsigned short* __restrict__ xb,
    float* __restrict__ ucur)
{
    long idx = (long)blockIdx.x*256 + threadIdx.x;
    const long GE = (long)NE*16;
    const long GX = GE + (long)NN*16;
    if (idx < GE){
        long row = idx>>4; int c8 = (int)(idx&15);
        long srow = perm[row];
        *(bf8*)(ea + row*Hdim + c8*8) = load_frag_f32(ea_i + srow*Hdim + c8*8);
    } else if (idx < GX){
        long i2 = idx - GE; long row = i2>>4; int c8 = (int)(i2&15);
        *(bf8*)(xb + row*Hdim + c8*8) = load_frag_f32(x + row*Hdim + c8*8);
    } else {
        int i3 = (int)(idx - GX);   // 0..255
        *(float4*)(ucur + i3*8)   = *(const float4*)(u + i3*8);
        *(float4*)(ucur + i3*8+4) = *(const float4*)(u + i3*8+4);
    }
}

// ------------------------------------------- initial gu/nu (t=0), zero xsum
__global__ __launch_bounds__(128) void graph_pre_kernel(
    const float* __restrict__ u, const float* __restrict__ We, const float* __restrict__ be,
    const float* __restrict__ Wn, const float* __restrict__ bn,
    float* __restrict__ gu, float* __restrict__ nu, float* __restrict__ xsum)
{
    __shared__ float sU[Hdim];
    int b = blockIdx.x, which = b>>4, g = b&15, j = threadIdx.x;
    sU[j] = u[g*Hdim + j];
    if (b == 0){
        #pragma unroll
        for (int q=0;q<NG;++q) xsum[q*Hdim + j] = 0.f;
    }
    __syncthreads();
    const float* W = which ? (Wn + 256*Hdim) : (We + 384*Hdim);
    float a0 = which ? bn[j] : be[j], a1=0.f, a2=0.f, a3=0.f;
    for (int k=0;k<Hdim;k+=4){
        a0 = fmaf(sU[k+0], W[(k+0)*Hdim+j], a0);
        a1 = fmaf(sU[k+1], W[(k+1)*Hdim+j], a1);
        a2 = fmaf(sU[k+2], W[(k+2)*Hdim+j], a2);
        a3 = fmaf(sU[k+3], W[(k+3)*Hdim+j], a3);
    }
    (which ? nu : gu)[g*Hdim + j] = (a0+a1)+(a2+a3);
}

// ------------------------------------------- xs1g (bf16) = x@We1 + gu[batch]; zero agg
__global__ __launch_bounds__(256,2) void xs_mfma(
    const unsigned short* __restrict__ xb, const unsigned short* __restrict__ PXS,
    const float* __restrict__ gu, const int* __restrict__ batch,
    unsigned short* __restrict__ xs1g, float* __restrict__ agg)
{
    int tid = threadIdx.x, lane = tid&63, wave = tid>>6;
    int nbB = blockIdx.x*EBX;
    int nb = nbB + wave*32;
    {
        long base = (long)nbB*Hdim;
        #pragma unroll
        for (int q=0;q<16;++q){
            long off = base + q*1024 + tid*4;
            if ((off>>7) < NN) *(float4*)(agg+off) = make_float4(0.f,0.f,0.f,0.f);
        }
    }
    int arow = lane&15, kg = lane>>4;
    int col = lane&15, crow = kg*4;
    bf8 xF[2][4];
    #pragma unroll
    for (int m=0;m<2;++m){
        int row = nb + m*16 + arow; if (row > NN-1) row = NN-1;
        #pragma unroll
        for (int ks=0;ks<4;++ks)
            xF[m][ks] = *(const bf8*)(xb + (long)row*Hdim + ks*32 + kg*8);
    }
    int g0[4], g1[4];
    #pragma unroll
    for (int r=0;r<4;++r){
        int ra = nb + crow + r;      if (ra > NN-1) ra = NN-1;
        int rb = nb + 16 + crow + r; if (rb > NN-1) rb = NN-1;
        g0[r] = batch[ra]; g1[r] = batch[rb];
    }
    #pragma unroll 2
    for (int nt=0; nt<8; ++nt){
        f4 acc0 = {0.f,0.f,0.f,0.f}, acc1 = {0.f,0.f,0.f,0.f};
        #pragma unroll
        for (int ks=0;ks<4;++ks){
            bf8 b = load_pb(PXS, nt, 4, ks, lane);
            acc0 = MFMA16(xF[0][ks], b, acc0, 0,0,0);
            acc1 = MFMA16(xF[1][ks], b, acc1, 0,0,0);
        }
        int j = nt*16 + col;
        #pragma unroll
        for (int r=0;r<4;++r){
            int row0 = nb + crow + r, row1 = nb + 16 + crow + r;
            if (row0 < NN) xs1g[(long)row0*Hdim + j] = f2bf(acc0[r] + gu[g0[r]*Hdim + j]);
            if (row1 < NN) xs1g[(long)row1*Hdim + j] = f2bf(acc1[r] + gu[g1[r]*Hdim + j]);
        }
    }
}

// ------------------------------------------- fused edge model + edge GRU (dst-sorted)
// 4 waves x 64 rows: each B-fragment load feeds 4 MFMAs (halves L2 B-traffic)
__global__ __launch_bounds__(256,2) void edge_mfma(
    unsigned short* __restrict__ ea,
    const unsigned short* __restrict__ xs1g, const unsigned short* __restrict__ xb,
    const unsigned short* __restrict__ PW1, const unsigned short* __restrict__ PX2,
    const unsigned short* __restrict__ PRZ,
    const unsigned short* __restrict__ PNI, const unsigned short* __restrict__ PNH,
    const float* __restrict__ bih, const float* __restrict__ bhh,
    const int* __restrict__ ssrc, const int* __restrict__ sdst,
    float* __restrict__ agg)
{
    __shared__ __align__(16) unsigned short sEo[EB*SXO];   // 69632 B
    __shared__ int sS[EB], sD[EB];
    int tid = threadIdx.x, lane = tid&63, wave = tid>>6;
    long eb = (long)blockIdx.x*EB;
    sS[tid] = ssrc[eb+tid]; sD[tid] = sdst[eb+tid];
    __syncthreads();
    int r0 = wave*64;
    int arow = lane&15, kg = lane>>4;
    int col = lane&15, crow = kg*4;
    bf8 eaF[4][4], xdF[4][4];
    #pragma unroll
    for (int m=0;m<4;++m){
        int lr = r0 + m*16 + arow;
        long drow = sD[lr];
        #pragma unroll
        for (int ks=0;ks<4;++ks){
            eaF[m][ks] = *(const bf8*)(ea + (eb + lr)*Hdim + ks*32 + kg*8);
            xdF[m][ks] = *(const bf8*)(xb + drow*Hdim + ks*32 + kg*8);
        }
    }
    // phase1: eo = relu(ea@We3 + xb[dst]@We2 + xs1g[src])
    #pragma unroll 1
    for (int nt=0; nt<8; ++nt){
        int j = nt*16 + col;
        f4 acc[4];
        #pragma unroll
        for (int m=0;m<4;++m)
            #pragma unroll
            for (int r=0;r<4;++r)
                acc[m][r] = bf2f(xs1g[(long)sS[r0 + m*16 + crow + r]*Hdim + j]);
        #pragma unroll
        for (int ks=0;ks<4;++ks){
            bf8 b = load_pb(PW1, nt, 4, ks, lane);
            #pragma unroll
            for (int m=0;m<4;++m) acc[m] = MFMA16(eaF[m][ks], b, acc[m], 0,0,0);
        }
        #pragma unroll
        for (int ks=0;ks<4;++ks){
            bf8 b = load_pb(PX2, nt, 4, ks, lane);
            #pragma unroll
            for (int m=0;m<4;++m) acc[m] = MFMA16(xdF[m][ks], b, acc[m], 0,0,0);
        }
        #pragma unroll
        for (int m=0;m<4;++m)
            #pragma unroll
            for (int r=0;r<4;++r)
                sEo[(r0 + m*16 + crow + r)*SXO + j] = f2bf(fmaxf(acc[m][r], 0.f));
    }
    bf8 eoF[4][4];
    #pragma unroll
    for (int m=0;m<4;++m)
        #pragma unroll
        for (int ks=0;ks<4;++ks)
            eoF[m][ks] = *(const bf8*)(sEo + (r0 + m*16 + arow)*SXO + ks*32 + kg*8);
    // gates
    #pragma unroll 1
    for (int nt=0; nt<8; ++nt){
        int j = nt*16 + col;
        float vr = bih[j] + bhh[j];
        float vz = bih[128+j] + bhh[128+j];
        float vi = bih[256+j], vh = bhh[256+j];
        f4 ar[4], az[4], ai[4], ah[4];
        #pragma unroll
        for (int m=0;m<4;++m){
            ar[m] = (f4){vr,vr,vr,vr}; az[m] = (f4){vz,vz,vz,vz};
            ai[m] = (f4){vi,vi,vi,vi}; ah[m] = (f4){vh,vh,vh,vh};
        }
        #pragma unroll
        for (int ks=0;ks<8;++ks){
            bf8 bR = load_pb(PRZ, nt,   8, ks, lane);
            bf8 bZ = load_pb(PRZ, nt+8, 8, ks, lane);
            #pragma unroll
            for (int m=0;m<4;++m){
                bf8 A = (ks<4) ? eoF[m][ks] : eaF[m][ks-4];
                ar[m] = MFMA16(A, bR, ar[m], 0,0,0);
                az[m] = MFMA16(A, bZ, az[m], 0,0,0);
            }
        }
        #pragma unroll
        for (int ks=0;ks<4;++ks){
            bf8 bI = load_pb(PNI, nt, 4, ks, lane);
            bf8 bH = load_pb(PNH, nt, 4, ks, lane);
            #pragma unroll
            for (int m=0;m<4;++m){
                ai[m] = MFMA16(eoF[m][ks], bI, ai[m], 0,0,0);
                ah[m] = MFMA16(eaF[m][ks], bH, ah[m], 0,0,0);
            }
        }
        #pragma unroll
        for (int m=0;m<4;++m)
            #pragma unroll
            for (int r=0;r<4;++r){
                int lr = r0 + m*16 + crow + r;
                long grow = eb + lr;
                float h  = bf2f(ea[grow*Hdim + j]);
                float rr = fsigm(ar[m][r]);
                float zz = fsigm(az[m][r]);
                float nn = ftanh(fmaf(rr, ah[m][r], ai[m][r]));
                float o  = (1.0f - zz)*nn + zz*h;
                unsigned short ob = f2bf(o);
                ea[grow*Hdim + j] = ob;
                sEo[lr*SXO + j] = ob;
            }
    }
    __syncthreads();
    // segmented column-sum over sorted dst runs
    {
        int j = tid & 127;
        int half = tid >> 7;
        int lo = half*128, hi = lo + 128;
        float acc = 0.f;
        for (int row=lo; row<hi; ++row){
            acc += bf2f(sEo[row*SXO + j]);
            bool flush = (row == hi-1) || (sD[row] != sD[row+1]);
            if (flush){
                atomicAdd(&agg[(long)sD[row]*Hdim + j], acc);
                acc = 0.f;
            }
        }
    }
}

// ------------------------------------------- fused node model + node GRU (bf16 state)
__global__ __launch_bounds__(256,4) void node_mfma(
    unsigned short* __restrict__ xb, const float* __restrict__ agg,
    const float* __restrict__ nu,
    const unsigned short* __restrict__ PP1, const unsigned short* __restrict__ PRZ,
    const unsigned short* __restrict__ PNI, const unsigned short* __restrict__ PNH,
    const float* __restrict__ bih, const float* __restrict__ bhh,
    const int* __restrict__ batch, float* __restrict__ xsum)
{
    __shared__ __align__(16) unsigned short sXo[NB*SXO];
    __shared__ int sG[NB];
    int tid = threadIdx.x, lane = tid&63, wave = tid>>6;
    int nb = blockIdx.x*NB;
    if (tid < NB){
        int row = nb + tid; if (row > NN-1) row = NN-1;
        sG[tid] = batch[row];
    }
    __syncthreads();
    int r0 = wave*16;                 // 16 rows per wave, 4 waves = 64 rows
    int arow = lane&15, kg = lane>>4;
    int col = lane&15, crow = kg*4;
    bf8 xF[4], agF[4];
    {
        int row = nb + r0 + arow; if (row > NN-1) row = NN-1;
        #pragma unroll
        for (int ks=0;ks<4;++ks){
            xF[ks]  = *(const bf8*)(xb + (long)row*Hdim + ks*32 + kg*8);
            agF[ks] = load_frag_f32(agg + (long)row*Hdim + ks*32 + kg*8);
        }
    }
    // phase1: xo = relu([x|agg]@Wn[0:256] + nu[g])
    #pragma unroll 2
    for (int nt=0; nt<8; ++nt){
        int j = nt*16 + col;
        f4 acc;
        #pragma unroll
        for (int r=0;r<4;++r)
            acc[r] = nu[sG[r0 + crow + r]*Hdim + j];
        #pragma unroll
        for (int ks=0;ks<8;++ks){
            bf8 A = (ks<4) ? xF[ks] : agF[ks-4];
            bf8 b = load_pb(PP1, nt, 8, ks, lane);
            acc = MFMA16(A, b, acc, 0,0,0);
        }
        #pragma unroll
        for (int r=0;r<4;++r)
            sXo[(r0 + crow + r)*SXO + j] = f2bf(fmaxf(acc[r], 0.f));
    }
    bf8 xoF[4];
    #pragma unroll
    for (int ks=0;ks<4;++ks)
        xoF[ks] = *(const bf8*)(sXo + (r0 + arow)*SXO + ks*32 + kg*8);
    #pragma unroll 1
    for (int nt=0; nt<8; ++nt){
        int j = nt*16 + col;
        float vr = bih[j] + bhh[j];
        float vz = bih[128+j] + bhh[128+j];
        float vi = bih[256+j], vh = bhh[256+j];
        f4 ar = {vr,vr,vr,vr}, az = {vz,vz,vz,vz};
        f4 ai = {vi,vi,vi,vi}, ah = {vh,vh,vh,vh};
        #pragma unroll
        for (int ks=0;ks<8;++ks){
            bf8 A = (ks<4) ? xoF[ks] : xF[ks-4];
            bf8 bR = load_pb(PRZ, nt,   8, ks, lane);
            bf8 bZ = load_pb(PRZ, nt+8, 8, ks, lane);
            ar = MFMA16(A, bR, ar, 0,0,0);
            az = MFMA16(A, bZ, az, 0,0,0);
        }
        #pragma unroll
        for (int ks=0;ks<4;++ks){
            bf8 bI = load_pb(PNI, nt, 4, ks, lane);
            bf8 bH = load_pb(PNH, nt, 4, ks, lane);
            ai = MFMA16(xoF[ks], bI, ai, 0,0,0);
            ah = MFMA16(xF[ks],  bH, ah, 0,0,0);
        }
        #pragma unroll
        for (int r=0;r<4;++r){
            int lr = r0 + crow + r;
            int row = nb + lr;
            unsigned short ob = 0;
            if (row < NN){
                float h  = bf2f(xb[(long)row*Hdim + j]);
                float rr = fsigm(ar[r]);
                float zz = fsigm(az[r]);
                float nn = ftanh(fmaf(rr, ah[r], ai[r]));
                float o  = (1.0f - zz)*nn + zz*h;
                ob = f2bf(o);
                xb[(long)row*Hdim + j] = ob;
            }
            sXo[lr*SXO + j] = ob;
        }
    }
    __syncthreads();
    // segmented column-sum over sorted batch runs -> xsum
    {
        int j = tid & 127;
        int half = tid >> 7;
        int lo = half*32, hi = lo + 32;
        float acc = 0.f;
        for (int row=lo; row<hi; ++row){
            acc += bf2f(sXo[row*SXO + j]);
            bool flush = (row == hi-1) || (sG[row] != sG[row+1]);
            if (flush){
                atomicAdd(&xsum[sG[row]*Hdim + j], acc);
                acc = 0.f;
            }
        }
    }
}

// ------------------------------------------- global model + GRU + next-step gu/nu
__global__ __launch_bounds__(128) void global_kernel(
    float* __restrict__ xsum, const float* __restrict__ cnt,
    float* __restrict__ u,
    const float* __restrict__ Wg, const float* __restrict__ bg,
    const float* __restrict__ Wih, const float* __restrict__ Whh,
    const float* __restrict__ bih, const float* __restrict__ bhh,
    const float* __restrict__ We, const float* __restrict__ be,
    const float* __restrict__ Wn, const float* __restrict__ bn,
    float* __restrict__ gu, float* __restrict__ nu,
    float* __restrict__ out, int step)
{
    __shared__ float sXm[Hdim], sU[Hdim], sUo[Hdim], sO[Hdim];
    int g = blockIdx.x, j = threadIdx.x;
    float inv = 1.0f / fmaxf(cnt[g], 1.0f);
    sXm[j] = xsum[g*Hdim + j] * inv;
    xsum[g*Hdim + j] = 0.f;
    float hj = u[g*Hdim + j];
    sU[j] = hj;
    __syncthreads();
    float a = bg[j];
    for (int k=0;k<Hdim;++k){
        a = fmaf(sXm[k], Wg[k*Hdim + j], a);
        a = fmaf(sU[k],  Wg[(128+k)*Hdim + j], a);
    }
    sUo[j] = fmaxf(a, 0.f);
    __syncthreads();
    float r = bih[j]+bhh[j], z = bih[128+j]+bhh[128+j];
    float ni = bih[256+j], nh = bhh[256+j];
    for (int k=0;k<Hdim;++k){
        float in = sUo[k], h = sU[k];
        r  = fmaf(in, Wih[k*384 + j],       r);
        r  = fmaf(h,  Whh[k*384 + j],       r);
        z  = fmaf(in, Wih[k*384 + 128 + j], z);
        z  = fmaf(h,  Whh[k*384 + 128 + j], z);
        ni = fmaf(in, Wih[k*384 + 256 + j], ni);
        nh = fmaf(h,  Whh[k*384 + 256 + j], nh);
    }
    float rr = fsigm(r), zz = fsigm(z);
    float n = ftanh(fmaf(rr, nh, ni));
    float o = (1.0f - zz)*n + zz*hj;
    u[g*Hdim + j] = o;
    out[(long)(g*3 + step)*Hdim + j] = o;
    sO[j] = o;
    __syncthreads();
    float a0 = be[j], a1 = bn[j];
    for (int k=0;k<Hdim;++k){
        float v = sO[k];
        a0 = fmaf(v, We[(384+k)*Hdim + j], a0);
        a1 = fmaf(v, Wn[(256+k)*Hdim + j], a1);
    }
    gu[g*Hdim + j] = a0;
    nu[g*Hdim + j] = a1;
}

// ---------------------------------------------------------------- host
extern "C" void kernel_launch(void* const* d_in, const int* in_sizes, int n_in,
                              void* d_out, int out_size, void* d_ws, size_t ws_size,
                              hipStream_t stream)
{
    const float* x    = (const float*)d_in[0];
    const float* ea_i = (const float*)d_in[1];
    const float* u    = (const float*)d_in[2];
    const float* We   = (const float*)d_in[3];
    const float* be   = (const float*)d_in[4];
    const float* Wn   = (const float*)d_in[5];
    const float* bn   = (const float*)d_in[6];
    const float* Wg   = (const float*)d_in[7];
    const float* bg   = (const float*)d_in[8];
    const float* eWih = (const float*)d_in[9];
    const float* eWhh = (const float*)d_in[10];
    const float* ebih = (const float*)d_in[11];
    const float* ebhh = (const float*)d_in[12];
    const float* nWih = (const float*)d_in[13];
    const float* nWhh = (const float*)d_in[14];
    const float* nbih = (const float*)d_in[15];
    const float* nbhh = (const float*)d_in[16];
    const float* gWih = (const float*)d_in[17];
    const float* gWhh = (const float*)d_in[18];
    const float* gbih = (const float*)d_in[19];
    const float* gbhh = (const float*)d_in[20];
    const int*   ei   = (const int*)d_in[21];
    const int*   batch= (const int*)d_in[22];
    const int* src = ei;
    const int* dst = ei + NE;
    float* out = (float*)d_out;

    size_t off = 0;
    auto alloc = [&](size_t bytes)->char*{
        char* p = (char*)d_ws + off;
        off += (bytes + 255) & ~(size_t)255;
        return p;
    };
    unsigned short* ea   = (unsigned short*)alloc((size_t)NE*Hdim*2);
    unsigned short* xb   = (unsigned short*)alloc((size_t)NN*Hdim*2);
    unsigned short* xs1g = (unsigned short*)alloc((size_t)NN*Hdim*2);
    float*          agg  = (float*)alloc((size_t)NN*Hdim*4);
    float*          ucur = (float*)alloc((size_t)NG*Hdim*4);
    float*          gu   = (float*)alloc((size_t)NG*Hdim*4);
    float*          nu   = (float*)alloc((size_t)NG*Hdim*4);
    float*          xsum = (float*)alloc((size_t)NG*Hdim*4);
    unsigned short* PK   = (unsigned short*)alloc((size_t)278528*2);
    int* histo  = (int*)alloc((size_t)(NN+NG)*4);
    float* cnt  = (float*)(histo + NN);
    int* cursor = (int*)alloc((size_t)NN*4);
    int* ssrc   = (int*)alloc((size_t)NE*4);
    int* sdst   = (int*)alloc((size_t)NE*4);
    int* perm   = (int*)alloc((size_t)NE*4);

    unsigned short* PXS  = PK + 0;        // We1
    unsigned short* PX2  = PK + 16384;    // We2
    unsigned short* PW1  = PK + 32768;    // We3
    unsigned short* PeRZ = PK + 49152;
    unsigned short* PeNI = PK + 114688;
    unsigned short* PeNH = PK + 131072;
    unsigned short* PnP1 = PK + 147456;
    unsigned short* PnRZ = PK + 180224;
    unsigned short* PnNI = PK + 245760;
    unsigned short* PnNH = PK + 262144;

    hipMemsetAsync(histo, 0, (size_t)(NN+NG)*4, stream);
    hist_count<<<(NE+255)/256, 256, 0, stream>>>(dst, batch, histo, cnt);
    scan_kernel<<<1, 256, 0, stream>>>(histo, cursor);
    scatter_kernel<<<(NE+255)/256, 256, 0, stream>>>(src, dst, cursor, ssrc, sdst, perm);
    {
        long groups = (long)(NE+NN+NG)*16;
        conv_all<<<(int)((groups+255)/256), 256, 0, stream>>>(ea_i, perm, x, u, ea, xb, ucur);
    }

    PackJobs PJ;
    auto setj = [&](int t, const float* s0, const float* s1, int ld, int coloff,
                    int kr0, int ktot, int ntot, int base){
        PJ.j[t] = PackJob{ s0, s1, ld, coloff, kr0, ktot, ktot*ntot, base };
    };
    setj(0, We,            We,   Hdim, 0,   128, 128, 128, 0);
    setj(1, We+128*Hdim,   We,   Hdim, 0,   128, 128, 128, 16384);
    setj(2, We+256*Hdim,   We,   Hdim, 0,   128, 128, 128, 32768);
    setj(3, eWih, eWhh, 384, 0,   128, 256, 256, 49152);
    setj(4, eWih, eWih, 384, 256, 128, 128, 128, 114688);
    setj(5, eWhh, eWhh, 384, 256, 128, 128, 128, 131072);
    setj(6, Wn,   Wn,   Hdim, 0,  256, 256, 128, 147456);
    setj(7, nWih, nWhh, 384, 0,   128, 256, 256, 180224);
    setj(8, nWih, nWih, 384, 256, 128, 128, 128, 245760);
    setj(9, nWhh, nWhh, 384, 256, 128, 128, 128, 262144);
    pack_all<<<278528/256, 256, 0, stream>>>(PJ, PK);

    graph_pre_kernel<<<32, 128, 0, stream>>>(ucur, We, be, Wn, bn, gu, nu, xsum);

    for (int t=0; t<3; ++t){
        xs_mfma<<<(NN+EBX-1)/EBX, 256, 0, stream>>>(xb, PXS, gu, batch, xs1g, agg);
        edge_mfma<<<NE/EB, 256, 0, stream>>>(ea, xs1g, xb, PW1, PX2, PeRZ, PeNI, PeNH,
                                             ebih, ebhh, ssrc, sdst, agg);
        node_mfma<<<(NN+NB-1)/NB, 256, 0, stream>>>(xb, agg, nu, PnP1, PnRZ, PnNI, PnNH,
                                                    nbih, nbhh, batch, xsum);
        global_kernel<<<NG, 128, 0, stream>>>(xsum, cnt, ucur, Wg, bg,
                                              gWih, gWhh, gbih, gbhh,
                                              We, be, Wn, bn, gu, nu, out, t);
    }
}

// Round 7
// 983.500 us; speedup vs baseline: 5.8207x; 1.0328x over previous
//
#include <hip/hip_runtime.h>

#define Hdim 128
#define NN 10000
#define NE 320000
#define NG 16
#define EB 256          // edge rows per block (4 waves x 64 rows)
#define EBX 64          // xs rows per block (4 waves x 16 rows)
#define NB 64           // node rows per block
#define SXO 136         // LDS bf16 row stride

typedef __attribute__((ext_vector_type(8))) short bf8;   // 8 bf16 = 4 VGPRs
typedef __attribute__((ext_vector_type(4))) float f4;
#define MFMA16 __builtin_amdgcn_mfma_f32_16x16x32_bf16

#if __has_builtin(__builtin_amdgcn_exp2f)
#define EXP2F(x) __builtin_amdgcn_exp2f(x)
#else
#define EXP2F(x) exp2f(x)
#endif
#if __has_builtin(__builtin_amdgcn_rcpf)
#define RCPF(x) __builtin_amdgcn_rcpf(x)
#else
#define RCPF(x) (1.0f/(x))
#endif

__device__ __forceinline__ float fsigm(float x){
    return RCPF(1.0f + EXP2F(-1.442695041f*x));
}
__device__ __forceinline__ float ftanh(float x){
    float t = EXP2F(2.885390082f*x);          // e^(2x)
    return 1.0f - 2.0f*RCPF(t + 1.0f);        // (t-1)/(t+1)
}

__device__ __forceinline__ unsigned short f2bf(float v){
    unsigned int b = __float_as_uint(v);
    return (unsigned short)((b + 0x7FFFu + ((b>>16)&1u)) >> 16);
}
__device__ __forceinline__ float bf2f(unsigned short u){
    return __uint_as_float(((unsigned int)u)<<16);
}

__device__ __forceinline__ bf8 load_frag_f32(const float* __restrict__ p){
    float4 a = *(const float4*)p;
    float4 b = *(const float4*)(p+4);
    bf8 f;
    f[0]=(short)f2bf(a.x); f[1]=(short)f2bf(a.y); f[2]=(short)f2bf(a.z); f[3]=(short)f2bf(a.w);
    f[4]=(short)f2bf(b.x); f[5]=(short)f2bf(b.y); f[6]=(short)f2bf(b.z); f[7]=(short)f2bf(b.w);
    return f;
}

__device__ __forceinline__ bf8 load_pb(const unsigned short* __restrict__ P,
                                       int ntile, int ksteps, int kstep, int lane){
    return *(const bf8*)(P + ((((ntile*ksteps + kstep)<<6) + lane)<<3));
}

// ---------------------------------------------------------------- pack all B mats
struct PackJob { const float* s0; const float* s1; int ld, coloff, kr0, ktot, cnt, base; };
struct PackJobs { PackJob j[10]; };

__global__ __launch_bounds__(256) void pack_all(PackJobs P, unsigned short* __restrict__ dst)
{
    int idx = blockIdx.x*256 + threadIdx.x;
    #pragma unroll
    for (int t=0; t<10; ++t){
        int lo = P.j[t].base, hi = lo + P.j[t].cnt;
        if (idx >= lo && idx < hi){
            int l = idx - lo;
            int e    = l & 7;
            int lane = (l >> 3) & 63;
            int kt   = l >> 9;
            int ksteps = P.j[t].ktot >> 5;
            int ntile = kt / ksteps, kstep = kt - ntile*ksteps;
            int k = kstep*32 + ((lane>>4)<<3) + e;
            int n = ntile*16 + (lane&15);
            const float* S = (k < P.j[t].kr0) ? P.j[t].s0 : P.j[t].s1;
            int kk = (k < P.j[t].kr0) ? k : (k - P.j[t].kr0);
            dst[idx] = f2bf(S[(long)kk*P.j[t].ld + P.j[t].coloff + n]);
        }
    }
}

// ---------------------------------------------------------------- edge sort by dst
__global__ void hist_count(const int* __restrict__ dst, const int* __restrict__ batch,
                           int* __restrict__ histo, float* __restrict__ cnt){
    int e = blockIdx.x*256 + threadIdx.x;
    if (e < NE) atomicAdd(&histo[dst[e]], 1);
    if (e < NN) atomicAdd(&cnt[batch[e]], 1.0f);
}

__global__ __launch_bounds__(256) void scan_kernel(const int* __restrict__ histo,
                                                   int* __restrict__ cursor){
    __shared__ int ls[256];
    int t = threadIdx.x;
    int s = 0;
    #pragma unroll 8
    for (int i=0;i<40;++i){ int idx = t*40+i; if (idx < NN) s += histo[idx]; }
    ls[t] = s; __syncthreads();
    for (int off=1; off<256; off<<=1){
        int v = ls[t];
        if (t >= off) v += ls[t-off];
        __syncthreads();
        ls[t] = v; __syncthreads();
    }
    int run = ls[t] - s;
    for (int i=0;i<40;++i){
        int idx = t*40+i;
        if (idx < NN){ cursor[idx] = run; run += histo[idx]; }
    }
}

__global__ void scatter_kernel(const int* __restrict__ src, const int* __restrict__ dst,
                               int* __restrict__ cursor,
                               int* __restrict__ ssrc, int* __restrict__ sdst,
                               int* __restrict__ perm){
    int e = blockIdx.x*256 + threadIdx.x;
    if (e < NE){
        int d = dst[e];
        int p = atomicAdd(&cursor[d], 1);
        ssrc[p] = src[e]; sdst[p] = d; perm[p] = e;
    }
}

// ---------------------------------------------------------------- all f32->bf16 converts
__global__ __launch_bounds__(256) void conv_all(
    const float* __restrict__ ea_i, const int* __restrict__ perm,
    const float* __restrict__ x, const float* __restrict__ u,
    unsigned short* __restrict__ ea, unsigned short* __restrict__ xb,
    float* __restrict__ ucur)
{
    long idx = (long)blockIdx.x*256 + threadIdx.x;
    const long GE = (long)NE*16;
    const long GX = GE + (long)NN*16;
    if (idx < GE){
        long row = idx>>4; int c8 = (int)(idx&15);
        long srow = perm[row];
        *(bf8*)(ea + row*Hdim + c8*8) = load_frag_f32(ea_i + srow*Hdim + c8*8);
    } else if (idx < GX){
        long i2 = idx - GE; long row = i2>>4; int c8 = (int)(i2&15);
        *(bf8*)(xb + row*Hdim + c8*8) = load_frag_f32(x + row*Hdim + c8*8);
    } else {
        int i3 = (int)(idx - GX);   // 0..255
        *(float4*)(ucur + i3*8)   = *(const float4*)(u + i3*8);
        *(float4*)(ucur + i3*8+4) = *(const float4*)(u + i3*8+4);
    }
}

// ------------------------------------------- initial gu/nu (t=0), zero xsum
__global__ __launch_bounds__(128) void graph_pre_kernel(
    const float* __restrict__ u, const float* __restrict__ We, const float* __restrict__ be,
    const float* __restrict__ Wn, const float* __restrict__ bn,
    float* __restrict__ gu, float* __restrict__ nu, float* __restrict__ xsum)
{
    __shared__ float sU[Hdim];
    int b = blockIdx.x, which = b>>4, g = b&15, j = threadIdx.x;
    sU[j] = u[g*Hdim + j];
    if (b == 0){
        #pragma unroll
        for (int q=0;q<NG;++q) xsum[q*Hdim + j] = 0.f;
    }
    __syncthreads();
    const float* W = which ? (Wn + 256*Hdim) : (We + 384*Hdim);
    float a0 = which ? bn[j] : be[j], a1=0.f, a2=0.f, a3=0.f;
    for (int k=0;k<Hdim;k+=4){
        a0 = fmaf(sU[k+0], W[(k+0)*Hdim+j], a0);
        a1 = fmaf(sU[k+1], W[(k+1)*Hdim+j], a1);
        a2 = fmaf(sU[k+2], W[(k+2)*Hdim+j], a2);
        a3 = fmaf(sU[k+3], W[(k+3)*Hdim+j], a3);
    }
    (which ? nu : gu)[g*Hdim + j] = (a0+a1)+(a2+a3);
}

// ------------------------------------------- xs1g (bf16) = x@We1 + gu[batch]; zero agg
// 4 waves x 16 rows = 64 rows/block -> 157 blocks (spread)
__global__ __launch_bounds__(256,4) void xs_mfma(
    const unsigned short* __restrict__ xb, const unsigned short* __restrict__ PXS,
    const float* __restrict__ gu, const int* __restrict__ batch,
    unsigned short* __restrict__ xs1g, float* __restrict__ agg)
{
    int tid = threadIdx.x, lane = tid&63, wave = tid>>6;
    int nbB = blockIdx.x*EBX;
    int nb = nbB + wave*16;
    {
        long base = (long)nbB*Hdim;
        #pragma unroll
        for (int q=0;q<8;++q){
            long off = base + q*1024 + tid*4;
            if ((off>>7) < NN) *(float4*)(agg+off) = make_float4(0.f,0.f,0.f,0.f);
        }
    }
    int arow = lane&15, kg = lane>>4;
    int col = lane&15, crow = kg*4;
    bf8 xF[4];
    {
        int row = nb + arow; if (row > NN-1) row = NN-1;
        #pragma unroll
        for (int ks=0;ks<4;++ks)
            xF[ks] = *(const bf8*)(xb + (long)row*Hdim + ks*32 + kg*8);
    }
    int g0[4];
    #pragma unroll
    for (int r=0;r<4;++r){
        int ra = nb + crow + r; if (ra > NN-1) ra = NN-1;
        g0[r] = batch[ra];
    }
    #pragma unroll 2
    for (int nt=0; nt<8; ++nt){
        f4 acc = {0.f,0.f,0.f,0.f};
        #pragma unroll
        for (int ks=0;ks<4;++ks){
            bf8 b = load_pb(PXS, nt, 4, ks, lane);
            acc = MFMA16(xF[ks], b, acc, 0,0,0);
        }
        int j = nt*16 + col;
        #pragma unroll
        for (int r=0;r<4;++r){
            int row0 = nb + crow + r;
            if (row0 < NN) xs1g[(long)row0*Hdim + j] = f2bf(acc[r] + gu[g0[r]*Hdim + j]);
        }
    }
}

// ------------------------------------------- fused edge model + edge GRU (dst-sorted)
// gates write LDS only; one bulk coalesced full-line write of ea at the end
__global__ __launch_bounds__(256,2) void edge_mfma(
    unsigned short* __restrict__ ea,
    const unsigned short* __restrict__ xs1g, const unsigned short* __restrict__ xb,
    const unsigned short* __restrict__ PW1, const unsigned short* __restrict__ PX2,
    const unsigned short* __restrict__ PRZ,
    const unsigned short* __restrict__ PNI, const unsigned short* __restrict__ PNH,
    const float* __restrict__ bih, const float* __restrict__ bhh,
    const int* __restrict__ ssrc, const int* __restrict__ sdst,
    float* __restrict__ agg)
{
    __shared__ __align__(16) unsigned short sEo[EB*SXO];   // 69632 B
    __shared__ int sS[EB], sD[EB];
    int tid = threadIdx.x, lane = tid&63, wave = tid>>6;
    long eb = (long)blockIdx.x*EB;
    sS[tid] = ssrc[eb+tid]; sD[tid] = sdst[eb+tid];
    __syncthreads();
    int r0 = wave*64;
    int arow = lane&15, kg = lane>>4;
    int col = lane&15, crow = kg*4;
    bf8 eaF[4][4], xdF[4][4];
    #pragma unroll
    for (int m=0;m<4;++m){
        int lr = r0 + m*16 + arow;
        long drow = sD[lr];
        #pragma unroll
        for (int ks=0;ks<4;++ks){
            eaF[m][ks] = *(const bf8*)(ea + (eb + lr)*Hdim + ks*32 + kg*8);
            xdF[m][ks] = *(const bf8*)(xb + drow*Hdim + ks*32 + kg*8);
        }
    }
    // phase1: eo = relu(ea@We3 + xb[dst]@We2 + xs1g[src])
    #pragma unroll 1
    for (int nt=0; nt<8; ++nt){
        int j = nt*16 + col;
        f4 acc[4];
        #pragma unroll
        for (int m=0;m<4;++m)
            #pragma unroll
            for (int r=0;r<4;++r)
                acc[m][r] = bf2f(xs1g[(long)sS[r0 + m*16 + crow + r]*Hdim + j]);
        #pragma unroll
        for (int ks=0;ks<4;++ks){
            bf8 b = load_pb(PW1, nt, 4, ks, lane);
            #pragma unroll
            for (int m=0;m<4;++m) acc[m] = MFMA16(eaF[m][ks], b, acc[m], 0,0,0);
        }
        #pragma unroll
        for (int ks=0;ks<4;++ks){
            bf8 b = load_pb(PX2, nt, 4, ks, lane);
            #pragma unroll
            for (int m=0;m<4;++m) acc[m] = MFMA16(xdF[m][ks], b, acc[m], 0,0,0);
        }
        #pragma unroll
        for (int m=0;m<4;++m)
            #pragma unroll
            for (int r=0;r<4;++r)
                sEo[(r0 + m*16 + crow + r)*SXO + j] = f2bf(fmaxf(acc[m][r], 0.f));
    }
    bf8 eoF[4][4];
    #pragma unroll
    for (int m=0;m<4;++m)
        #pragma unroll
        for (int ks=0;ks<4;++ks)
            eoF[m][ks] = *(const bf8*)(sEo + (r0 + m*16 + arow)*SXO + ks*32 + kg*8);
    // gates -> write new state to sEo only (global write happens in bulk below)
    #pragma unroll 1
    for (int nt=0; nt<8; ++nt){
        int j = nt*16 + col;
        float vr = bih[j] + bhh[j];
        float vz = bih[128+j] + bhh[128+j];
        float vi = bih[256+j], vh = bhh[256+j];
        f4 ar[4], az[4], ai[4], ah[4];
        #pragma unroll
        for (int m=0;m<4;++m){
            ar[m] = (f4){vr,vr,vr,vr}; az[m] = (f4){vz,vz,vz,vz};
            ai[m] = (f4){vi,vi,vi,vi}; ah[m] = (f4){vh,vh,vh,vh};
        }
        #pragma unroll
        for (int ks=0;ks<8;++ks){
            bf8 bR = load_pb(PRZ, nt,   8, ks, lane);
            bf8 bZ = load_pb(PRZ, nt+8, 8, ks, lane);
            #pragma unroll
            for (int m=0;m<4;++m){
                bf8 A = (ks<4) ? eoF[m][ks] : eaF[m][ks-4];
                ar[m] = MFMA16(A, bR, ar[m], 0,0,0);
                az[m] = MFMA16(A, bZ, az[m], 0,0,0);
            }
        }
        #pragma unroll
        for (int ks=0;ks<4;++ks){
            bf8 bI = load_pb(PNI, nt, 4, ks, lane);
            bf8 bH = load_pb(PNH, nt, 4, ks, lane);
            #pragma unroll
            for (int m=0;m<4;++m){
                ai[m] = MFMA16(eoF[m][ks], bI, ai[m], 0,0,0);
                ah[m] = MFMA16(eaF[m][ks], bH, ah[m], 0,0,0);
            }
        }
        #pragma unroll
        for (int m=0;m<4;++m)
            #pragma unroll
            for (int r=0;r<4;++r){
                int lr = r0 + m*16 + crow + r;
                long grow = eb + lr;
                float h  = bf2f(ea[grow*Hdim + j]);
                float rr = fsigm(ar[m][r]);
                float zz = fsigm(az[m][r]);
                float nn = ftanh(fmaf(rr, ah[m][r], ai[m][r]));
                float o  = (1.0f - zz)*nn + zz*h;
                sEo[lr*SXO + j] = f2bf(o);
            }
    }
    __syncthreads();
    // bulk coalesced write of new state: full rows, full cache lines
    {
        #pragma unroll
        for (int q=0;q<16;++q){
            int idx = q*256 + tid;
            int row = idx >> 4, c8 = idx & 15;
            *(bf8*)(ea + (eb + row)*Hdim + c8*8) = *(const bf8*)(sEo + row*SXO + c8*8);
        }
    }
    // segmented column-sum over sorted dst runs
    {
        int j = tid & 127;
        int half = tid >> 7;
        int lo = half*128, hi = lo + 128;
        float acc = 0.f;
        for (int row=lo; row<hi; ++row){
            acc += bf2f(sEo[row*SXO + j]);
            bool flush = (row == hi-1) || (sD[row] != sD[row+1]);
            if (flush){
                atomicAdd(&agg[(long)sD[row]*Hdim + j], acc);
                acc = 0.f;
            }
        }
    }
}

// ------------------------------------------- fused node model + node GRU (bf16 state)
__global__ __launch_bounds__(256,4) void node_mfma(
    unsigned short* __restrict__ xb, const float* __restrict__ agg,
    const float* __restrict__ nu,
    const unsigned short* __restrict__ PP1, const unsigned short* __restrict__ PRZ,
    const unsigned short* __restrict__ PNI, const unsigned short* __restrict__ PNH,
    const float* __restrict__ bih, const float* __restrict__ bhh,
    const int* __restrict__ batch, float* __restrict__ xsum)
{
    __shared__ __align__(16) unsigned short sXo[NB*SXO];
    __shared__ int sG[NB];
    int tid = threadIdx.x, lane = tid&63, wave = tid>>6;
    int nb = blockIdx.x*NB;
    if (tid < NB){
        int row = nb + tid; if (row > NN-1) row = NN-1;
        sG[tid] = batch[row];
    }
    __syncthreads();
    int r0 = wave*16;                 // 16 rows per wave, 4 waves = 64 rows
    int arow = lane&15, kg = lane>>4;
    int col = lane&15, crow = kg*4;
    bf8 xF[4], agF[4];
    {
        int row = nb + r0 + arow; if (row > NN-1) row = NN-1;
        #pragma unroll
        for (int ks=0;ks<4;++ks){
            xF[ks]  = *(const bf8*)(xb + (long)row*Hdim + ks*32 + kg*8);
            agF[ks] = load_frag_f32(agg + (long)row*Hdim + ks*32 + kg*8);
        }
    }
    // phase1: xo = relu([x|agg]@Wn[0:256] + nu[g])
    #pragma unroll 2
    for (int nt=0; nt<8; ++nt){
        int j = nt*16 + col;
        f4 acc;
        #pragma unroll
        for (int r=0;r<4;++r)
            acc[r] = nu[sG[r0 + crow + r]*Hdim + j];
        #pragma unroll
        for (int ks=0;ks<8;++ks){
            bf8 A = (ks<4) ? xF[ks] : agF[ks-4];
            bf8 b = load_pb(PP1, nt, 8, ks, lane);
            acc = MFMA16(A, b, acc, 0,0,0);
        }
        #pragma unroll
        for (int r=0;r<4;++r)
            sXo[(r0 + crow + r)*SXO + j] = f2bf(fmaxf(acc[r], 0.f));
    }
    bf8 xoF[4];
    #pragma unroll
    for (int ks=0;ks<4;++ks)
        xoF[ks] = *(const bf8*)(sXo + (r0 + arow)*SXO + ks*32 + kg*8);
    #pragma unroll 1
    for (int nt=0; nt<8; ++nt){
        int j = nt*16 + col;
        float vr = bih[j] + bhh[j];
        float vz = bih[128+j] + bhh[128+j];
        float vi = bih[256+j], vh = bhh[256+j];
        f4 ar = {vr,vr,vr,vr}, az = {vz,vz,vz,vz};
        f4 ai = {vi,vi,vi,vi}, ah = {vh,vh,vh,vh};
        #pragma unroll
        for (int ks=0;ks<8;++ks){
            bf8 A = (ks<4) ? xoF[ks] : xF[ks-4];
            bf8 bR = load_pb(PRZ, nt,   8, ks, lane);
            bf8 bZ = load_pb(PRZ, nt+8, 8, ks, lane);
            ar = MFMA16(A, bR, ar, 0,0,0);
            az = MFMA16(A, bZ, az, 0,0,0);
        }
        #pragma unroll
        for (int ks=0;ks<4;++ks){
            bf8 bI = load_pb(PNI, nt, 4, ks, lane);
            bf8 bH = load_pb(PNH, nt, 4, ks, lane);
            ai = MFMA16(xoF[ks], bI, ai, 0,0,0);
            ah = MFMA16(xF[ks],  bH, ah, 0,0,0);
        }
        #pragma unroll
        for (int r=0;r<4;++r){
            int lr = r0 + crow + r;
            int row = nb + lr;
            unsigned short ob = 0;
            if (row < NN){
                float h  = bf2f(xb[(long)row*Hdim + j]);
                float rr = fsigm(ar[r]);
                float zz = fsigm(az[r]);
                float nn = ftanh(fmaf(rr, ah[r], ai[r]));
                float o  = (1.0f - zz)*nn + zz*h;
                ob = f2bf(o);
            }
            sXo[lr*SXO + j] = ob;
        }
    }
    __syncthreads();
    // bulk coalesced write of new node state
    {
        #pragma unroll
        for (int q=0;q<4;++q){
            int idx = q*256 + tid;
            int row = idx >> 4, c8 = idx & 15;
            int grow = nb + row;
            if (grow < NN)
                *(bf8*)(xb + (long)grow*Hdim + c8*8) = *(const bf8*)(sXo + row*SXO + c8*8);
        }
    }
    // segmented column-sum over sorted batch runs -> xsum
    {
        int j = tid & 127;
        int half = tid >> 7;
        int lo = half*32, hi = lo + 32;
        float acc = 0.f;
        for (int row=lo; row<hi; ++row){
            acc += bf2f(sXo[row*SXO + j]);
            bool flush = (row == hi-1) || (sG[row] != sG[row+1]);
            if (flush){
                atomicAdd(&xsum[sG[row]*Hdim + j], acc);
                acc = 0.f;
            }
        }
    }
}

// ------------------------------------------- global model + GRU + next-step gu/nu
__global__ __launch_bounds__(128) void global_kernel(
    float* __restrict__ xsum, const float* __restrict__ cnt,
    float* __restrict__ u,
    const float* __restrict__ Wg, const float* __restrict__ bg,
    const float* __restrict__ Wih, const float* __restrict__ Whh,
    const float* __restrict__ bih, const float* __restrict__ bhh,
    const float* __restrict__ We, const float* __restrict__ be,
    const float* __restrict__ Wn, const float* __restrict__ bn,
    float* __restrict__ gu, float* __restrict__ nu,
    float* __restrict__ out, int step)
{
    __shared__ float sXm[Hdim], sU[Hdim], sUo[Hdim], sO[Hdim];
    int g = blockIdx.x, j = threadIdx.x;
    float inv = 1.0f / fmaxf(cnt[g], 1.0f);
    sXm[j] = xsum[g*Hdim + j] * inv;
    xsum[g*Hdim + j] = 0.f;
    float hj = u[g*Hdim + j];
    sU[j] = hj;
    __syncthreads();
    float a = bg[j];
    for (int k=0;k<Hdim;++k){
        a = fmaf(sXm[k], Wg[k*Hdim + j], a);
        a = fmaf(sU[k],  Wg[(128+k)*Hdim + j], a);
    }
    sUo[j] = fmaxf(a, 0.f);
    __syncthreads();
    float r = bih[j]+bhh[j], z = bih[128+j]+bhh[128+j];
    float ni = bih[256+j], nh = bhh[256+j];
    for (int k=0;k<Hdim;++k){
        float in = sUo[k], h = sU[k];
        r  = fmaf(in, Wih[k*384 + j],       r);
        r  = fmaf(h,  Whh[k*384 + j],       r);
        z  = fmaf(in, Wih[k*384 + 128 + j], z);
        z  = fmaf(h,  Whh[k*384 + 128 + j], z);
        ni = fmaf(in, Wih[k*384 + 256 + j], ni);
        nh = fmaf(h,  Whh[k*384 + 256 + j], nh);
    }
    float rr = fsigm(r), zz = fsigm(z);
    float n = ftanh(fmaf(rr, nh, ni));
    float o = (1.0f - zz)*n + zz*hj;
    u[g*Hdim + j] = o;
    out[(long)(g*3 + step)*Hdim + j] = o;
    sO[j] = o;
    __syncthreads();
    float a0 = be[j], a1 = bn[j];
    for (int k=0;k<Hdim;++k){
        float v = sO[k];
        a0 = fmaf(v, We[(384+k)*Hdim + j], a0);
        a1 = fmaf(v, Wn[(256+k)*Hdim + j], a1);
    }
    gu[g*Hdim + j] = a0;
    nu[g*Hdim + j] = a1;
}

// ---------------------------------------------------------------- host
extern "C" void kernel_launch(void* const* d_in, const int* in_sizes, int n_in,
                              void* d_out, int out_size, void* d_ws, size_t ws_size,
                              hipStream_t stream)
{
    const float* x    = (const float*)d_in[0];
    const float* ea_i = (const float*)d_in[1];
    const float* u    = (const float*)d_in[2];
    const float* We   = (const float*)d_in[3];
    const float* be   = (const float*)d_in[4];
    const float* Wn   = (const float*)d_in[5];
    const float* bn   = (const float*)d_in[6];
    const float* Wg   = (const float*)d_in[7];
    const float* bg   = (const float*)d_in[8];
    const float* eWih = (const float*)d_in[9];
    const float* eWhh = (const float*)d_in[10];
    const float* ebih = (const float*)d_in[11];
    const float* ebhh = (const float*)d_in[12];
    const float* nWih = (const float*)d_in[13];
    const float* nWhh = (const float*)d_in[14];
    const float* nbih = (const float*)d_in[15];
    const float* nbhh = (const float*)d_in[16];
    const float* gWih = (const float*)d_in[17];
    const float* gWhh = (const float*)d_in[18];
    const float* gbih = (const float*)d_in[19];
    const float* gbhh = (const float*)d_in[20];
    const int*   ei   = (const int*)d_in[21];
    const int*   batch= (const int*)d_in[22];
    const int* src = ei;
    const int* dst = ei + NE;
    float* out = (float*)d_out;

    size_t off = 0;
    auto alloc = [&](size_t bytes)->char*{
        char* p = (char*)d_ws + off;
        off += (bytes + 255) & ~(size_t)255;
        return p;
    };
    unsigned short* ea   = (unsigned short*)alloc((size_t)NE*Hdim*2);
    unsigned short* xb   = (unsigned short*)alloc((size_t)NN*Hdim*2);
    unsigned short* xs1g = (unsigned short*)alloc((size_t)NN*Hdim*2);
    float*          agg  = (float*)alloc((size_t)NN*Hdim*4);
    float*          ucur = (float*)alloc((size_t)NG*Hdim*4);
    float*          gu   = (float*)alloc((size_t)NG*Hdim*4);
    float*          nu   = (float*)alloc((size_t)NG*Hdim*4);
    float*          xsum = (float*)alloc((size_t)NG*Hdim*4);
    unsigned short* PK   = (unsigned short*)alloc((size_t)278528*2);
    int* histo  = (int*)alloc((size_t)(NN+NG)*4);
    float* cnt  = (float*)(histo + NN);
    int* cursor = (int*)alloc((size_t)NN*4);
    int* ssrc   = (int*)alloc((size_t)NE*4);
    int* sdst   = (int*)alloc((size_t)NE*4);
    int* perm   = (int*)alloc((size_t)NE*4);

    unsigned short* PXS  = PK + 0;        // We1
    unsigned short* PX2  = PK + 16384;    // We2
    unsigned short* PW1  = PK + 32768;    // We3
    unsigned short* PeRZ = PK + 49152;
    unsigned short* PeNI = PK + 114688;
    unsigned short* PeNH = PK + 131072;
    unsigned short* PnP1 = PK + 147456;
    unsigned short* PnRZ = PK + 180224;
    unsigned short* PnNI = PK + 245760;
    unsigned short* PnNH = PK + 262144;

    hipMemsetAsync(histo, 0, (size_t)(NN+NG)*4, stream);
    hist_count<<<(NE+255)/256, 256, 0, stream>>>(dst, batch, histo, cnt);
    scan_kernel<<<1, 256, 0, stream>>>(histo, cursor);
    scatter_kernel<<<(NE+255)/256, 256, 0, stream>>>(src, dst, cursor, ssrc, sdst, perm);
    {
        long groups = (long)(NE+NN+NG)*16;
        conv_all<<<(int)((groups+255)/256), 256, 0, stream>>>(ea_i, perm, x, u, ea, xb, ucur);
    }

    PackJobs PJ;
    auto setj = [&](int t, const float* s0, const float* s1, int ld, int coloff,
                    int kr0, int ktot, int ntot, int base){
        PJ.j[t] = PackJob{ s0, s1, ld, coloff, kr0, ktot, ktot*ntot, base };
    };
    setj(0, We,            We,   Hdim, 0,   128, 128, 128, 0);
    setj(1, We+128*Hdim,   We,   Hdim, 0,   128, 128, 128, 16384);
    setj(2, We+256*Hdim,   We,   Hdim, 0,   128, 128, 128, 32768);
    setj(3, eWih, eWhh, 384, 0,   128, 256, 256, 49152);
    setj(4, eWih, eWih, 384, 256, 128, 128, 128, 114688);
    setj(5, eWhh, eWhh, 384, 256, 128, 128, 128, 131072);
    setj(6, Wn,   Wn,   Hdim, 0,  256, 256, 128, 147456);
    setj(7, nWih, nWhh, 384, 0,   128, 256, 256, 180224);
    setj(8, nWih, nWih, 384, 256, 128, 128, 128, 245760);
    setj(9, nWhh, nWhh, 384, 256, 128, 128, 128, 262144);
    pack_all<<<278528/256, 256, 0, stream>>>(PJ, PK);

    graph_pre_kernel<<<32, 128, 0, stream>>>(ucur, We, be, Wn, bn, gu, nu, xsum);

    for (int t=0; t<3; ++t){
        xs_mfma<<<(NN+EBX-1)/EBX, 256, 0, stream>>>(xb, PXS, gu, batch, xs1g, agg);
        edge_mfma<<<NE/EB, 256, 0, stream>>>(ea, xs1g, xb, PW1, PX2, PeRZ, PeNI, PeNH,
                                             ebih, ebhh, ssrc, sdst, agg);
        node_mfma<<<(NN+NB-1)/NB, 256, 0, stream>>>(xb, agg, nu, PnP1, PnRZ, PnNI, PnNH,
                                                    nbih, nbhh, batch, xsum);
        global_kernel<<<NG, 128, 0, stream>>>(xsum, cnt, ucur, Wg, bg,
                                              gWih, gWhh, gbih, gbhh,
                                              We, be, Wn, bn, gu, nu, out, t);
    }
}

// Round 8
// 977.454 us; speedup vs baseline: 5.8567x; 1.0062x over previous
//
#include <hip/hip_runtime.h>

#define Hdim 128
#define NN 10000
#define NE 320000
#define NG 16
#define EB 256          // edge rows per block (4 waves x 64 rows)
#define EBX 64          // xs rows per block (4 waves x 16 rows)
#define NB 64           // node rows per block
#define SXO 136         // LDS bf16 row stride

typedef __attribute__((ext_vector_type(8))) short bf8;   // 8 bf16 = 4 VGPRs
typedef __attribute__((ext_vector_type(4))) float f4;
#define MFMA16 __builtin_amdgcn_mfma_f32_16x16x32_bf16

#if __has_builtin(__builtin_amdgcn_exp2f)
#define EXP2F(x) __builtin_amdgcn_exp2f(x)
#else
#define EXP2F(x) exp2f(x)
#endif
#if __has_builtin(__builtin_amdgcn_rcpf)
#define RCPF(x) __builtin_amdgcn_rcpf(x)
#else
#define RCPF(x) (1.0f/(x))
#endif

__device__ __forceinline__ float fsigm(float x){
    return RCPF(1.0f + EXP2F(-1.442695041f*x));
}
__device__ __forceinline__ float ftanh(float x){
    float t = EXP2F(2.885390082f*x);          // e^(2x)
    return 1.0f - 2.0f*RCPF(t + 1.0f);        // (t-1)/(t+1)
}

__device__ __forceinline__ unsigned short f2bf(float v){
    unsigned int b = __float_as_uint(v);
    return (unsigned short)((b + 0x7FFFu + ((b>>16)&1u)) >> 16);
}
__device__ __forceinline__ float bf2f(unsigned short u){
    return __uint_as_float(((unsigned int)u)<<16);
}

__device__ __forceinline__ bf8 load_frag_f32(const float* __restrict__ p){
    float4 a = *(const float4*)p;
    float4 b = *(const float4*)(p+4);
    bf8 f;
    f[0]=(short)f2bf(a.x); f[1]=(short)f2bf(a.y); f[2]=(short)f2bf(a.z); f[3]=(short)f2bf(a.w);
    f[4]=(short)f2bf(b.x); f[5]=(short)f2bf(b.y); f[6]=(short)f2bf(b.z); f[7]=(short)f2bf(b.w);
    return f;
}

__device__ __forceinline__ bf8 load_pb(const unsigned short* __restrict__ P,
                                       int ntile, int ksteps, int kstep, int lane){
    return *(const bf8*)(P + ((((ntile*ksteps + kstep)<<6) + lane)<<3));
}

// ---------------------------------------------------------------- pack all B mats
struct PackJob { const float* s0; const float* s1; int ld, coloff, kr0, ktot, cnt, base; };
struct PackJobs { PackJob j[10]; };

__global__ __launch_bounds__(256) void pack_all(PackJobs P, unsigned short* __restrict__ dst)
{
    int idx = blockIdx.x*256 + threadIdx.x;
    #pragma unroll
    for (int t=0; t<10; ++t){
        int lo = P.j[t].base, hi = lo + P.j[t].cnt;
        if (idx >= lo && idx < hi){
            int l = idx - lo;
            int e    = l & 7;
            int lane = (l >> 3) & 63;
            int kt   = l >> 9;
            int ksteps = P.j[t].ktot >> 5;
            int ntile = kt / ksteps, kstep = kt - ntile*ksteps;
            int k = kstep*32 + ((lane>>4)<<3) + e;
            int n = ntile*16 + (lane&15);
            const float* S = (k < P.j[t].kr0) ? P.j[t].s0 : P.j[t].s1;
            int kk = (k < P.j[t].kr0) ? k : (k - P.j[t].kr0);
            dst[idx] = f2bf(S[(long)kk*P.j[t].ld + P.j[t].coloff + n]);
        }
    }
}

// ---------------------------------------------------------------- edge sort by dst
__global__ void hist_count(const int* __restrict__ dst, const int* __restrict__ batch,
                           int* __restrict__ histo, float* __restrict__ cnt){
    int e = blockIdx.x*256 + threadIdx.x;
    if (e < NE) atomicAdd(&histo[dst[e]], 1);
    if (e < NN) atomicAdd(&cnt[batch[e]], 1.0f);
}

__global__ __launch_bounds__(256) void scan_kernel(const int* __restrict__ histo,
                                                   int* __restrict__ cursor){
    __shared__ int ls[256];
    int t = threadIdx.x;
    int s = 0;
    #pragma unroll 8
    for (int i=0;i<40;++i){ int idx = t*40+i; if (idx < NN) s += histo[idx]; }
    ls[t] = s; __syncthreads();
    for (int off=1; off<256; off<<=1){
        int v = ls[t];
        if (t >= off) v += ls[t-off];
        __syncthreads();
        ls[t] = v; __syncthreads();
    }
    int run = ls[t] - s;
    for (int i=0;i<40;++i){
        int idx = t*40+i;
        if (idx < NN){ cursor[idx] = run; run += histo[idx]; }
    }
}

__global__ void scatter_kernel(const int* __restrict__ src, const int* __restrict__ dst,
                               int* __restrict__ cursor,
                               int* __restrict__ ssrc, int* __restrict__ sdst,
                               int* __restrict__ perm){
    int e = blockIdx.x*256 + threadIdx.x;
    if (e < NE){
        int d = dst[e];
        int p = atomicAdd(&cursor[d], 1);
        ssrc[p] = src[e]; sdst[p] = d; perm[p] = e;
    }
}

// ---------------------------------------------------------------- all f32->bf16 converts
__global__ __launch_bounds__(256) void conv_all(
    const float* __restrict__ ea_i, const int* __restrict__ perm,
    const float* __restrict__ x, const float* __restrict__ u,
    unsigned short* __restrict__ ea, unsigned short* __restrict__ xb,
    float* __restrict__ ucur)
{
    long idx = (long)blockIdx.x*256 + threadIdx.x;
    const long GE = (long)NE*16;
    const long GX = GE + (long)NN*16;
    if (idx < GE){
        long row = idx>>4; int c8 = (int)(idx&15);
        long srow = perm[row];
        *(bf8*)(ea + row*Hdim + c8*8) = load_frag_f32(ea_i + srow*Hdim + c8*8);
    } else if (idx < GX){
        long i2 = idx - GE; long row = i2>>4; int c8 = (int)(i2&15);
        *(bf8*)(xb + row*Hdim + c8*8) = load_frag_f32(x + row*Hdim + c8*8);
    } else {
        int i3 = (int)(idx - GX);   // 0..255
        *(float4*)(ucur + i3*8)   = *(const float4*)(u + i3*8);
        *(float4*)(ucur + i3*8+4) = *(const float4*)(u + i3*8+4);
    }
}

// ------------------------------------------- initial gu/nu (t=0), zero xsum
__global__ __launch_bounds__(128) void graph_pre_kernel(
    const float* __restrict__ u, const float* __restrict__ We, const float* __restrict__ be,
    const float* __restrict__ Wn, const float* __restrict__ bn,
    float* __restrict__ gu, float* __restrict__ nu, float* __restrict__ xsum)
{
    __shared__ float sU[Hdim];
    int b = blockIdx.x, which = b>>4, g = b&15, j = threadIdx.x;
    sU[j] = u[g*Hdim + j];
    if (b == 0){
        #pragma unroll
        for (int q=0;q<NG;++q) xsum[q*Hdim + j] = 0.f;
    }
    __syncthreads();
    const float* W = which ? (Wn + 256*Hdim) : (We + 384*Hdim);
    float a0 = which ? bn[j] : be[j], a1=0.f, a2=0.f, a3=0.f;
    for (int k=0;k<Hdim;k+=4){
        a0 = fmaf(sU[k+0], W[(k+0)*Hdim+j], a0);
        a1 = fmaf(sU[k+1], W[(k+1)*Hdim+j], a1);
        a2 = fmaf(sU[k+2], W[(k+2)*Hdim+j], a2);
        a3 = fmaf(sU[k+3], W[(k+3)*Hdim+j], a3);
    }
    (which ? nu : gu)[g*Hdim + j] = (a0+a1)+(a2+a3);
}

// ------------------------------------------- xs1g (bf16) = x@We1 + gu[batch]; zero agg
__global__ __launch_bounds__(256,4) void xs_mfma(
    const unsigned short* __restrict__ xb, const unsigned short* __restrict__ PXS,
    const float* __restrict__ gu, const int* __restrict__ batch,
    unsigned short* __restrict__ xs1g, float* __restrict__ agg)
{
    int tid = threadIdx.x, lane = tid&63, wave = tid>>6;
    int nbB = blockIdx.x*EBX;
    int nb = nbB + wave*16;
    {
        long base = (long)nbB*Hdim;
        #pragma unroll
        for (int q=0;q<8;++q){
            long off = base + q*1024 + tid*4;
            if ((off>>7) < NN) *(float4*)(agg+off) = make_float4(0.f,0.f,0.f,0.f);
        }
    }
    int arow = lane&15, kg = lane>>4;
    int col = lane&15, crow = kg*4;
    bf8 xF[4];
    {
        int row = nb + arow; if (row > NN-1) row = NN-1;
        #pragma unroll
        for (int ks=0;ks<4;++ks)
            xF[ks] = *(const bf8*)(xb + (long)row*Hdim + ks*32 + kg*8);
    }
    int g0[4];
    #pragma unroll
    for (int r=0;r<4;++r){
        int ra = nb + crow + r; if (ra > NN-1) ra = NN-1;
        g0[r] = batch[ra];
    }
    #pragma unroll 2
    for (int nt=0; nt<8; ++nt){
        f4 acc = {0.f,0.f,0.f,0.f};
        #pragma unroll
        for (int ks=0;ks<4;++ks){
            bf8 b = load_pb(PXS, nt, 4, ks, lane);
            acc = MFMA16(xF[ks], b, acc, 0,0,0);
        }
        int j = nt*16 + col;
        #pragma unroll
        for (int r=0;r<4;++r){
            int row0 = nb + crow + r;
            if (row0 < NN) xs1g[(long)row0*Hdim + j] = f2bf(acc[r] + gu[g0[r]*Hdim + j]);
        }
    }
}

// ------------------------------------------- fused edge model + edge GRU (dst-sorted)
// h comes from LDS (eaF stashed over dead eo buffer) instead of global re-read
__global__ __launch_bounds__(256,2) void edge_mfma(
    unsigned short* __restrict__ ea,
    const unsigned short* __restrict__ xs1g, const unsigned short* __restrict__ xb,
    const unsigned short* __restrict__ PW1, const unsigned short* __restrict__ PX2,
    const unsigned short* __restrict__ PRZ,
    const unsigned short* __restrict__ PNI, const unsigned short* __restrict__ PNH,
    const float* __restrict__ bih, const float* __restrict__ bhh,
    const int* __restrict__ ssrc, const int* __restrict__ sdst,
    float* __restrict__ agg)
{
    __shared__ __align__(16) unsigned short sEo[EB*SXO];   // 69632 B
    __shared__ int sS[EB], sD[EB];
    int tid = threadIdx.x, lane = tid&63, wave = tid>>6;
    long eb = (long)blockIdx.x*EB;
    sS[tid] = ssrc[eb+tid]; sD[tid] = sdst[eb+tid];
    __syncthreads();
    int r0 = wave*64;
    int arow = lane&15, kg = lane>>4;
    int col = lane&15, crow = kg*4;
    bf8 eaF[4][4], xdF[4][4];
    #pragma unroll
    for (int m=0;m<4;++m){
        int lr = r0 + m*16 + arow;
        long drow = sD[lr];
        #pragma unroll
        for (int ks=0;ks<4;++ks){
            eaF[m][ks] = *(const bf8*)(ea + (eb + lr)*Hdim + ks*32 + kg*8);
            xdF[m][ks] = *(const bf8*)(xb + drow*Hdim + ks*32 + kg*8);
        }
    }
    // phase1: eo = relu(ea@We3 + xb[dst]@We2 + xs1g[src])
    // xs1g gather moved to epilogue so MFMAs issue immediately
    #pragma unroll 1
    for (int nt=0; nt<8; ++nt){
        int j = nt*16 + col;
        f4 acc[4];
        #pragma unroll
        for (int m=0;m<4;++m) acc[m] = (f4){0.f,0.f,0.f,0.f};
        #pragma unroll
        for (int ks=0;ks<4;++ks){
            bf8 b = load_pb(PW1, nt, 4, ks, lane);
            #pragma unroll
            for (int m=0;m<4;++m) acc[m] = MFMA16(eaF[m][ks], b, acc[m], 0,0,0);
        }
        #pragma unroll
        for (int ks=0;ks<4;++ks){
            bf8 b = load_pb(PX2, nt, 4, ks, lane);
            #pragma unroll
            for (int m=0;m<4;++m) acc[m] = MFMA16(xdF[m][ks], b, acc[m], 0,0,0);
        }
        #pragma unroll
        for (int m=0;m<4;++m)
            #pragma unroll
            for (int r=0;r<4;++r){
                int lr = r0 + m*16 + crow + r;
                float x1 = bf2f(xs1g[(long)sS[lr]*Hdim + j]);
                sEo[lr*SXO + j] = f2bf(fmaxf(acc[m][r] + x1, 0.f));
            }
    }
    bf8 eoF[4][4];
    #pragma unroll
    for (int m=0;m<4;++m)
        #pragma unroll
        for (int ks=0;ks<4;++ks)
            eoF[m][ks] = *(const bf8*)(sEo + (r0 + m*16 + arow)*SXO + ks*32 + kg*8);
    // stash h (eaF) over the dead eo buffer; lane reads-then-writes its OWN address,
    // cross-lane reads below are same-wave (compiler inserts lgkmcnt, proven pattern)
    #pragma unroll
    for (int m=0;m<4;++m)
        #pragma unroll
        for (int ks=0;ks<4;++ks)
            *(bf8*)(sEo + (r0 + m*16 + arow)*SXO + ks*32 + kg*8) = eaF[m][ks];
    // gates -> write new state to sEo only (global write happens in bulk below)
    #pragma unroll 1
    for (int nt=0; nt<8; ++nt){
        int j = nt*16 + col;
        float vr = bih[j] + bhh[j];
        float vz = bih[128+j] + bhh[128+j];
        float vi = bih[256+j], vh = bhh[256+j];
        f4 ar[4], az[4], ai[4], ah[4];
        #pragma unroll
        for (int m=0;m<4;++m){
            ar[m] = (f4){vr,vr,vr,vr}; az[m] = (f4){vz,vz,vz,vz};
            ai[m] = (f4){vi,vi,vi,vi}; ah[m] = (f4){vh,vh,vh,vh};
        }
        #pragma unroll
        for (int ks=0;ks<8;++ks){
            bf8 bR = load_pb(PRZ, nt,   8, ks, lane);
            bf8 bZ = load_pb(PRZ, nt+8, 8, ks, lane);
            #pragma unroll
            for (int m=0;m<4;++m){
                bf8 A = (ks<4) ? eoF[m][ks] : eaF[m][ks-4];
                ar[m] = MFMA16(A, bR, ar[m], 0,0,0);
                az[m] = MFMA16(A, bZ, az[m], 0,0,0);
            }
        }
        #pragma unroll
        for (int ks=0;ks<4;++ks){
            bf8 bI = load_pb(PNI, nt, 4, ks, lane);
            bf8 bH = load_pb(PNH, nt, 4, ks, lane);
            #pragma unroll
            for (int m=0;m<4;++m){
                ai[m] = MFMA16(eoF[m][ks], bI, ai[m], 0,0,0);
                ah[m] = MFMA16(eaF[m][ks], bH, ah[m], 0,0,0);
            }
        }
        #pragma unroll
        for (int m=0;m<4;++m)
            #pragma unroll
            for (int r=0;r<4;++r){
                int lr = r0 + m*16 + crow + r;
                float h  = bf2f(sEo[lr*SXO + j]);   // h from LDS stash
                float rr = fsigm(ar[m][r]);
                float zz = fsigm(az[m][r]);
                float nn = ftanh(fmaf(rr, ah[m][r], ai[m][r]));
                float o  = (1.0f - zz)*nn + zz*h;
                sEo[lr*SXO + j] = f2bf(o);          // overwrite h (same owner thread)
            }
    }
    __syncthreads();
    // bulk coalesced write of new state: full rows, full cache lines
    {
        #pragma unroll
        for (int q=0;q<16;++q){
            int idx = q*256 + tid;
            int row = idx >> 4, c8 = idx & 15;
            *(bf8*)(ea + (eb + row)*Hdim + c8*8) = *(const bf8*)(sEo + row*SXO + c8*8);
        }
    }
    // segmented column-sum over sorted dst runs
    {
        int j = tid & 127;
        int half = tid >> 7;
        int lo = half*128, hi = lo + 128;
        float acc = 0.f;
        for (int row=lo; row<hi; ++row){
            acc += bf2f(sEo[row*SXO + j]);
            bool flush = (row == hi-1) || (sD[row] != sD[row+1]);
            if (flush){
                atomicAdd(&agg[(long)sD[row]*Hdim + j], acc);
                acc = 0.f;
            }
        }
    }
}

// ------------------------------------------- fused node model + node GRU (bf16 state)
__global__ __launch_bounds__(256,4) void node_mfma(
    unsigned short* __restrict__ xb, const float* __restrict__ agg,
    const float* __restrict__ nu,
    const unsigned short* __restrict__ PP1, const unsigned short* __restrict__ PRZ,
    const unsigned short* __restrict__ PNI, const unsigned short* __restrict__ PNH,
    const float* __restrict__ bih, const float* __restrict__ bhh,
    const int* __restrict__ batch, float* __restrict__ xsum)
{
    __shared__ __align__(16) unsigned short sXo[NB*SXO];
    __shared__ int sG[NB];
    int tid = threadIdx.x, lane = tid&63, wave = tid>>6;
    int nb = blockIdx.x*NB;
    if (tid < NB){
        int row = nb + tid; if (row > NN-1) row = NN-1;
        sG[tid] = batch[row];
    }
    __syncthreads();
    int r0 = wave*16;                 // 16 rows per wave, 4 waves = 64 rows
    int arow = lane&15, kg = lane>>4;
    int col = lane&15, crow = kg*4;
    bf8 xF[4], agF[4];
    {
        int row = nb + r0 + arow; if (row > NN-1) row = NN-1;
        #pragma unroll
        for (int ks=0;ks<4;++ks){
            xF[ks]  = *(const bf8*)(xb + (long)row*Hdim + ks*32 + kg*8);
            agF[ks] = load_frag_f32(agg + (long)row*Hdim + ks*32 + kg*8);
        }
    }
    // phase1: xo = relu([x|agg]@Wn[0:256] + nu[g]); nu add moved to epilogue
    #pragma unroll 2
    for (int nt=0; nt<8; ++nt){
        int j = nt*16 + col;
        f4 acc = {0.f,0.f,0.f,0.f};
        #pragma unroll
        for (int ks=0;ks<8;++ks){
            bf8 A = (ks<4) ? xF[ks] : agF[ks-4];
            bf8 b = load_pb(PP1, nt, 8, ks, lane);
            acc = MFMA16(A, b, acc, 0,0,0);
        }
        #pragma unroll
        for (int r=0;r<4;++r){
            float nv = nu[sG[r0 + crow + r]*Hdim + j];
            sXo[(r0 + crow + r)*SXO + j] = f2bf(fmaxf(acc[r] + nv, 0.f));
        }
    }
    bf8 xoF[4];
    #pragma unroll
    for (int ks=0;ks<4;++ks)
        xoF[ks] = *(const bf8*)(sXo + (r0 + arow)*SXO + ks*32 + kg*8);
    // stash h (xF) over dead xo buffer
    #pragma unroll
    for (int ks=0;ks<4;++ks)
        *(bf8*)(sXo + (r0 + arow)*SXO + ks*32 + kg*8) = xF[ks];
    #pragma unroll 1
    for (int nt=0; nt<8; ++nt){
        int j = nt*16 + col;
        float vr = bih[j] + bhh[j];
        float vz = bih[128+j] + bhh[128+j];
        float vi = bih[256+j], vh = bhh[256+j];
        f4 ar = {vr,vr,vr,vr}, az = {vz,vz,vz,vz};
        f4 ai = {vi,vi,vi,vi}, ah = {vh,vh,vh,vh};
        #pragma unroll
        for (int ks=0;ks<8;++ks){
            bf8 A = (ks<4) ? xoF[ks] : xF[ks-4];
            bf8 bR = load_pb(PRZ, nt,   8, ks, lane);
            bf8 bZ = load_pb(PRZ, nt+8, 8, ks, lane);
            ar = MFMA16(A, bR, ar, 0,0,0);
            az = MFMA16(A, bZ, az, 0,0,0);
        }
        #pragma unroll
        for (int ks=0;ks<4;++ks){
            bf8 bI = load_pb(PNI, nt, 4, ks, lane);
            bf8 bH = load_pb(PNH, nt, 4, ks, lane);
            ai = MFMA16(xoF[ks], bI, ai, 0,0,0);
            ah = MFMA16(xF[ks],  bH, ah, 0,0,0);
        }
        #pragma unroll
        for (int r=0;r<4;++r){
            int lr = r0 + crow + r;
            int row = nb + lr;
            unsigned short ob = 0;
            if (row < NN){
                float h  = bf2f(sXo[lr*SXO + j]);   // h from LDS stash
                float rr = fsigm(ar[r]);
                float zz = fsigm(az[r]);
                float nn = ftanh(fmaf(rr, ah[r], ai[r]));
                float o  = (1.0f - zz)*nn + zz*h;
                ob = f2bf(o);
            }
            sXo[lr*SXO + j] = ob;
        }
    }
    __syncthreads();
    // bulk coalesced write of new node state
    {
        #pragma unroll
        for (int q=0;q<4;++q){
            int idx = q*256 + tid;
            int row = idx >> 4, c8 = idx & 15;
            int grow = nb + row;
            if (grow < NN)
                *(bf8*)(xb + (long)grow*Hdim + c8*8) = *(const bf8*)(sXo + row*SXO + c8*8);
        }
    }
    // segmented column-sum over sorted batch runs -> xsum
    {
        int j = tid & 127;
        int half = tid >> 7;
        int lo = half*32, hi = lo + 32;
        float acc = 0.f;
        for (int row=lo; row<hi; ++row){
            acc += bf2f(sXo[row*SXO + j]);
            bool flush = (row == hi-1) || (sG[row] != sG[row+1]);
            if (flush){
                atomicAdd(&xsum[sG[row]*Hdim + j], acc);
                acc = 0.f;
            }
        }
    }
}

// ------------------------------------------- global model + GRU + next-step gu/nu
// 4-way independent accumulators cut the serial fmaf chains 4x
__global__ __launch_bounds__(128) void global_kernel(
    float* __restrict__ xsum, const float* __restrict__ cnt,
    float* __restrict__ u,
    const float* __restrict__ Wg, const float* __restrict__ bg,
    const float* __restrict__ Wih, const float* __restrict__ Whh,
    const float* __restrict__ bih, const float* __restrict__ bhh,
    const float* __restrict__ We, const float* __restrict__ be,
    const float* __restrict__ Wn, const float* __restrict__ bn,
    float* __restrict__ gu, float* __restrict__ nu,
    float* __restrict__ out, int step)
{
    __shared__ float sXm[Hdim], sU[Hdim], sUo[Hdim], sO[Hdim];
    int g = blockIdx.x, j = threadIdx.x;
    float inv = 1.0f / fmaxf(cnt[g], 1.0f);
    sXm[j] = xsum[g*Hdim + j] * inv;
    xsum[g*Hdim + j] = 0.f;
    float hj = u[g*Hdim + j];
    sU[j] = hj;
    __syncthreads();
    {
        float a0=bg[j], a1=0.f, a2=0.f, a3=0.f;
        for (int k=0;k<Hdim;k+=4){
            a0 = fmaf(sXm[k+0], Wg[(k+0)*Hdim + j], a0);
            a1 = fmaf(sXm[k+1], Wg[(k+1)*Hdim + j], a1);
            a2 = fmaf(sXm[k+2], Wg[(k+2)*Hdim + j], a2);
            a3 = fmaf(sXm[k+3], Wg[(k+3)*Hdim + j], a3);
            a0 = fmaf(sU[k+0],  Wg[(128+k+0)*Hdim + j], a0);
            a1 = fmaf(sU[k+1],  Wg[(128+k+1)*Hdim + j], a1);
            a2 = fmaf(sU[k+2],  Wg[(128+k+2)*Hdim + j], a2);
            a3 = fmaf(sU[k+3],  Wg[(128+k+3)*Hdim + j], a3);
        }
        sUo[j] = fmaxf((a0+a1)+(a2+a3), 0.f);
    }
    __syncthreads();
    float o;
    {
        float r[4]  = {bih[j]+bhh[j], 0.f, 0.f, 0.f};
        float z[4]  = {bih[128+j]+bhh[128+j], 0.f, 0.f, 0.f};
        float ni[4] = {bih[256+j], 0.f, 0.f, 0.f};
        float nh[4] = {bhh[256+j], 0.f, 0.f, 0.f};
        for (int k=0;k<Hdim;k+=4){
            #pragma unroll
            for (int q=0;q<4;++q){
                float in = sUo[k+q], h = sU[k+q];
                r[q]  = fmaf(in, Wih[(k+q)*384 + j],       r[q]);
                r[q]  = fmaf(h,  Whh[(k+q)*384 + j],       r[q]);
                z[q]  = fmaf(in, Wih[(k+q)*384 + 128 + j], z[q]);
                z[q]  = fmaf(h,  Whh[(k+q)*384 + 128 + j], z[q]);
                ni[q] = fmaf(in, Wih[(k+q)*384 + 256 + j], ni[q]);
                nh[q] = fmaf(h,  Whh[(k+q)*384 + 256 + j], nh[q]);
            }
        }
        float rr = fsigm((r[0]+r[1])+(r[2]+r[3]));
        float zz = fsigm((z[0]+z[1])+(z[2]+z[3]));
        float n  = ftanh(fmaf(rr, (nh[0]+nh[1])+(nh[2]+nh[3]),
                                  (ni[0]+ni[1])+(ni[2]+ni[3])));
        o = (1.0f - zz)*n + zz*hj;
        u[g*Hdim + j] = o;
        out[(long)(g*3 + step)*Hdim + j] = o;
        sO[j] = o;
    }
    __syncthreads();
    {
        float a0=be[j], a1=0.f, b0=bn[j], b1=0.f;
        for (int k=0;k<Hdim;k+=2){
            float v0 = sO[k], v1 = sO[k+1];
            a0 = fmaf(v0, We[(384+k)*Hdim + j],   a0);
            a1 = fmaf(v1, We[(384+k+1)*Hdim + j], a1);
            b0 = fmaf(v0, Wn[(256+k)*Hdim + j],   b0);
            b1 = fmaf(v1, Wn[(256+k+1)*Hdim + j], b1);
        }
        gu[g*Hdim + j] = a0+a1;
        nu[g*Hdim + j] = b0+b1;
    }
}

// ---------------------------------------------------------------- host
extern "C" void kernel_launch(void* const* d_in, const int* in_sizes, int n_in,
                              void* d_out, int out_size, void* d_ws, size_t ws_size,
                              hipStream_t stream)
{
    const float* x    = (const float*)d_in[0];
    const float* ea_i = (const float*)d_in[1];
    const float* u    = (const float*)d_in[2];
    const float* We   = (const float*)d_in[3];
    const float* be   = (const float*)d_in[4];
    const float* Wn   = (const float*)d_in[5];
    const float* bn   = (const float*)d_in[6];
    const float* Wg   = (const float*)d_in[7];
    const float* bg   = (const float*)d_in[8];
    const float* eWih = (const float*)d_in[9];
    const float* eWhh = (const float*)d_in[10];
    const float* ebih = (const float*)d_in[11];
    const float* ebhh = (const float*)d_in[12];
    const float* nWih = (const float*)d_in[13];
    const float* nWhh = (const float*)d_in[14];
    const float* nbih = (const float*)d_in[15];
    const float* nbhh = (const float*)d_in[16];
    const float* gWih = (const float*)d_in[17];
    const float* gWhh = (const float*)d_in[18];
    const float* gbih = (const float*)d_in[19];
    const float* gbhh = (const float*)d_in[20];
    const int*   ei   = (const int*)d_in[21];
    const int*   batch= (const int*)d_in[22];
    const int* src = ei;
    const int* dst = ei + NE;
    float* out = (float*)d_out;

    size_t off = 0;
    auto alloc = [&](size_t bytes)->char*{
        char* p = (char*)d_ws + off;
        off += (bytes + 255) & ~(size_t)255;
        return p;
    };
    unsigned short* ea   = (unsigned short*)alloc((size_t)NE*Hdim*2);
    unsigned short* xb   = (unsigned short*)alloc((size_t)NN*Hdim*2);
    unsigned short* xs1g = (unsigned short*)alloc((size_t)NN*Hdim*2);
    float*          agg  = (float*)alloc((size_t)NN*Hdim*4);
    float*          ucur = (float*)alloc((size_t)NG*Hdim*4);
    float*          gu   = (float*)alloc((size_t)NG*Hdim*4);
    float*          nu   = (float*)alloc((size_t)NG*Hdim*4);
    float*          xsum = (float*)alloc((size_t)NG*Hdim*4);
    unsigned short* PK   = (unsigned short*)alloc((size_t)278528*2);
    int* histo  = (int*)alloc((size_t)(NN+NG)*4);
    float* cnt  = (float*)(histo + NN);
    int* cursor = (int*)alloc((size_t)NN*4);
    int* ssrc   = (int*)alloc((size_t)NE*4);
    int* sdst   = (int*)alloc((size_t)NE*4);
    int* perm   = (int*)alloc((size_t)NE*4);

    unsigned short* PXS  = PK + 0;        // We1
    unsigned short* PX2  = PK + 16384;    // We2
    unsigned short* PW1  = PK + 32768;    // We3
    unsigned short* PeRZ = PK + 49152;
    unsigned short* PeNI = PK + 114688;
    unsigned short* PeNH = PK + 131072;
    unsigned short* PnP1 = PK + 147456;
    unsigned short* PnRZ = PK + 180224;
    unsigned short* PnNI = PK + 245760;
    unsigned short* PnNH = PK + 262144;

    hipMemsetAsync(histo, 0, (size_t)(NN+NG)*4, stream);
    hist_count<<<(NE+255)/256, 256, 0, stream>>>(dst, batch, histo, cnt);
    scan_kernel<<<1, 256, 0, stream>>>(histo, cursor);
    scatter_kernel<<<(NE+255)/256, 256, 0, stream>>>(src, dst, cursor, ssrc, sdst, perm);
    {
        long groups = (long)(NE+NN+NG)*16;
        conv_all<<<(int)((groups+255)/256), 256, 0, stream>>>(ea_i, perm, x, u, ea, xb, ucur);
    }

    PackJobs PJ;
    auto setj = [&](int t, const float* s0, const float* s1, int ld, int coloff,
                    int kr0, int ktot, int ntot, int base){
        PJ.j[t] = PackJob{ s0, s1, ld, coloff, kr0, ktot, ktot*ntot, base };
    };
    setj(0, We,            We,   Hdim, 0,   128, 128, 128, 0);
    setj(1, We+128*Hdim,   We,   Hdim, 0,   128, 128, 128, 16384);
    setj(2, We+256*Hdim,   We,   Hdim, 0,   128, 128, 128, 32768);
    setj(3, eWih, eWhh, 384, 0,   128, 256, 256, 49152);
    setj(4, eWih, eWih, 384, 256, 128, 128, 128, 114688);
    setj(5, eWhh, eWhh, 384, 256, 128, 128, 128, 131072);
    setj(6, Wn,   Wn,   Hdim, 0,  256, 256, 128, 147456);
    setj(7, nWih, nWhh, 384, 0,   128, 256, 256, 180224);
    setj(8, nWih, nWih, 384, 256, 128, 128, 128, 245760);
    setj(9, nWhh, nWhh, 384, 256, 128, 128, 128, 262144);
    pack_all<<<278528/256, 256, 0, stream>>>(PJ, PK);

    graph_pre_kernel<<<32, 128, 0, stream>>>(ucur, We, be, Wn, bn, gu, nu, xsum);

    for (int t=0; t<3; ++t){
        xs_mfma<<<(NN+EBX-1)/EBX, 256, 0, stream>>>(xb, PXS, gu, batch, xs1g, agg);
        edge_mfma<<<NE/EB, 256, 0, stream>>>(ea, xs1g, xb, PW1, PX2, PeRZ, PeNI, PeNH,
                                             ebih, ebhh, ssrc, sdst, agg);
        node_mfma<<<(NN+NB-1)/NB, 256, 0, stream>>>(xb, agg, nu, PnP1, PnRZ, PnNI, PnNH,
                                                    nbih, nbhh, batch, xsum);
        global_kernel<<<NG, 128, 0, stream>>>(xsum, cnt, ucur, Wg, bg,
                                              gWih, gWhh, gbih, gbhh,
                                              We, be, Wn, bn, gu, nu, out, t);
    }
}